// Round 5
// baseline (809.774 us; speedup 1.0000x reference)
//
#include <hip/hip_runtime.h>
#include <math.h>

#define N_WORD 50000
#define N_DOC  10000
#define E_WW   800000
#define E_WD   320000
#define D_IN   256
#define D_H    128

typedef __attribute__((ext_vector_type(8))) short short8;
typedef __attribute__((ext_vector_type(4))) float f32x4;

__device__ inline unsigned short f2bf(float f) {  // fp32 -> bf16 bits, RNE
  unsigned u = __float_as_uint(f);
  u = (u + 0x7fffu + ((u >> 16) & 1u)) >> 16;
  return (unsigned short)u;
}

// ---------------- MFMA GEMM: C[M,128] = A[M,K] @ Bp(packed bf16) ------------
// ABF: A is bf16 (else fp32, converted in-register). OBF: C is bf16 (else fp32).
// 256 thr = 4 waves; wave owns 16 rows x 128 cols; mfma 16x16x32 bf16.
template <int ABF, int OBF>
__global__ __launch_bounds__(256) void mfma_gemm_t(
    const void* __restrict__ Ap, const short* __restrict__ Bp,
    void* __restrict__ Cp, int M, int K) {
  int wid = threadIdx.x >> 6;
  int lane = threadIdx.x & 63;
  int m0 = blockIdx.x * 64 + wid * 16;
  int mA = m0 + (lane & 15);
  if (mA >= M) mA = M - 1;           // clamp: garbage rows never stored
  int quad = lane >> 4;
  f32x4 acc[8];
#pragma unroll
  for (int nt = 0; nt < 8; ++nt) acc[nt] = (f32x4){0.f, 0.f, 0.f, 0.f};
  int KT = K >> 5;
  for (int kt = 0; kt < KT; ++kt) {
    short8 af;
    if (ABF) {
      af = *(const short8*)((const short*)Ap + (size_t)mA * K + quad * 8 + kt * 32);
    } else {
      const float* arow = (const float*)Ap + (size_t)mA * K + quad * 8 + kt * 32;
      float4 a0 = *(const float4*)arow;
      float4 a1 = *(const float4*)(arow + 4);
      af[0] = (short)f2bf(a0.x); af[1] = (short)f2bf(a0.y);
      af[2] = (short)f2bf(a0.z); af[3] = (short)f2bf(a0.w);
      af[4] = (short)f2bf(a1.x); af[5] = (short)f2bf(a1.y);
      af[6] = (short)f2bf(a1.z); af[7] = (short)f2bf(a1.w);
    }
    const short* bbase = Bp + ((size_t)kt * 8 * 512) + lane * 8;
#pragma unroll
    for (int nt = 0; nt < 8; ++nt) {
      short8 bf = *(const short8*)(bbase + (size_t)nt * 512);
      acc[nt] = __builtin_amdgcn_mfma_f32_16x16x32_bf16(af, bf, acc[nt], 0, 0, 0);
    }
  }
  // C/D layout: col = lane&15, row = quad*4 + r   [m89-verified]
  int ccol = lane & 15;
#pragma unroll
  for (int nt = 0; nt < 8; ++nt) {
#pragma unroll
    for (int r = 0; r < 4; ++r) {
      int row = m0 + quad * 4 + r;
      if (row < M) {
        if (OBF)
          ((unsigned short*)Cp)[(size_t)row * 128 + nt * 16 + ccol] = f2bf(acc[nt][r]);
        else
          ((float*)Cp)[(size_t)row * 128 + nt * 16 + ccol] = acc[nt][r];
      }
    }
  }
}

// ---------------- weight pack: fp32 [K,128] -> bf16 B-fragment layout --------
// mats (K=256 l1 / K=128 l2): 0:Ws[0]+Ws[1]+Ws[3], 1..4:Wn[0..3], 5:Ws[2]
__global__ void pack_w_kernel(const float* __restrict__ Ws1, const float* __restrict__ Wn1,
                              const float* __restrict__ Ws2, const float* __restrict__ Wn2,
                              short* __restrict__ Bp1, short* __restrict__ Bp2) {
  int tid = blockIdx.x * blockDim.x + threadIdx.x;
  const int L1T = 6 * 4096;
  const int L2T = 6 * 2048;
  if (tid >= L1T + L2T) return;
  const float *src0, *src1 = nullptr, *src2 = nullptr;
  short* dst;
  int kt, nt, lane;
  if (tid < L1T) {
    int mat = tid / 4096, rem = tid % 4096;
    kt = rem / 512; nt = (rem / 64) % 8; lane = rem % 64;
    const int W1 = 256 * 128;
    if (mat == 0) { src0 = Ws1; src1 = Ws1 + W1; src2 = Ws1 + 3 * W1; }
    else if (mat <= 4) src0 = Wn1 + (size_t)(mat - 1) * W1;
    else src0 = Ws1 + 2 * W1;
    dst = Bp1 + (size_t)mat * W1 + ((size_t)(kt * 8 + nt) * 64 + lane) * 8;
  } else {
    int t2 = tid - L1T;
    int mat = t2 / 2048, rem = t2 % 2048;
    kt = rem / 512; nt = (rem / 64) % 8; lane = rem % 64;
    const int W2 = 128 * 128;
    if (mat == 0) { src0 = Ws2; src1 = Ws2 + W2; src2 = Ws2 + 3 * W2; }
    else if (mat <= 4) src0 = Wn2 + (size_t)(mat - 1) * W2;
    else src0 = Ws2 + 2 * W2;
    dst = Bp2 + (size_t)mat * W2 + ((size_t)(kt * 8 + nt) * 64 + lane) * 8;
  }
  int n = nt * 16 + (lane & 15);
  int kb = kt * 32 + (lane >> 4) * 8;
  short8 v;
#pragma unroll
  for (int j = 0; j < 8; ++j) {
    float f = src0[(size_t)(kb + j) * 128 + n];
    if (src1) f += src1[(size_t)(kb + j) * 128 + n] + src2[(size_t)(kb + j) * 128 + n];
    v[j] = (short)f2bf(f);
  }
  *(short8*)dst = v;
}

// ---------------- CSR build --------------------------------------------------
__global__ void count4_kernel(const int* __restrict__ wwd, const int* __restrict__ wwrd,
                              const int* __restrict__ wdrd, const int* __restrict__ wdd,
                              int* rww, int* rwwr, int* rwdr, int* rwd) {
  int i = blockIdx.x * blockDim.x + threadIdx.x;
  if (i < E_WW) atomicAdd(&rww[wwd[i]], 1);
  else if (i < 2 * E_WW) atomicAdd(&rwwr[wwrd[i - E_WW]], 1);
  else if (i < 2 * E_WW + E_WD) atomicAdd(&rwdr[wdrd[i - 2 * E_WW]], 1);
  else if (i < 2 * E_WW + 2 * E_WD) atomicAdd(&rwd[wdd[i - 2 * E_WW - E_WD]], 1);
}

#define SCHUNK 1024
#define NB_W 49
#define NB_D 10
#define NB_TOT (3 * NB_W + NB_D)

__device__ inline void scan_map(int b, int* rww, int* rwwr, int* rwdr, int* rwd,
                                int*& a, int& n, int& cb) {
  if (b < NB_W) { a = rww; n = N_WORD; cb = b; }
  else if (b < 2 * NB_W) { a = rwwr; n = N_WORD; cb = b - NB_W; }
  else if (b < 3 * NB_W) { a = rwdr; n = N_WORD; cb = b - 2 * NB_W; }
  else { a = rwd; n = N_DOC; cb = b - 3 * NB_W; }
}

__global__ __launch_bounds__(256) void scan_p1_kernel(int* rww, int* rwwr, int* rwdr,
                                                      int* rwd, int* partials) {
  int* a; int n, cb;
  scan_map(blockIdx.x, rww, rwwr, rwdr, rwd, a, n, cb);
  int base = cb * SCHUNK + threadIdx.x * 4;
  int s = 0;
#pragma unroll
  for (int j = 0; j < 4; ++j) { int i = base + j; if (i < n) s += a[i]; }
#pragma unroll
  for (int off = 32; off > 0; off >>= 1) s += __shfl_down(s, off);
  __shared__ int sm[4];
  if ((threadIdx.x & 63) == 0) sm[threadIdx.x >> 6] = s;
  __syncthreads();
  if (threadIdx.x == 0) partials[blockIdx.x] = sm[0] + sm[1] + sm[2] + sm[3];
}

__global__ __launch_bounds__(256) void scan_p2_kernel(int* partials) {
  __shared__ int sm[256];
  int tid = threadIdx.x;
  int v = (tid < NB_TOT) ? partials[tid] : 0;
  sm[tid] = v;
  __syncthreads();
  int base = tid < NB_W ? 0 : tid < 2 * NB_W ? NB_W
           : tid < 3 * NB_W ? 2 * NB_W : tid < NB_TOT ? 3 * NB_W : NB_TOT;
  for (int off = 1; off < 256; off <<= 1) {
    int add = (tid - off >= base) ? sm[tid - off] : 0;
    __syncthreads();
    sm[tid] += add;
    __syncthreads();
  }
  if (tid < NB_TOT) partials[tid] = sm[tid] - v;
}

__global__ __launch_bounds__(256) void scan_p3_kernel(int* rww, int* rwwr, int* rwdr,
                                                      int* rwd, const int* __restrict__ partials) {
  int* a; int n, cb;
  scan_map(blockIdx.x, rww, rwwr, rwdr, rwd, a, n, cb);
  int base = cb * SCHUNK + threadIdx.x * 4;
  int c[4];
#pragma unroll
  for (int j = 0; j < 4; ++j) { int i = base + j; c[j] = (i < n) ? a[i] : 0; }
  int s = c[0] + c[1] + c[2] + c[3];
  __shared__ int sm[256];
  sm[threadIdx.x] = s;
  __syncthreads();
  for (int off = 1; off < 256; off <<= 1) {
    int add = (threadIdx.x >= off) ? sm[threadIdx.x - off] : 0;
    __syncthreads();
    sm[threadIdx.x] += add;
    __syncthreads();
  }
  int ex = sm[threadIdx.x] - s + partials[blockIdx.x];
#pragma unroll
  for (int j = 0; j < 4; ++j) {
    int i = base + j;
    if (i < n) a[i] = ex;
    ex += c[j];
  }
}

// CSR store via atomicOr: executes in L2 (line-allocating) — kills the 117MB
// partial-line HBM write amplification of plain 2B scattered stores (round 4).
// csr32 pre-zeroed; each 16-bit slot written exactly once.
__global__ void fill4_kernel(const int* wws, const int* wwd, const int* wwrs, const int* wwrd,
                             const int* wdrs, const int* wdrd, const int* wds, const int* wdd,
                             int* rww, int* rwwr, int* rwdr, int* rwd,
                             unsigned* cww, unsigned* cwwr, unsigned* cwdr, unsigned* cwd) {
  int i = blockIdx.x * blockDim.x + threadIdx.x;
  const int *src, *dst; int* rp; unsigned* csr; int e;
  if (i < E_WW) { src = wws; dst = wwd; rp = rww; csr = cww; e = i; }
  else if (i < 2 * E_WW) { src = wwrs; dst = wwrd; rp = rwwr; csr = cwwr; e = i - E_WW; }
  else if (i < 2 * E_WW + E_WD) { src = wdrs; dst = wdrd; rp = rwdr; csr = cwdr; e = i - 2 * E_WW; }
  else if (i < 2 * E_WW + 2 * E_WD) { src = wds; dst = wdd; rp = rwd; csr = cwd; e = i - 2 * E_WW - E_WD; }
  else return;
  int pos = atomicAdd(&rp[dst[e]], 1);
  atomicOr(&csr[pos >> 1], (unsigned)src[e] << ((pos & 1) << 4));
}

// ---------------- gathers ----------------------------------------------------
// lane owns channels {2*lane, 2*lane+1}; y word = low|high bf16 pair.
__device__ inline void accum_rel(const unsigned* __restrict__ y,
                                 const unsigned short* __restrict__ csr,
                                 int beg, int end, int lane, float& f0, float& f1) {
  float a0 = 0.f, a1 = 0.f;
  int j = beg;
  for (; j + 3 < end; j += 4) {
    int s0 = csr[j], s1 = csr[j + 1], s2 = csr[j + 2], s3 = csr[j + 3];
    unsigned u0 = y[((size_t)s0 << 6) + lane];
    unsigned u1 = y[((size_t)s1 << 6) + lane];
    unsigned u2 = y[((size_t)s2 << 6) + lane];
    unsigned u3 = y[((size_t)s3 << 6) + lane];
    a0 += __uint_as_float(u0 << 16) + __uint_as_float(u1 << 16)
        + __uint_as_float(u2 << 16) + __uint_as_float(u3 << 16);
    a1 += __uint_as_float(u0 & 0xffff0000u) + __uint_as_float(u1 & 0xffff0000u)
        + __uint_as_float(u2 & 0xffff0000u) + __uint_as_float(u3 & 0xffff0000u);
  }
  for (; j < end; ++j) {
    unsigned u = y[((size_t)csr[j] << 6) + lane];
    a0 += __uint_as_float(u << 16);
    a1 += __uint_as_float(u & 0xffff0000u);
  }
  int deg = end - beg;
  float inv = 1.0f / (float)(deg > 1 ? deg : 1);
  f0 += a0 * inv;
  f1 += a1 * inv;
}

// fused word gather: self(t) + 3 relation means + bias + relu, then
// mode 1: write bf16 activations; mode 2: fused linear+sigmoid readout.
__global__ __launch_bounds__(256) void gather3_kernel(
    const unsigned* __restrict__ y0, const unsigned* __restrict__ y1,
    const unsigned* __restrict__ y2,
    const unsigned short* __restrict__ c0, const unsigned short* __restrict__ c1,
    const unsigned short* __restrict__ c2,
    const int* __restrict__ r0, const int* __restrict__ r1, const int* __restrict__ r2,
    const float* __restrict__ t, const float* __restrict__ bias,
    const float* __restrict__ lw, const float* __restrict__ lb,
    unsigned* __restrict__ out16, float* __restrict__ outF, int n, int mode) {
  int node = (blockIdx.x << 2) + (threadIdx.x >> 6);
  if (node >= n) return;
  int lane = threadIdx.x & 63;
  float2 tv = ((const float2*)(t + ((size_t)node << 7)))[lane];
  float f0 = tv.x, f1 = tv.y;
  accum_rel(y0, c0, node ? r0[node - 1] : 0, r0[node], lane, f0, f1);
  accum_rel(y1, c1, node ? r1[node - 1] : 0, r1[node], lane, f0, f1);
  accum_rel(y2, c2, node ? r2[node - 1] : 0, r2[node], lane, f0, f1);
  float2 bv = ((const float2*)bias)[lane];
  f0 += bv.x; f1 += bv.y;
  f0 = f0 > 0.f ? f0 : 0.f;
  f1 = f1 > 0.f ? f1 : 0.f;
  if (mode == 1) {
    out16[((size_t)node << 6) + lane] = (unsigned)f2bf(f0) | ((unsigned)f2bf(f1) << 16);
  } else {
    float2 lv = ((const float2*)lw)[lane];
    float s = f0 * lv.x + f1 * lv.y;
#pragma unroll
    for (int off = 32; off > 0; off >>= 1) s += __shfl_xor(s, off);
    if (lane == 0) outF[node] = 1.0f / (1.0f + expf(-(s + lb[0])));
  }
}

// doc gather: self(t) + 1 relation mean + bias + relu; modes as above
__global__ __launch_bounds__(256) void gather1_kernel(
    const unsigned* __restrict__ y, const unsigned short* __restrict__ csr,
    const int* __restrict__ rp, const float* __restrict__ t,
    const float* __restrict__ bias, const float* __restrict__ lw,
    const float* __restrict__ lb, unsigned* __restrict__ out16,
    float* __restrict__ outF, int n, int mode) {
  int node = (blockIdx.x << 2) + (threadIdx.x >> 6);
  if (node >= n) return;
  int lane = threadIdx.x & 63;
  float2 tv = ((const float2*)(t + ((size_t)node << 7)))[lane];
  float f0 = tv.x, f1 = tv.y;
  accum_rel(y, csr, node ? rp[node - 1] : 0, rp[node], lane, f0, f1);
  float2 bv = ((const float2*)bias)[lane];
  f0 += bv.x; f1 += bv.y;
  f0 = f0 > 0.f ? f0 : 0.f;
  f1 = f1 > 0.f ? f1 : 0.f;
  if (mode == 1) {
    out16[((size_t)node << 6) + lane] = (unsigned)f2bf(f0) | ((unsigned)f2bf(f1) << 16);
  } else {
    float2 lv = ((const float2*)lw)[lane];
    float s = f0 * lv.x + f1 * lv.y;
#pragma unroll
    for (int off = 32; off > 0; off >>= 1) s += __shfl_xor(s, off);
    if (lane == 0) outF[node] = 1.0f / (1.0f + expf(-(s + lb[0])));
  }
}

__global__ void add3_kernel(const float* __restrict__ a, const float* __restrict__ b,
                            const float* __restrict__ c, float* __restrict__ o, int n) {
  int i = blockIdx.x * blockDim.x + threadIdx.x;
  if (i < n) o[i] = a[i] + b[i] + c[i];
}

// ---------------------------------------------------------------------------
extern "C" void kernel_launch(void* const* d_in, const int* in_sizes, int n_in,
                              void* d_out, int out_size, void* d_ws, size_t ws_size,
                              hipStream_t stream) {
  const float* xw      = (const float*)d_in[0];
  const float* xd      = (const float*)d_in[1];
  const int*   ww_src  = (const int*)d_in[2];
  const int*   ww_dst  = (const int*)d_in[3];
  const int*   wwr_src = (const int*)d_in[4];
  const int*   wwr_dst = (const int*)d_in[5];
  const int*   wd_src  = (const int*)d_in[6];
  const int*   wd_dst  = (const int*)d_in[7];
  const int*   wdr_src = (const int*)d_in[8];
  const int*   wdr_dst = (const int*)d_in[9];
  const float* Ws1     = (const float*)d_in[10];
  const float* Wn1     = (const float*)d_in[11];
  const float* b1      = (const float*)d_in[12];
  const float* Ws2     = (const float*)d_in[13];
  const float* Wn2     = (const float*)d_in[14];
  const float* b2      = (const float*)d_in[15];
  const float* lin_w   = (const float*)d_in[16];
  const float* lin_b   = (const float*)d_in[17];
  float* out = (float*)d_out;

  // ---- workspace carve (~80 MB) ----
  char* p = (char*)d_ws;
  auto alloc = [&](size_t nbytes) {
    char* r = p;
    p += (nbytes + 255) & ~(size_t)255;
    return r;
  };
  float* twA  = (float*)alloc((size_t)N_WORD * D_H * 4);   // word fp32 acc (both layers)
  float* tdA  = (float*)alloc((size_t)N_DOC * D_H * 4);    // doc fp32 acc (both layers)
  unsigned* xw1B = (unsigned*)alloc((size_t)N_WORD * D_H * 2);  // layer-1 word act, bf16
  unsigned* xd1B = (unsigned*)alloc((size_t)N_DOC * D_H * 2);   // layer-1 doc act, bf16
  unsigned* yB0 = (unsigned*)alloc((size_t)N_WORD * D_H * 2);   // bf16 transformed feats
  unsigned* yB1 = (unsigned*)alloc((size_t)N_WORD * D_H * 2);
  unsigned* ydB = (unsigned*)alloc((size_t)N_DOC * D_H * 2);
  unsigned* csr_ww  = (unsigned*)alloc((size_t)E_WW * 2);
  unsigned* csr_wwr = (unsigned*)alloc((size_t)E_WW * 2);
  unsigned* csr_wdr = (unsigned*)alloc((size_t)E_WD * 2);
  unsigned* csr_wd  = (unsigned*)alloc((size_t)E_WD * 2);
  int* rp_ww  = (int*)alloc((size_t)(N_WORD + 1) * 4);
  int* rp_wwr = (int*)alloc((size_t)(N_WORD + 1) * 4);
  int* rp_wdr = (int*)alloc((size_t)(N_WORD + 1) * 4);
  int* rp_wd  = (int*)alloc((size_t)(N_DOC + 1) * 4);
  short* Bp1 = (short*)alloc((size_t)6 * 256 * 128 * 2);
  short* Bp2 = (short*)alloc((size_t)6 * 128 * 128 * 2);
  int* partials = (int*)alloc((size_t)NB_TOT * 4);
  float* bs1 = (float*)alloc(D_H * 4);
  float* bs2 = (float*)alloc(D_H * 4);

  // ---- CSR build ----
  size_t rp_span = (size_t)((char*)rp_wd + (N_DOC + 1) * 4 - (char*)rp_ww);
  hipMemsetAsync(rp_ww, 0, rp_span, stream);
  size_t csr_span = (size_t)((char*)csr_wd + E_WD * 2 - (char*)csr_ww);
  hipMemsetAsync(csr_ww, 0, csr_span, stream);   // atomicOr needs zeroed base
  const int ETOT = 2 * E_WW + 2 * E_WD;
  count4_kernel<<<(ETOT + 255) / 256, 256, 0, stream>>>(
      ww_dst, wwr_dst, wdr_dst, wd_dst, rp_ww, rp_wwr, rp_wdr, rp_wd);
  scan_p1_kernel<<<NB_TOT, 256, 0, stream>>>(rp_ww, rp_wwr, rp_wdr, rp_wd, partials);
  scan_p2_kernel<<<1, 256, 0, stream>>>(partials);
  scan_p3_kernel<<<NB_TOT, 256, 0, stream>>>(rp_ww, rp_wwr, rp_wdr, rp_wd, partials);
  fill4_kernel<<<(ETOT + 255) / 256, 256, 0, stream>>>(
      ww_src, ww_dst, wwr_src, wwr_dst, wdr_src, wdr_dst, wd_src, wd_dst,
      rp_ww, rp_wwr, rp_wdr, rp_wd, csr_ww, csr_wwr, csr_wdr, csr_wd);

  // ---- weight pack + combined biases ----
  pack_w_kernel<<<(6 * 4096 + 6 * 2048 + 255) / 256, 256, 0, stream>>>(
      Ws1, Wn1, Ws2, Wn2, Bp1, Bp2);
  add3_kernel<<<1, 128, 0, stream>>>(b1, b1 + 128, b1 + 384, bs1, 128);
  add3_kernel<<<1, 128, 0, stream>>>(b2, b2 + 128, b2 + 384, bs2, 128);

  const int W1 = 256 * 128;
  const int W2 = 128 * 128;
  auto g32F = [&](const float* A, const short* Bm, float* C, int M, int K) {
    mfma_gemm_t<0, 0><<<(M + 63) / 64, 256, 0, stream>>>(A, Bm, C, M, K);
  };
  auto g32H = [&](const float* A, const short* Bm, unsigned* C, int M, int K) {
    mfma_gemm_t<0, 1><<<(M + 63) / 64, 256, 0, stream>>>(A, Bm, C, M, K);
  };
  auto g16F = [&](const unsigned* A, const short* Bm, float* C, int M, int K) {
    mfma_gemm_t<1, 0><<<(M + 63) / 64, 256, 0, stream>>>(A, Bm, C, M, K);
  };
  auto g16H = [&](const unsigned* A, const short* Bm, unsigned* C, int M, int K) {
    mfma_gemm_t<1, 1><<<(M + 63) / 64, 256, 0, stream>>>(A, Bm, C, M, K);
  };

  // ================= layer 1 =================
  g32F(xw, Bp1 + 0 * W1, twA, N_WORD, 256);       // word self (3 rels combined)
  g32H(xw, Bp1 + 1 * W1, yB0, N_WORD, 256);       // ww neigh
  g32H(xw, Bp1 + 2 * W1, yB1, N_WORD, 256);       // wwr neigh
  g32H(xd, Bp1 + 4 * W1, ydB, N_DOC, 256);        // wdr neigh (doc -> word)
  gather3_kernel<<<(N_WORD + 3) / 4, 256, 0, stream>>>(
      yB0, yB1, ydB, (unsigned short*)csr_ww, (unsigned short*)csr_wwr,
      (unsigned short*)csr_wdr, rp_ww, rp_wwr, rp_wdr,
      twA, bs1, lin_w, lin_b, xw1B, nullptr, N_WORD, 1);
  g32F(xd, Bp1 + 5 * W1, tdA, N_DOC, 256);        // doc self
  g32H(xw, Bp1 + 3 * W1, yB0, N_WORD, 256);       // wd neigh (word -> doc)
  gather1_kernel<<<(N_DOC + 3) / 4, 256, 0, stream>>>(
      yB0, (unsigned short*)csr_wd, rp_wd, tdA, b1 + 256, lin_w, lin_b,
      xd1B, nullptr, N_DOC, 1);

  // ================= layer 2 (+ fused readout) =================
  g16F(xw1B, Bp2 + 0 * W2, twA, N_WORD, 128);     // twA reused as L2 word acc
  g16H(xw1B, Bp2 + 1 * W2, yB0, N_WORD, 128);
  g16H(xw1B, Bp2 + 2 * W2, yB1, N_WORD, 128);
  g16H(xd1B, Bp2 + 4 * W2, ydB, N_DOC, 128);
  gather3_kernel<<<(N_WORD + 3) / 4, 256, 0, stream>>>(
      yB0, yB1, ydB, (unsigned short*)csr_ww, (unsigned short*)csr_wwr,
      (unsigned short*)csr_wdr, rp_ww, rp_wwr, rp_wdr,
      twA, bs2, lin_w, lin_b, nullptr, out, N_WORD, 2);      // word scores
  g16F(xd1B, Bp2 + 5 * W2, tdA, N_DOC, 128);      // tdA reused as L2 doc acc
  g16H(xw1B, Bp2 + 3 * W2, yB0, N_WORD, 128);
  gather1_kernel<<<(N_DOC + 3) / 4, 256, 0, stream>>>(
      yB0, (unsigned short*)csr_wd, rp_wd, tdA, b2 + 256, lin_w, lin_b,
      nullptr, out + N_WORD, N_DOC, 2);                      // doc scores
}

// Round 6
// 570.258 us; speedup vs baseline: 1.4200x; 1.4200x over previous
//
#include <hip/hip_runtime.h>
#include <math.h>

#define N_WORD 50000
#define N_DOC  10000
#define E_WW   800000
#define E_WD   320000
#define D_IN   256
#define D_H    128

#define NPB    1024           // nodes per bucket
#define NBK_W  49             // ceil(50000/1024)
#define NBK_D  10             // ceil(10000/1024)
#define BKT    (3 * NBK_W + NBK_D)   // 157 buckets total
#define EPB    8192           // edges per block in hist/bin
// block ranges for hist/bin: ww [0,98) wwr [98,196) wdr [196,236) wd [236,276)
#define NBLK_WW 98
#define NBLK_WD 40
#define NBLK_TOT (2 * NBLK_WW + 2 * NBLK_WD)

typedef __attribute__((ext_vector_type(8))) short short8;
typedef __attribute__((ext_vector_type(4))) float f32x4;

__device__ inline unsigned short f2bf(float f) {  // fp32 -> bf16 bits, RNE
  unsigned u = __float_as_uint(f);
  u = (u + 0x7fffu + ((u >> 16) & 1u)) >> 16;
  return (unsigned short)u;
}

// ---------------- multi-head MFMA GEMM --------------------------------------
// One dispatch runs 6 independent C[M,128] = A[M,K] @ B GEMMs (blockIdx.y).
// ABF: A bf16 (else fp32 converted in-register). obf per head: C bf16/fp32.
struct HeadDesc { const void* A; void* C; const short* B; int M; int obf; };
struct Heads6 { HeadDesc h[6]; };

template <int ABF>
__global__ __launch_bounds__(256) void mfma_gemm6(Heads6 H, int K) {
  HeadDesc d = H.h[blockIdx.y];
  if (blockIdx.x * 64 >= d.M) return;
  int wid = threadIdx.x >> 6;
  int lane = threadIdx.x & 63;
  int m0 = blockIdx.x * 64 + wid * 16;
  int mA = m0 + (lane & 15);
  if (mA >= d.M) mA = d.M - 1;       // clamp: garbage rows never stored
  int quad = lane >> 4;
  f32x4 acc[8];
#pragma unroll
  for (int nt = 0; nt < 8; ++nt) acc[nt] = (f32x4){0.f, 0.f, 0.f, 0.f};
  int KT = K >> 5;
  for (int kt = 0; kt < KT; ++kt) {
    short8 af;
    if (ABF) {
      af = *(const short8*)((const short*)d.A + (size_t)mA * K + quad * 8 + kt * 32);
    } else {
      const float* arow = (const float*)d.A + (size_t)mA * K + quad * 8 + kt * 32;
      float4 a0 = *(const float4*)arow;
      float4 a1 = *(const float4*)(arow + 4);
      af[0] = (short)f2bf(a0.x); af[1] = (short)f2bf(a0.y);
      af[2] = (short)f2bf(a0.z); af[3] = (short)f2bf(a0.w);
      af[4] = (short)f2bf(a1.x); af[5] = (short)f2bf(a1.y);
      af[6] = (short)f2bf(a1.z); af[7] = (short)f2bf(a1.w);
    }
    const short* bbase = d.B + ((size_t)kt * 8 * 512) + lane * 8;
#pragma unroll
    for (int nt = 0; nt < 8; ++nt) {
      short8 bf = *(const short8*)(bbase + (size_t)nt * 512);
      acc[nt] = __builtin_amdgcn_mfma_f32_16x16x32_bf16(af, bf, acc[nt], 0, 0, 0);
    }
  }
  int ccol = lane & 15;   // C/D: col = lane&15, row = quad*4 + r  [m89-verified]
  if (d.obf) {
#pragma unroll
    for (int nt = 0; nt < 8; ++nt)
#pragma unroll
      for (int r = 0; r < 4; ++r) {
        int row = m0 + quad * 4 + r;
        if (row < d.M)
          ((unsigned short*)d.C)[(size_t)row * 128 + nt * 16 + ccol] = f2bf(acc[nt][r]);
      }
  } else {
#pragma unroll
    for (int nt = 0; nt < 8; ++nt)
#pragma unroll
      for (int r = 0; r < 4; ++r) {
        int row = m0 + quad * 4 + r;
        if (row < d.M)
          ((float*)d.C)[(size_t)row * 128 + nt * 16 + ccol] = acc[nt][r];
      }
  }
}

// ---------------- weight pack: fp32 [K,128] -> bf16 B-fragment layout --------
// mats: 0:Ws[0]+Ws[1]+Ws[3], 1..4:Wn[0..3], 5:Ws[2]
__global__ void pack_w_kernel(const float* __restrict__ Ws1, const float* __restrict__ Wn1,
                              const float* __restrict__ Ws2, const float* __restrict__ Wn2,
                              short* __restrict__ Bp1, short* __restrict__ Bp2) {
  int tid = blockIdx.x * blockDim.x + threadIdx.x;
  const int L1T = 6 * 4096;
  const int L2T = 6 * 2048;
  if (tid >= L1T + L2T) return;
  const float *src0, *src1 = nullptr, *src2 = nullptr;
  short* dst;
  int kt, nt, lane;
  if (tid < L1T) {
    int mat = tid / 4096, rem = tid % 4096;
    kt = rem / 512; nt = (rem / 64) % 8; lane = rem % 64;
    const int W1 = 256 * 128;
    if (mat == 0) { src0 = Ws1; src1 = Ws1 + W1; src2 = Ws1 + 3 * W1; }
    else if (mat <= 4) src0 = Wn1 + (size_t)(mat - 1) * W1;
    else src0 = Ws1 + 2 * W1;
    dst = Bp1 + (size_t)mat * W1 + ((size_t)(kt * 8 + nt) * 64 + lane) * 8;
  } else {
    int t2 = tid - L1T;
    int mat = t2 / 2048, rem = t2 % 2048;
    kt = rem / 512; nt = (rem / 64) % 8; lane = rem % 64;
    const int W2 = 128 * 128;
    if (mat == 0) { src0 = Ws2; src1 = Ws2 + W2; src2 = Ws2 + 3 * W2; }
    else if (mat <= 4) src0 = Wn2 + (size_t)(mat - 1) * W2;
    else src0 = Ws2 + 2 * W2;
    dst = Bp2 + (size_t)mat * W2 + ((size_t)(kt * 8 + nt) * 64 + lane) * 8;
  }
  int n = nt * 16 + (lane & 15);
  int kb = kt * 32 + (lane >> 4) * 8;
  short8 v;
#pragma unroll
  for (int j = 0; j < 8; ++j) {
    float f = src0[(size_t)(kb + j) * 128 + n];
    if (src1) f += src1[(size_t)(kb + j) * 128 + n] + src2[(size_t)(kb + j) * 128 + n];
    v[j] = (short)f2bf(f);
  }
  *(short8*)dst = v;
}

// ---------------- CSR build: bucketed counting sort, NO scattered atomics ----
__device__ inline void rel_map(int b, const int* wwd, const int* wwrd, const int* wdrd,
                               const int* wdd, const int*& dst, int& E, int& gbase, int& lb) {
  if (b < NBLK_WW) { dst = wwd; E = E_WW; gbase = 0; lb = b; }
  else if (b < 2 * NBLK_WW) { dst = wwrd; E = E_WW; gbase = NBK_W; lb = b - NBLK_WW; }
  else if (b < 2 * NBLK_WW + NBLK_WD) { dst = wdrd; E = E_WD; gbase = 2 * NBK_W; lb = b - 2 * NBLK_WW; }
  else { dst = wdd; E = E_WD; gbase = 3 * NBK_W; lb = b - 2 * NBLK_WW - NBLK_WD; }
}

__global__ __launch_bounds__(256) void hist_kernel(
    const int* wwd, const int* wwrd, const int* wdrd, const int* wdd, int* btot) {
  __shared__ int h[NBK_W];
  const int* dst; int E, gbase, lb;
  rel_map(blockIdx.x, wwd, wwrd, wdrd, wdd, dst, E, gbase, lb);
  for (int i = threadIdx.x; i < NBK_W; i += 256) h[i] = 0;
  __syncthreads();
  int e0 = lb * EPB;
#pragma unroll
  for (int k = 0; k < EPB / 256; ++k) {
    int i = e0 + k * 256 + threadIdx.x;
    if (i < E) atomicAdd(&h[dst[i] >> 10], 1);
  }
  __syncthreads();
  if (threadIdx.x < NBK_W && h[threadIdx.x])
    atomicAdd(&btot[gbase + threadIdx.x], h[threadIdx.x]);
}

// segmented exclusive scan of 157 bucket totals; bases double as CSR bases
__global__ __launch_bounds__(256) void bscan_kernel(const int* __restrict__ btot,
    int* bbase, int* bcur, int* rp_ww, int* rp_wwr, int* rp_wdr, int* rp_wd) {
  __shared__ int sm[256];
  int tid = threadIdx.x;
  int v = (tid < BKT) ? btot[tid] : 0;
  sm[tid] = v;
  __syncthreads();
  int segbase = tid < NBK_W ? 0 : tid < 2 * NBK_W ? NBK_W
              : tid < 3 * NBK_W ? 2 * NBK_W : tid < BKT ? 3 * NBK_W : BKT;
  for (int off = 1; off < 256; off <<= 1) {
    int add = (tid - off >= segbase) ? sm[tid - off] : 0;
    __syncthreads();
    sm[tid] += add;
    __syncthreads();
  }
  if (tid < BKT) { int ex = sm[tid] - v; bbase[tid] = ex; bcur[tid] = ex; }
  if (tid == 0) rp_ww[N_WORD] = E_WW;
  if (tid == 1) rp_wwr[N_WORD] = E_WW;
  if (tid == 2) rp_wdr[N_WORD] = E_WD;
  if (tid == 3) rp_wd[N_DOC] = E_WD;
}

// bin edges into per-bucket staging; writes are contiguous per (block,bucket) run
__global__ __launch_bounds__(256) void bin_kernel(
    const int* wws, const int* wwd, const int* wwrs, const int* wwrd,
    const int* wdrs, const int* wdrd, const int* wds, const int* wdd,
    int* bcur, unsigned* st_ww, unsigned* st_wwr, unsigned* st_wdr, unsigned* st_wd) {
  __shared__ int h[NBK_W], base[NBK_W], cur[NBK_W];
  int b = blockIdx.x;
  const int* dst; int E, gbase, lb;
  rel_map(b, wwd, wwrd, wdrd, wdd, dst, E, gbase, lb);
  const int* src; unsigned* st;
  if (b < NBLK_WW) { src = wws; st = st_ww; }
  else if (b < 2 * NBLK_WW) { src = wwrs; st = st_wwr; }
  else if (b < 2 * NBLK_WW + NBLK_WD) { src = wdrs; st = st_wdr; }
  else { src = wds; st = st_wd; }
  for (int i = threadIdx.x; i < NBK_W; i += 256) h[i] = 0;
  __syncthreads();
  int e0 = lb * EPB;
#pragma unroll
  for (int k = 0; k < EPB / 256; ++k) {
    int i = e0 + k * 256 + threadIdx.x;
    if (i < E) atomicAdd(&h[dst[i] >> 10], 1);
  }
  __syncthreads();
  if (threadIdx.x < NBK_W) {
    base[threadIdx.x] = h[threadIdx.x] ? atomicAdd(&bcur[gbase + threadIdx.x], h[threadIdx.x]) : 0;
    cur[threadIdx.x] = 0;
  }
  __syncthreads();
#pragma unroll
  for (int k = 0; k < EPB / 256; ++k) {
    int i = e0 + k * 256 + threadIdx.x;
    if (i < E) {
      int d = dst[i];
      int bk = d >> 10;
      int l = atomicAdd(&cur[bk], 1);
      st[base[bk] + l] = (unsigned)(src[i] & 0xFFFF) | ((unsigned)(d & (NPB - 1)) << 16);
    }
  }
}

// one block per bucket: per-node LDS count+scan -> rp (coalesced) and final
// csr placement into a block-private contiguous window (single-XCD L2 combining)
__global__ __launch_bounds__(256) void place_kernel(
    const int* __restrict__ bbase,
    const unsigned* st_ww, const unsigned* st_wwr, const unsigned* st_wdr, const unsigned* st_wd,
    unsigned short* c_ww, unsigned short* c_wwr, unsigned short* c_wdr, unsigned short* c_wd,
    int* rp_ww, int* rp_wwr, int* rp_wdr, int* rp_wd) {
  __shared__ int cnt[NPB], off[NPB], sm[256];
  int g = blockIdx.x;
  const unsigned* st; unsigned short* csr; int* rp; int relFirst, n, E;
  if (g < NBK_W)            { st = st_ww;  csr = c_ww;  rp = rp_ww;  relFirst = 0;          n = N_WORD; E = E_WW; }
  else if (g < 2 * NBK_W)   { st = st_wwr; csr = c_wwr; rp = rp_wwr; relFirst = NBK_W;      n = N_WORD; E = E_WW; }
  else if (g < 3 * NBK_W)   { st = st_wdr; csr = c_wdr; rp = rp_wdr; relFirst = 2 * NBK_W;  n = N_WORD; E = E_WD; }
  else                      { st = st_wd;  csr = c_wd;  rp = rp_wd;  relFirst = 3 * NBK_W;  n = N_DOC;  E = E_WD; }
  int relLast = (g < 3 * NBK_W) ? relFirst + NBK_W - 1 : BKT - 1;
  int node_base = (g - relFirst) << 10;
  int node_cnt = n - node_base; if (node_cnt > NPB) node_cnt = NPB;
  int bstart = bbase[g];
  int bend = (g == relLast) ? E : bbase[g + 1];
  int tid = threadIdx.x;
  for (int i = tid; i < NPB; i += 256) cnt[i] = 0;
  __syncthreads();
  for (int j = bstart + tid; j < bend; j += 256) atomicAdd(&cnt[st[j] >> 16], 1);
  __syncthreads();
  int c[4], s = 0;
#pragma unroll
  for (int jj = 0; jj < 4; ++jj) { c[jj] = cnt[tid * 4 + jj]; s += c[jj]; }
  sm[tid] = s;
  __syncthreads();
  for (int o = 1; o < 256; o <<= 1) {
    int add = (tid >= o) ? sm[tid - o] : 0;
    __syncthreads();
    sm[tid] += add;
    __syncthreads();
  }
  int ex = sm[tid] - s;
#pragma unroll
  for (int jj = 0; jj < 4; ++jj) { off[tid * 4 + jj] = ex; ex += c[jj]; }
  __syncthreads();
#pragma unroll
  for (int jj = 0; jj < 4; ++jj) {
    int i = tid * 4 + jj;
    if (i < node_cnt) rp[node_base + i] = bstart + off[i];
  }
  __syncthreads();     // rp reads of off[] done before cursor mutation
  for (int j = bstart + tid; j < bend; j += 256) {
    unsigned e = st[j];
    int p = atomicAdd(&off[e >> 16], 1);
    csr[bstart + p] = (unsigned short)(e & 0xFFFFu);
  }
}

// ---------------- gathers (rp now clean exclusive: beg=rp[v], end=rp[v+1]) ---
__device__ inline void accum_rel(const unsigned* __restrict__ y,
                                 const unsigned short* __restrict__ csr,
                                 int beg, int end, int lane, float& f0, float& f1) {
  float a0 = 0.f, a1 = 0.f;
  int j = beg;
  for (; j + 3 < end; j += 4) {
    int s0 = csr[j], s1 = csr[j + 1], s2 = csr[j + 2], s3 = csr[j + 3];
    unsigned u0 = y[((size_t)s0 << 6) + lane];
    unsigned u1 = y[((size_t)s1 << 6) + lane];
    unsigned u2 = y[((size_t)s2 << 6) + lane];
    unsigned u3 = y[((size_t)s3 << 6) + lane];
    a0 += __uint_as_float(u0 << 16) + __uint_as_float(u1 << 16)
        + __uint_as_float(u2 << 16) + __uint_as_float(u3 << 16);
    a1 += __uint_as_float(u0 & 0xffff0000u) + __uint_as_float(u1 & 0xffff0000u)
        + __uint_as_float(u2 & 0xffff0000u) + __uint_as_float(u3 & 0xffff0000u);
  }
  for (; j < end; ++j) {
    unsigned u = y[((size_t)csr[j] << 6) + lane];
    a0 += __uint_as_float(u << 16);
    a1 += __uint_as_float(u & 0xffff0000u);
  }
  int deg = end - beg;
  float inv = 1.0f / (float)(deg > 1 ? deg : 1);
  f0 += a0 * inv;
  f1 += a1 * inv;
}

__global__ __launch_bounds__(256) void gather3_kernel(
    const unsigned* __restrict__ y0, const unsigned* __restrict__ y1,
    const unsigned* __restrict__ y2,
    const unsigned short* __restrict__ c0, const unsigned short* __restrict__ c1,
    const unsigned short* __restrict__ c2,
    const int* __restrict__ r0, const int* __restrict__ r1, const int* __restrict__ r2,
    const float* __restrict__ t, const float* __restrict__ bias,
    const float* __restrict__ lw, const float* __restrict__ lb,
    unsigned* __restrict__ out16, float* __restrict__ outF, int n, int mode) {
  int node = (blockIdx.x << 2) + (threadIdx.x >> 6);
  if (node >= n) return;
  int lane = threadIdx.x & 63;
  float2 tv = ((const float2*)(t + ((size_t)node << 7)))[lane];
  float f0 = tv.x, f1 = tv.y;
  accum_rel(y0, c0, r0[node], r0[node + 1], lane, f0, f1);
  accum_rel(y1, c1, r1[node], r1[node + 1], lane, f0, f1);
  accum_rel(y2, c2, r2[node], r2[node + 1], lane, f0, f1);
  float2 bv = ((const float2*)bias)[lane];
  f0 += bv.x; f1 += bv.y;
  f0 = f0 > 0.f ? f0 : 0.f;
  f1 = f1 > 0.f ? f1 : 0.f;
  if (mode == 1) {
    out16[((size_t)node << 6) + lane] = (unsigned)f2bf(f0) | ((unsigned)f2bf(f1) << 16);
  } else {
    float2 lv = ((const float2*)lw)[lane];
    float s = f0 * lv.x + f1 * lv.y;
#pragma unroll
    for (int off = 32; off > 0; off >>= 1) s += __shfl_xor(s, off);
    if (lane == 0) outF[node] = 1.0f / (1.0f + expf(-(s + lb[0])));
  }
}

__global__ __launch_bounds__(256) void gather1_kernel(
    const unsigned* __restrict__ y, const unsigned short* __restrict__ csr,
    const int* __restrict__ rp, const float* __restrict__ t,
    const float* __restrict__ bias, const float* __restrict__ lw,
    const float* __restrict__ lb, unsigned* __restrict__ out16,
    float* __restrict__ outF, int n, int mode) {
  int node = (blockIdx.x << 2) + (threadIdx.x >> 6);
  if (node >= n) return;
  int lane = threadIdx.x & 63;
  float2 tv = ((const float2*)(t + ((size_t)node << 7)))[lane];
  float f0 = tv.x, f1 = tv.y;
  accum_rel(y, csr, rp[node], rp[node + 1], lane, f0, f1);
  float2 bv = ((const float2*)bias)[lane];
  f0 += bv.x; f1 += bv.y;
  f0 = f0 > 0.f ? f0 : 0.f;
  f1 = f1 > 0.f ? f1 : 0.f;
  if (mode == 1) {
    out16[((size_t)node << 6) + lane] = (unsigned)f2bf(f0) | ((unsigned)f2bf(f1) << 16);
  } else {
    float2 lv = ((const float2*)lw)[lane];
    float s = f0 * lv.x + f1 * lv.y;
#pragma unroll
    for (int off = 32; off > 0; off >>= 1) s += __shfl_xor(s, off);
    if (lane == 0) outF[node] = 1.0f / (1.0f + expf(-(s + lb[0])));
  }
}

__global__ void add3_kernel(const float* __restrict__ a, const float* __restrict__ b,
                            const float* __restrict__ c, float* __restrict__ o, int n) {
  int i = blockIdx.x * blockDim.x + threadIdx.x;
  if (i < n) o[i] = a[i] + b[i] + c[i];
}

// ---------------------------------------------------------------------------
extern "C" void kernel_launch(void* const* d_in, const int* in_sizes, int n_in,
                              void* d_out, int out_size, void* d_ws, size_t ws_size,
                              hipStream_t stream) {
  const float* xw      = (const float*)d_in[0];
  const float* xd      = (const float*)d_in[1];
  const int*   ww_src  = (const int*)d_in[2];
  const int*   ww_dst  = (const int*)d_in[3];
  const int*   wwr_src = (const int*)d_in[4];
  const int*   wwr_dst = (const int*)d_in[5];
  const int*   wd_src  = (const int*)d_in[6];
  const int*   wd_dst  = (const int*)d_in[7];
  const int*   wdr_src = (const int*)d_in[8];
  const int*   wdr_dst = (const int*)d_in[9];
  const float* Ws1     = (const float*)d_in[10];
  const float* Wn1     = (const float*)d_in[11];
  const float* b1      = (const float*)d_in[12];
  const float* Ws2     = (const float*)d_in[13];
  const float* Wn2     = (const float*)d_in[14];
  const float* b2      = (const float*)d_in[15];
  const float* lin_w   = (const float*)d_in[16];
  const float* lin_b   = (const float*)d_in[17];
  float* out = (float*)d_out;

  // ---- workspace carve (~92.8 MB; staging aliases yB0 pre-GEMM) ----
  char* p = (char*)d_ws;
  auto alloc = [&](size_t nbytes) {
    char* r = p;
    p += (nbytes + 255) & ~(size_t)255;
    return r;
  };
  float* twA  = (float*)alloc((size_t)N_WORD * D_H * 4);
  float* tdA  = (float*)alloc((size_t)N_DOC * D_H * 4);
  unsigned* xw1B = (unsigned*)alloc((size_t)N_WORD * D_H * 2);
  unsigned* xd1B = (unsigned*)alloc((size_t)N_DOC * D_H * 2);
  unsigned* yB0 = (unsigned*)alloc((size_t)N_WORD * D_H * 2);
  unsigned* yB1 = (unsigned*)alloc((size_t)N_WORD * D_H * 2);
  unsigned* yB2 = (unsigned*)alloc((size_t)N_WORD * D_H * 2);
  unsigned* ydB = (unsigned*)alloc((size_t)N_DOC * D_H * 2);
  unsigned short* csr_ww  = (unsigned short*)alloc((size_t)E_WW * 2);
  unsigned short* csr_wwr = (unsigned short*)alloc((size_t)E_WW * 2);
  unsigned short* csr_wdr = (unsigned short*)alloc((size_t)E_WD * 2);
  unsigned short* csr_wd  = (unsigned short*)alloc((size_t)E_WD * 2);
  int* rp_ww  = (int*)alloc((size_t)(N_WORD + 1) * 4);
  int* rp_wwr = (int*)alloc((size_t)(N_WORD + 1) * 4);
  int* rp_wdr = (int*)alloc((size_t)(N_WORD + 1) * 4);
  int* rp_wd  = (int*)alloc((size_t)(N_DOC + 1) * 4);
  short* Bp1 = (short*)alloc((size_t)6 * 256 * 128 * 2);
  short* Bp2 = (short*)alloc((size_t)6 * 128 * 128 * 2);
  int* btot  = (int*)alloc((size_t)BKT * 4);
  int* bbase = (int*)alloc((size_t)BKT * 4);
  int* bcur  = (int*)alloc((size_t)BKT * 4);
  float* bs1 = (float*)alloc(D_H * 4);
  float* bs2 = (float*)alloc(D_H * 4);
  // staging (9 MB) aliased onto yB0 (12.8 MB): dead before first GEMM writes yB0
  unsigned* st_ww  = yB0;
  unsigned* st_wwr = st_ww + E_WW;
  unsigned* st_wdr = (unsigned*)yB1;          // keep runs line-disjoint per relation
  unsigned* st_wd  = st_wdr + E_WD;

  // ---- CSR build: hist -> bucket scan -> bin -> place (no scattered atomics)
  hipMemsetAsync(btot, 0, BKT * 4, stream);
  hist_kernel<<<NBLK_TOT, 256, 0, stream>>>(ww_dst, wwr_dst, wdr_dst, wd_dst, btot);
  bscan_kernel<<<1, 256, 0, stream>>>(btot, bbase, bcur, rp_ww, rp_wwr, rp_wdr, rp_wd);
  bin_kernel<<<NBLK_TOT, 256, 0, stream>>>(
      ww_src, ww_dst, wwr_src, wwr_dst, wdr_src, wdr_dst, wd_src, wd_dst,
      bcur, st_ww, st_wwr, st_wdr, st_wd);
  place_kernel<<<BKT, 256, 0, stream>>>(
      bbase, st_ww, st_wwr, st_wdr, st_wd,
      csr_ww, csr_wwr, csr_wdr, csr_wd, rp_ww, rp_wwr, rp_wdr, rp_wd);

  // ---- weight pack + combined biases ----
  pack_w_kernel<<<(6 * 4096 + 6 * 2048 + 255) / 256, 256, 0, stream>>>(
      Ws1, Wn1, Ws2, Wn2, Bp1, Bp2);
  add3_kernel<<<1, 128, 0, stream>>>(b1, b1 + 128, b1 + 384, bs1, 128);
  add3_kernel<<<1, 128, 0, stream>>>(b2, b2 + 128, b2 + 384, bs2, 128);

  const int W1 = 256 * 128;
  const int W2 = 128 * 128;
  dim3 ggrid((N_WORD + 63) / 64, 6);

  // ================= layer 1: one 6-head GEMM + 2 gathers =================
  Heads6 H1;
  H1.h[0] = { xw, twA, Bp1 + 0 * W1, N_WORD, 0 };   // word self (combined)
  H1.h[1] = { xw, yB0, Bp1 + 1 * W1, N_WORD, 1 };   // ww neigh
  H1.h[2] = { xw, yB1, Bp1 + 2 * W1, N_WORD, 1 };   // wwr neigh
  H1.h[3] = { xw, yB2, Bp1 + 3 * W1, N_WORD, 1 };   // wd neigh (word->doc)
  H1.h[4] = { xd, tdA, Bp1 + 5 * W1, N_DOC, 0 };    // doc self
  H1.h[5] = { xd, ydB, Bp1 + 4 * W1, N_DOC, 1 };    // wdr neigh (doc->word)
  mfma_gemm6<0><<<ggrid, 256, 0, stream>>>(H1, 256);
  gather3_kernel<<<(N_WORD + 3) / 4, 256, 0, stream>>>(
      yB0, yB1, ydB, csr_ww, csr_wwr, csr_wdr, rp_ww, rp_wwr, rp_wdr,
      twA, bs1, lin_w, lin_b, xw1B, nullptr, N_WORD, 1);
  gather1_kernel<<<(N_DOC + 3) / 4, 256, 0, stream>>>(
      yB2, csr_wd, rp_wd, tdA, b1 + 256, lin_w, lin_b, xd1B, nullptr, N_DOC, 1);

  // ================= layer 2: one 6-head GEMM + 2 fused-readout gathers ====
  Heads6 H2;
  H2.h[0] = { xw1B, twA, Bp2 + 0 * W2, N_WORD, 0 };
  H2.h[1] = { xw1B, yB0, Bp2 + 1 * W2, N_WORD, 1 };
  H2.h[2] = { xw1B, yB1, Bp2 + 2 * W2, N_WORD, 1 };
  H2.h[3] = { xw1B, yB2, Bp2 + 3 * W2, N_WORD, 1 };
  H2.h[4] = { xd1B, tdA, Bp2 + 5 * W2, N_DOC, 0 };
  H2.h[5] = { xd1B, ydB, Bp2 + 4 * W2, N_DOC, 1 };
  mfma_gemm6<1><<<ggrid, 256, 0, stream>>>(H2, 128);
  gather3_kernel<<<(N_WORD + 3) / 4, 256, 0, stream>>>(
      yB0, yB1, ydB, csr_ww, csr_wwr, csr_wdr, rp_ww, rp_wwr, rp_wdr,
      twA, bs2, lin_w, lin_b, nullptr, out, N_WORD, 2);
  gather1_kernel<<<(N_DOC + 3) / 4, 256, 0, stream>>>(
      yB2, csr_wd, rp_wd, tdA, b2 + 256, lin_w, lin_b,
      nullptr, out + N_WORD, N_DOC, 2);
}

// Round 7
// 521.734 us; speedup vs baseline: 1.5521x; 1.0930x over previous
//
#include <hip/hip_runtime.h>
#include <math.h>

#define N_WORD 50000
#define N_DOC  10000
#define E_WW   800000
#define E_WD   320000
#define D_IN   256
#define D_H    128

#define NPB    1024           // nodes per bucket
#define NBK_W  49             // ceil(50000/1024)
#define NBK_D  10             // ceil(10000/1024)
#define BKT    (3 * NBK_W + NBK_D)   // 157 buckets total
#define EPB    8192           // edges per block in hist/bin
#define NBLK_WW 98
#define NBLK_WD 40
#define NBLK_TOT (2 * NBLK_WW + 2 * NBLK_WD)

#define WSTRIP ((N_WORD + 63) / 64)  // 782
#define DSTRIP ((N_DOC + 63) / 64)   // 157

typedef __attribute__((ext_vector_type(8))) short short8;
typedef __attribute__((ext_vector_type(4))) float f32x4;

__device__ inline unsigned short f2bf(float f) {  // fp32 -> bf16 bits, RNE
  unsigned u = __float_as_uint(f);
  u = (u + 0x7fffu + ((u >> 16) & 1u)) >> 16;
  return (unsigned short)u;
}

// ---------------- strip GEMM: stage A once in LDS, run all heads on it ------
// Block owns a 64-row strip. Word strips run heads 0..3, doc strips 4..5.
// A staged fp32->bf16 (ABF=0) or bf16 copy (ABF=1) into LDS row-major with
// +8-short row pad (even 8-way bank spread on ds_read_b128 fragments).
struct G6 { const short* B[6]; void* C[6]; unsigned obf; };

template <int ABF>
__global__ __launch_bounds__(256) void gemm_strip(
    const void* __restrict__ Aw, const void* __restrict__ Ad,
    G6 g, int K, int kd8s) {
  __shared__ short As[64 * 264];   // max K=256: 64*(256+8) shorts = 33.8 KB
  int blk = blockIdx.x;
  const void* A; int M, row0, h0, h1;
  if (blk < WSTRIP) { A = Aw; M = N_WORD; row0 = blk << 6; h0 = 0; h1 = 4; }
  else { A = Ad; M = N_DOC; row0 = (blk - WSTRIP) << 6; h0 = 4; h1 = 6; }
  int stride = K + 8;
  int kd8 = K >> 3;
  int total = kd8 << 6;            // 64 rows * K/8 chunks
  for (int c = threadIdx.x; c < total; c += 256) {
    int row = c >> kd8s;
    int col8 = c & (kd8 - 1);
    int grow = row0 + row; if (grow >= M) grow = M - 1;  // clamp, never stored
    short8 v;
    if (ABF) {
      v = *(const short8*)((const short*)A + (size_t)grow * K + col8 * 8);
    } else {
      const float* a = (const float*)A + (size_t)grow * K + col8 * 8;
      float4 a0 = *(const float4*)a, a1 = *(const float4*)(a + 4);
      v[0] = (short)f2bf(a0.x); v[1] = (short)f2bf(a0.y);
      v[2] = (short)f2bf(a0.z); v[3] = (short)f2bf(a0.w);
      v[4] = (short)f2bf(a1.x); v[5] = (short)f2bf(a1.y);
      v[6] = (short)f2bf(a1.z); v[7] = (short)f2bf(a1.w);
    }
    *(short8*)&As[row * stride + col8 * 8] = v;
  }
  __syncthreads();
  int wid = threadIdx.x >> 6, lane = threadIdx.x & 63;
  int r = lane & 15, quad = lane >> 4;
  int KT = K >> 5;
  int m0 = row0 + wid * 16;
  for (int h = h0; h < h1; ++h) {
    const short* Bp = g.B[h];
    f32x4 acc[8];
#pragma unroll
    for (int nt = 0; nt < 8; ++nt) acc[nt] = (f32x4){0.f, 0.f, 0.f, 0.f};
    for (int kt = 0; kt < KT; ++kt) {
      short8 af = *(const short8*)&As[(wid * 16 + r) * stride + kt * 32 + quad * 8];
      const short* bbase = Bp + ((size_t)kt * 4096) + lane * 8;
#pragma unroll
      for (int nt = 0; nt < 8; ++nt) {
        short8 bf = *(const short8*)(bbase + (size_t)nt * 512);
        acc[nt] = __builtin_amdgcn_mfma_f32_16x16x32_bf16(af, bf, acc[nt], 0, 0, 0);
      }
    }
    // C/D: col = lane&15, row = quad*4 + rr  [m89-verified]
    if ((g.obf >> h) & 1) {
      unsigned short* C = (unsigned short*)g.C[h];
#pragma unroll
      for (int nt = 0; nt < 8; ++nt)
#pragma unroll
        for (int rr = 0; rr < 4; ++rr) {
          int row = m0 + quad * 4 + rr;
          if (row < M) C[(size_t)row * 128 + nt * 16 + r] = f2bf(acc[nt][rr]);
        }
    } else {
      float* C = (float*)g.C[h];
#pragma unroll
      for (int nt = 0; nt < 8; ++nt)
#pragma unroll
        for (int rr = 0; rr < 4; ++rr) {
          int row = m0 + quad * 4 + rr;
          if (row < M) C[(size_t)row * 128 + nt * 16 + r] = acc[nt][rr];
        }
    }
  }
}

// ---------------- weight pack: fp32 [K,128] -> bf16 B-fragment layout --------
// mats: 0:Ws[0]+Ws[1]+Ws[3], 1..4:Wn[0..3], 5:Ws[2]
__global__ void pack_w_kernel(const float* __restrict__ Ws1, const float* __restrict__ Wn1,
                              const float* __restrict__ Ws2, const float* __restrict__ Wn2,
                              short* __restrict__ Bp1, short* __restrict__ Bp2) {
  int tid = blockIdx.x * blockDim.x + threadIdx.x;
  const int L1T = 6 * 4096;
  const int L2T = 6 * 2048;
  if (tid >= L1T + L2T) return;
  const float *src0, *src1 = nullptr, *src2 = nullptr;
  short* dst;
  int kt, nt, lane;
  if (tid < L1T) {
    int mat = tid / 4096, rem = tid % 4096;
    kt = rem / 512; nt = (rem / 64) % 8; lane = rem % 64;
    const int W1 = 256 * 128;
    if (mat == 0) { src0 = Ws1; src1 = Ws1 + W1; src2 = Ws1 + 3 * W1; }
    else if (mat <= 4) src0 = Wn1 + (size_t)(mat - 1) * W1;
    else src0 = Ws1 + 2 * W1;
    dst = Bp1 + (size_t)mat * W1 + ((size_t)(kt * 8 + nt) * 64 + lane) * 8;
  } else {
    int t2 = tid - L1T;
    int mat = t2 / 2048, rem = t2 % 2048;
    kt = rem / 512; nt = (rem / 64) % 8; lane = rem % 64;
    const int W2 = 128 * 128;
    if (mat == 0) { src0 = Ws2; src1 = Ws2 + W2; src2 = Ws2 + 3 * W2; }
    else if (mat <= 4) src0 = Wn2 + (size_t)(mat - 1) * W2;
    else src0 = Ws2 + 2 * W2;
    dst = Bp2 + (size_t)mat * W2 + ((size_t)(kt * 8 + nt) * 64 + lane) * 8;
  }
  int n = nt * 16 + (lane & 15);
  int kb = kt * 32 + (lane >> 4) * 8;
  short8 v;
#pragma unroll
  for (int j = 0; j < 8; ++j) {
    float f = src0[(size_t)(kb + j) * 128 + n];
    if (src1) f += src1[(size_t)(kb + j) * 128 + n] + src2[(size_t)(kb + j) * 128 + n];
    v[j] = (short)f2bf(f);
  }
  *(short8*)dst = v;
}

__global__ void bias_kernel(const float* __restrict__ b1, const float* __restrict__ b2,
                            float* __restrict__ bs1, float* __restrict__ bs2) {
  int t = threadIdx.x;
  if (t < 128) bs1[t] = b1[t] + b1[128 + t] + b1[384 + t];
  else { int u = t - 128; bs2[u] = b2[u] + b2[128 + u] + b2[384 + u]; }
}

// ---------------- CSR build: bucketed counting sort, NO scattered atomics ----
__device__ inline void rel_map(int b, const int* wwd, const int* wwrd, const int* wdrd,
                               const int* wdd, const int*& dst, int& E, int& gbase, int& lb) {
  if (b < NBLK_WW) { dst = wwd; E = E_WW; gbase = 0; lb = b; }
  else if (b < 2 * NBLK_WW) { dst = wwrd; E = E_WW; gbase = NBK_W; lb = b - NBLK_WW; }
  else if (b < 2 * NBLK_WW + NBLK_WD) { dst = wdrd; E = E_WD; gbase = 2 * NBK_W; lb = b - 2 * NBLK_WW; }
  else { dst = wdd; E = E_WD; gbase = 3 * NBK_W; lb = b - 2 * NBLK_WW - NBLK_WD; }
}

__global__ __launch_bounds__(256) void hist_kernel(
    const int* wwd, const int* wwrd, const int* wdrd, const int* wdd, int* btot) {
  __shared__ int h[NBK_W];
  const int* dst; int E, gbase, lb;
  rel_map(blockIdx.x, wwd, wwrd, wdrd, wdd, dst, E, gbase, lb);
  for (int i = threadIdx.x; i < NBK_W; i += 256) h[i] = 0;
  __syncthreads();
  int e0 = lb * EPB;
#pragma unroll
  for (int k = 0; k < EPB / 256; ++k) {
    int i = e0 + k * 256 + threadIdx.x;
    if (i < E) atomicAdd(&h[dst[i] >> 10], 1);
  }
  __syncthreads();
  if (threadIdx.x < NBK_W && h[threadIdx.x])
    atomicAdd(&btot[gbase + threadIdx.x], h[threadIdx.x]);
}

__global__ __launch_bounds__(256) void bscan_kernel(const int* __restrict__ btot,
    int* bbase, int* bcur, int* rp_ww, int* rp_wwr, int* rp_wdr, int* rp_wd) {
  __shared__ int sm[256];
  int tid = threadIdx.x;
  int v = (tid < BKT) ? btot[tid] : 0;
  sm[tid] = v;
  __syncthreads();
  int segbase = tid < NBK_W ? 0 : tid < 2 * NBK_W ? NBK_W
              : tid < 3 * NBK_W ? 2 * NBK_W : tid < BKT ? 3 * NBK_W : BKT;
  for (int off = 1; off < 256; off <<= 1) {
    int add = (tid - off >= segbase) ? sm[tid - off] : 0;
    __syncthreads();
    sm[tid] += add;
    __syncthreads();
  }
  if (tid < BKT) { int ex = sm[tid] - v; bbase[tid] = ex; bcur[tid] = ex; }
  if (tid == 0) rp_ww[N_WORD] = E_WW;
  if (tid == 1) rp_wwr[N_WORD] = E_WW;
  if (tid == 2) rp_wdr[N_WORD] = E_WD;
  if (tid == 3) rp_wd[N_DOC] = E_WD;
}

__global__ __launch_bounds__(256) void bin_kernel(
    const int* wws, const int* wwd, const int* wwrs, const int* wwrd,
    const int* wdrs, const int* wdrd, const int* wds, const int* wdd,
    int* bcur, unsigned* st_ww, unsigned* st_wwr, unsigned* st_wdr, unsigned* st_wd) {
  __shared__ int h[NBK_W], base[NBK_W], cur[NBK_W];
  int b = blockIdx.x;
  const int* dst; int E, gbase, lb;
  rel_map(b, wwd, wwrd, wdrd, wdd, dst, E, gbase, lb);
  const int* src; unsigned* st;
  if (b < NBLK_WW) { src = wws; st = st_ww; }
  else if (b < 2 * NBLK_WW) { src = wwrs; st = st_wwr; }
  else if (b < 2 * NBLK_WW + NBLK_WD) { src = wdrs; st = st_wdr; }
  else { src = wds; st = st_wd; }
  for (int i = threadIdx.x; i < NBK_W; i += 256) h[i] = 0;
  __syncthreads();
  int e0 = lb * EPB;
#pragma unroll
  for (int k = 0; k < EPB / 256; ++k) {
    int i = e0 + k * 256 + threadIdx.x;
    if (i < E) atomicAdd(&h[dst[i] >> 10], 1);
  }
  __syncthreads();
  if (threadIdx.x < NBK_W) {
    base[threadIdx.x] = h[threadIdx.x] ? atomicAdd(&bcur[gbase + threadIdx.x], h[threadIdx.x]) : 0;
    cur[threadIdx.x] = 0;
  }
  __syncthreads();
#pragma unroll
  for (int k = 0; k < EPB / 256; ++k) {
    int i = e0 + k * 256 + threadIdx.x;
    if (i < E) {
      int d = dst[i];
      int bk = d >> 10;
      int l = atomicAdd(&cur[bk], 1);
      st[base[bk] + l] = (unsigned)(src[i] & 0xFFFF) | ((unsigned)(d & (NPB - 1)) << 16);
    }
  }
}

__global__ __launch_bounds__(256) void place_kernel(
    const int* __restrict__ bbase,
    const unsigned* st_ww, const unsigned* st_wwr, const unsigned* st_wdr, const unsigned* st_wd,
    unsigned short* c_ww, unsigned short* c_wwr, unsigned short* c_wdr, unsigned short* c_wd,
    int* rp_ww, int* rp_wwr, int* rp_wdr, int* rp_wd) {
  __shared__ int cnt[NPB], off[NPB], sm[256];
  int g = blockIdx.x;
  const unsigned* st; unsigned short* csr; int* rp; int relFirst, n, E;
  if (g < NBK_W)            { st = st_ww;  csr = c_ww;  rp = rp_ww;  relFirst = 0;          n = N_WORD; E = E_WW; }
  else if (g < 2 * NBK_W)   { st = st_wwr; csr = c_wwr; rp = rp_wwr; relFirst = NBK_W;      n = N_WORD; E = E_WW; }
  else if (g < 3 * NBK_W)   { st = st_wdr; csr = c_wdr; rp = rp_wdr; relFirst = 2 * NBK_W;  n = N_WORD; E = E_WD; }
  else                      { st = st_wd;  csr = c_wd;  rp = rp_wd;  relFirst = 3 * NBK_W;  n = N_DOC;  E = E_WD; }
  int relLast = (g < 3 * NBK_W) ? relFirst + NBK_W - 1 : BKT - 1;
  int node_base = (g - relFirst) << 10;
  int node_cnt = n - node_base; if (node_cnt > NPB) node_cnt = NPB;
  int bstart = bbase[g];
  int bend = (g == relLast) ? E : bbase[g + 1];
  int tid = threadIdx.x;
  for (int i = tid; i < NPB; i += 256) cnt[i] = 0;
  __syncthreads();
  for (int j = bstart + tid; j < bend; j += 256) atomicAdd(&cnt[st[j] >> 16], 1);
  __syncthreads();
  int c[4], s = 0;
#pragma unroll
  for (int jj = 0; jj < 4; ++jj) { c[jj] = cnt[tid * 4 + jj]; s += c[jj]; }
  sm[tid] = s;
  __syncthreads();
  for (int o = 1; o < 256; o <<= 1) {
    int add = (tid >= o) ? sm[tid - o] : 0;
    __syncthreads();
    sm[tid] += add;
    __syncthreads();
  }
  int ex = sm[tid] - s;
#pragma unroll
  for (int jj = 0; jj < 4; ++jj) { off[tid * 4 + jj] = ex; ex += c[jj]; }
  __syncthreads();
#pragma unroll
  for (int jj = 0; jj < 4; ++jj) {
    int i = tid * 4 + jj;
    if (i < node_cnt) rp[node_base + i] = bstart + off[i];
  }
  __syncthreads();
  for (int j = bstart + tid; j < bend; j += 256) {
    unsigned e = st[j];
    int p = atomicAdd(&off[e >> 16], 1);
    csr[bstart + p] = (unsigned short)(e & 0xFFFFu);
  }
}

// ---------------- merged gather (word + doc nodes in one dispatch) -----------
__device__ inline void accum_rel(const unsigned* __restrict__ y,
                                 const unsigned short* __restrict__ csr,
                                 int beg, int end, int lane, float& f0, float& f1) {
  float a0 = 0.f, a1 = 0.f;
  int j = beg;
  for (; j + 3 < end; j += 4) {
    int s0 = csr[j], s1 = csr[j + 1], s2 = csr[j + 2], s3 = csr[j + 3];
    unsigned u0 = y[((size_t)s0 << 6) + lane];
    unsigned u1 = y[((size_t)s1 << 6) + lane];
    unsigned u2 = y[((size_t)s2 << 6) + lane];
    unsigned u3 = y[((size_t)s3 << 6) + lane];
    a0 += __uint_as_float(u0 << 16) + __uint_as_float(u1 << 16)
        + __uint_as_float(u2 << 16) + __uint_as_float(u3 << 16);
    a1 += __uint_as_float(u0 & 0xffff0000u) + __uint_as_float(u1 & 0xffff0000u)
        + __uint_as_float(u2 & 0xffff0000u) + __uint_as_float(u3 & 0xffff0000u);
  }
  for (; j < end; ++j) {
    unsigned u = y[((size_t)csr[j] << 6) + lane];
    a0 += __uint_as_float(u << 16);
    a1 += __uint_as_float(u & 0xffff0000u);
  }
  int deg = end - beg;
  float inv = 1.0f / (float)(deg > 1 ? deg : 1);
  f0 += a0 * inv;
  f1 += a1 * inv;
}

// mode 1: write bf16 activations; mode 2: fused linear+sigmoid readout.
__global__ __launch_bounds__(256) void gather_all(
    const unsigned* __restrict__ y_ww, const unsigned* __restrict__ y_wwr,
    const unsigned* __restrict__ y_wdr, const unsigned* __restrict__ y_wd,
    const unsigned short* __restrict__ c_ww, const unsigned short* __restrict__ c_wwr,
    const unsigned short* __restrict__ c_wdr, const unsigned short* __restrict__ c_wd,
    const int* __restrict__ r_ww, const int* __restrict__ r_wwr,
    const int* __restrict__ r_wdr, const int* __restrict__ r_wd,
    const float* __restrict__ tW, const float* __restrict__ tD,
    const float* __restrict__ bW, const float* __restrict__ bD,
    const float* __restrict__ lw, const float* __restrict__ lb,
    unsigned* __restrict__ oW16, unsigned* __restrict__ oD16,
    float* __restrict__ oF, int mode) {
  int gn = (blockIdx.x << 2) + (threadIdx.x >> 6);
  if (gn >= N_WORD + N_DOC) return;
  int lane = threadIdx.x & 63;
  float f0, f1;
  if (gn < N_WORD) {
    int node = gn;
    float2 tv = ((const float2*)(tW + ((size_t)node << 7)))[lane];
    f0 = tv.x; f1 = tv.y;
    accum_rel(y_ww, c_ww, r_ww[node], r_ww[node + 1], lane, f0, f1);
    accum_rel(y_wwr, c_wwr, r_wwr[node], r_wwr[node + 1], lane, f0, f1);
    accum_rel(y_wdr, c_wdr, r_wdr[node], r_wdr[node + 1], lane, f0, f1);
    float2 bv = ((const float2*)bW)[lane];
    f0 = fmaxf(f0 + bv.x, 0.f);
    f1 = fmaxf(f1 + bv.y, 0.f);
    if (mode == 1) {
      oW16[((size_t)node << 6) + lane] = (unsigned)f2bf(f0) | ((unsigned)f2bf(f1) << 16);
    } else {
      float2 lv = ((const float2*)lw)[lane];
      float s = f0 * lv.x + f1 * lv.y;
#pragma unroll
      for (int off = 32; off > 0; off >>= 1) s += __shfl_xor(s, off);
      if (lane == 0) oF[node] = 1.0f / (1.0f + expf(-(s + lb[0])));
    }
  } else {
    int node = gn - N_WORD;
    float2 tv = ((const float2*)(tD + ((size_t)node << 7)))[lane];
    f0 = tv.x; f1 = tv.y;
    accum_rel(y_wd, c_wd, r_wd[node], r_wd[node + 1], lane, f0, f1);
    float2 bv = ((const float2*)bD)[lane];
    f0 = fmaxf(f0 + bv.x, 0.f);
    f1 = fmaxf(f1 + bv.y, 0.f);
    if (mode == 1) {
      oD16[((size_t)node << 6) + lane] = (unsigned)f2bf(f0) | ((unsigned)f2bf(f1) << 16);
    } else {
      float2 lv = ((const float2*)lw)[lane];
      float s = f0 * lv.x + f1 * lv.y;
#pragma unroll
      for (int off = 32; off > 0; off >>= 1) s += __shfl_xor(s, off);
      if (lane == 0) oF[N_WORD + node] = 1.0f / (1.0f + expf(-(s + lb[0])));
    }
  }
}

// ---------------------------------------------------------------------------
extern "C" void kernel_launch(void* const* d_in, const int* in_sizes, int n_in,
                              void* d_out, int out_size, void* d_ws, size_t ws_size,
                              hipStream_t stream) {
  const float* xw      = (const float*)d_in[0];
  const float* xd      = (const float*)d_in[1];
  const int*   ww_src  = (const int*)d_in[2];
  const int*   ww_dst  = (const int*)d_in[3];
  const int*   wwr_src = (const int*)d_in[4];
  const int*   wwr_dst = (const int*)d_in[5];
  const int*   wd_src  = (const int*)d_in[6];
  const int*   wd_dst  = (const int*)d_in[7];
  const int*   wdr_src = (const int*)d_in[8];
  const int*   wdr_dst = (const int*)d_in[9];
  const float* Ws1     = (const float*)d_in[10];
  const float* Wn1     = (const float*)d_in[11];
  const float* b1      = (const float*)d_in[12];
  const float* Ws2     = (const float*)d_in[13];
  const float* Wn2     = (const float*)d_in[14];
  const float* b2      = (const float*)d_in[15];
  const float* lin_w   = (const float*)d_in[16];
  const float* lin_b   = (const float*)d_in[17];
  float* out = (float*)d_out;

  // ---- workspace carve (~92.8 MB; staging aliases yB0/yB1 pre-GEMM) ----
  char* p = (char*)d_ws;
  auto alloc = [&](size_t nbytes) {
    char* r = p;
    p += (nbytes + 255) & ~(size_t)255;
    return r;
  };
  float* twA  = (float*)alloc((size_t)N_WORD * D_H * 4);
  float* tdA  = (float*)alloc((size_t)N_DOC * D_H * 4);
  unsigned* xw1B = (unsigned*)alloc((size_t)N_WORD * D_H * 2);
  unsigned* xd1B = (unsigned*)alloc((size_t)N_DOC * D_H * 2);
  unsigned* yB0 = (unsigned*)alloc((size_t)N_WORD * D_H * 2);
  unsigned* yB1 = (unsigned*)alloc((size_t)N_WORD * D_H * 2);
  unsigned* yB2 = (unsigned*)alloc((size_t)N_WORD * D_H * 2);
  unsigned* ydB = (unsigned*)alloc((size_t)N_DOC * D_H * 2);
  unsigned short* csr_ww  = (unsigned short*)alloc((size_t)E_WW * 2);
  unsigned short* csr_wwr = (unsigned short*)alloc((size_t)E_WW * 2);
  unsigned short* csr_wdr = (unsigned short*)alloc((size_t)E_WD * 2);
  unsigned short* csr_wd  = (unsigned short*)alloc((size_t)E_WD * 2);
  int* rp_ww  = (int*)alloc((size_t)(N_WORD + 1) * 4);
  int* rp_wwr = (int*)alloc((size_t)(N_WORD + 1) * 4);
  int* rp_wdr = (int*)alloc((size_t)(N_WORD + 1) * 4);
  int* rp_wd  = (int*)alloc((size_t)(N_DOC + 1) * 4);
  short* Bp1 = (short*)alloc((size_t)6 * 256 * 128 * 2);
  short* Bp2 = (short*)alloc((size_t)6 * 128 * 128 * 2);
  int* btot  = (int*)alloc((size_t)BKT * 4);
  int* bbase = (int*)alloc((size_t)BKT * 4);
  int* bcur  = (int*)alloc((size_t)BKT * 4);
  float* bs1 = (float*)alloc(D_H * 4);
  float* bs2 = (float*)alloc(D_H * 4);
  // staging (9 MB) aliased onto yB0/yB1: dead before first GEMM writes them
  unsigned* st_ww  = yB0;
  unsigned* st_wwr = st_ww + E_WW;
  unsigned* st_wdr = (unsigned*)yB1;
  unsigned* st_wd  = st_wdr + E_WD;

  // ---- CSR build: hist -> bucket scan -> bin -> place ----
  hipMemsetAsync(btot, 0, BKT * 4, stream);
  hist_kernel<<<NBLK_TOT, 256, 0, stream>>>(ww_dst, wwr_dst, wdr_dst, wd_dst, btot);
  bscan_kernel<<<1, 256, 0, stream>>>(btot, bbase, bcur, rp_ww, rp_wwr, rp_wdr, rp_wd);
  bin_kernel<<<NBLK_TOT, 256, 0, stream>>>(
      ww_src, ww_dst, wwr_src, wwr_dst, wdr_src, wdr_dst, wd_src, wd_dst,
      bcur, st_ww, st_wwr, st_wdr, st_wd);
  place_kernel<<<BKT, 256, 0, stream>>>(
      bbase, st_ww, st_wwr, st_wdr, st_wd,
      csr_ww, csr_wwr, csr_wdr, csr_wd, rp_ww, rp_wwr, rp_wdr, rp_wd);

  // ---- weight pack + combined biases ----
  pack_w_kernel<<<(6 * 4096 + 6 * 2048 + 255) / 256, 256, 0, stream>>>(
      Ws1, Wn1, Ws2, Wn2, Bp1, Bp2);
  bias_kernel<<<1, 256, 0, stream>>>(b1, b2, bs1, bs2);

  const int W1 = 256 * 128;
  const int W2 = 128 * 128;
  const int NSTRIP = WSTRIP + DSTRIP;

  // ================= layer 1: strip GEMM + merged gather =================
  G6 g1;
  g1.B[0] = Bp1 + 0 * W1; g1.C[0] = twA;   // word self (combined)
  g1.B[1] = Bp1 + 1 * W1; g1.C[1] = yB0;   // ww neigh
  g1.B[2] = Bp1 + 2 * W1; g1.C[2] = yB1;   // wwr neigh
  g1.B[3] = Bp1 + 3 * W1; g1.C[3] = yB2;   // wd neigh (word->doc)
  g1.B[4] = Bp1 + 5 * W1; g1.C[4] = tdA;   // doc self
  g1.B[5] = Bp1 + 4 * W1; g1.C[5] = ydB;   // wdr neigh (doc->word)
  g1.obf = 0x2E;                            // bf16 out: heads 1,2,3,5
  gemm_strip<0><<<NSTRIP, 256, 0, stream>>>(xw, xd, g1, 256, 5);
  gather_all<<<(N_WORD + N_DOC + 3) / 4, 256, 0, stream>>>(
      yB0, yB1, ydB, yB2, csr_ww, csr_wwr, csr_wdr, csr_wd,
      rp_ww, rp_wwr, rp_wdr, rp_wd, twA, tdA, bs1, b1 + 256,
      lin_w, lin_b, xw1B, xd1B, nullptr, 1);

  // ================= layer 2: strip GEMM + merged gather (readout) =========
  G6 g2;
  g2.B[0] = Bp2 + 0 * W2; g2.C[0] = twA;
  g2.B[1] = Bp2 + 1 * W2; g2.C[1] = yB0;
  g2.B[2] = Bp2 + 2 * W2; g2.C[2] = yB1;
  g2.B[3] = Bp2 + 3 * W2; g2.C[3] = yB2;
  g2.B[4] = Bp2 + 5 * W2; g2.C[4] = tdA;
  g2.B[5] = Bp2 + 4 * W2; g2.C[5] = ydB;
  g2.obf = 0x2E;
  gemm_strip<1><<<NSTRIP, 256, 0, stream>>>(xw1B, xd1B, g2, 128, 4);
  gather_all<<<(N_WORD + N_DOC + 3) / 4, 256, 0, stream>>>(
      yB0, yB1, ydB, yB2, csr_ww, csr_wwr, csr_wdr, csr_wd,
      rp_ww, rp_wwr, rp_wdr, rp_wd, twA, tdA, bs2, b2 + 256,
      lin_w, lin_b, nullptr, nullptr, out, 2);
}

// Round 9
// 479.408 us; speedup vs baseline: 1.6891x; 1.0883x over previous
//
#include <hip/hip_runtime.h>
#include <math.h>

#define N_WORD 50000
#define N_DOC  10000
#define E_WW   800000
#define E_WD   320000
#define D_IN   256
#define D_H    128

#define NPB    1024           // nodes per bucket
#define NBK_W  49             // ceil(50000/1024)
#define NBK_D  10             // ceil(10000/1024)
#define BKT    (3 * NBK_W + NBK_D)   // 157 buckets total
#define EPB    8192           // edges per block in bin
#define NBLK_WW 98
#define NBLK_WD 40
#define NBLK_TOT (2 * NBLK_WW + 2 * NBLK_WD)

// fixed per-bucket staging capacity (mean + >16 sigma for binomial counts)
// ww/wwr: dst=word, 49 buckets, mean 16327, sigma ~127
// wdr:    dst=word, 49 buckets, mean  6531, sigma ~80   (round-8 bug: had wd's cap)
// wd:     dst=doc,  10 buckets, mean 32000, sigma ~170  (round-8 bug: had wdr's cap)
#define CAP_WW  18432
#define CAP_WDR 8192
#define CAP_WD  34816

#define WSTRIP ((N_WORD + 63) / 64)  // 782
#define DSTRIP ((N_DOC + 63) / 64)   // 157

typedef __attribute__((ext_vector_type(8))) short short8;
typedef __attribute__((ext_vector_type(4))) float f32x4;

__device__ inline unsigned short f2bf(float f) {  // fp32 -> bf16 bits, RNE
  unsigned u = __float_as_uint(f);
  u = (u + 0x7fffu + ((u >> 16) & 1u)) >> 16;
  return (unsigned short)u;
}

// ---------------- strip GEMM: stage A once in LDS, run all heads on it ------
// Block owns a 64-row strip. Word strips run heads 0..3, doc strips 4..5.
// All outputs bf16 (self-term t included — one extra rounding, within budget).
struct G6 { const short* B[6]; unsigned short* C[6]; };

template <int ABF>
__global__ __launch_bounds__(256) void gemm_strip(
    const void* __restrict__ Aw, const void* __restrict__ Ad,
    G6 g, int K, int kd8s) {
  __shared__ short As[64 * 264];   // max K=256: 64*(256+8) shorts = 33.8 KB
  int blk = blockIdx.x;
  const void* A; int M, row0, h0, h1;
  if (blk < WSTRIP) { A = Aw; M = N_WORD; row0 = blk << 6; h0 = 0; h1 = 4; }
  else { A = Ad; M = N_DOC; row0 = (blk - WSTRIP) << 6; h0 = 4; h1 = 6; }
  int stride = K + 8;
  int kd8 = K >> 3;
  int total = kd8 << 6;            // 64 rows * K/8 chunks
  for (int c = threadIdx.x; c < total; c += 256) {
    int row = c >> kd8s;
    int col8 = c & (kd8 - 1);
    int grow = row0 + row; if (grow >= M) grow = M - 1;  // clamp, never stored
    short8 v;
    if (ABF) {
      v = *(const short8*)((const short*)A + (size_t)grow * K + col8 * 8);
    } else {
      const float* a = (const float*)A + (size_t)grow * K + col8 * 8;
      float4 a0 = *(const float4*)a, a1 = *(const float4*)(a + 4);
      v[0] = (short)f2bf(a0.x); v[1] = (short)f2bf(a0.y);
      v[2] = (short)f2bf(a0.z); v[3] = (short)f2bf(a0.w);
      v[4] = (short)f2bf(a1.x); v[5] = (short)f2bf(a1.y);
      v[6] = (short)f2bf(a1.z); v[7] = (short)f2bf(a1.w);
    }
    *(short8*)&As[row * stride + col8 * 8] = v;
  }
  __syncthreads();
  int wid = threadIdx.x >> 6, lane = threadIdx.x & 63;
  int r = lane & 15, quad = lane >> 4;
  int KT = K >> 5;
  int m0 = row0 + wid * 16;
  for (int h = h0; h < h1; ++h) {
    const short* Bp = g.B[h];
    f32x4 acc[8];
#pragma unroll
    for (int nt = 0; nt < 8; ++nt) acc[nt] = (f32x4){0.f, 0.f, 0.f, 0.f};
    for (int kt = 0; kt < KT; ++kt) {
      short8 af = *(const short8*)&As[(wid * 16 + r) * stride + kt * 32 + quad * 8];
      const short* bbase = Bp + ((size_t)kt * 4096) + lane * 8;
#pragma unroll
      for (int nt = 0; nt < 8; ++nt) {
        short8 bf = *(const short8*)(bbase + (size_t)nt * 512);
        acc[nt] = __builtin_amdgcn_mfma_f32_16x16x32_bf16(af, bf, acc[nt], 0, 0, 0);
      }
    }
    // C/D: col = lane&15, row = quad*4 + rr  [m89-verified]
    unsigned short* C = g.C[h];
#pragma unroll
    for (int nt = 0; nt < 8; ++nt)
#pragma unroll
      for (int rr = 0; rr < 4; ++rr) {
        int row = m0 + quad * 4 + rr;
        if (row < M) C[(size_t)row * 128 + nt * 16 + r] = f2bf(acc[nt][rr]);
      }
  }
}

// ---------------- weight pack (+ fused bias combine) ------------------------
// mats: 0:Ws[0]+Ws[1]+Ws[3], 1..4:Wn[0..3], 5:Ws[2]
__global__ void pack_w_kernel(const float* __restrict__ Ws1, const float* __restrict__ Wn1,
                              const float* __restrict__ Ws2, const float* __restrict__ Wn2,
                              short* __restrict__ Bp1, short* __restrict__ Bp2,
                              const float* __restrict__ b1, const float* __restrict__ b2,
                              float* __restrict__ bs1, float* __restrict__ bs2) {
  int tid = blockIdx.x * blockDim.x + threadIdx.x;
  const int L1T = 6 * 4096;
  const int L2T = 6 * 2048;
  if (tid >= L1T + L2T) {            // tail block: bias combine
    int t = tid - (L1T + L2T);
    if (t < 128) bs1[t] = b1[t] + b1[128 + t] + b1[384 + t];
    else if (t < 256) { int u = t - 128; bs2[u] = b2[u] + b2[128 + u] + b2[384 + u]; }
    return;
  }
  const float *src0, *src1 = nullptr, *src2 = nullptr;
  short* dst;
  int kt, nt, lane;
  if (tid < L1T) {
    int mat = tid / 4096, rem = tid % 4096;
    kt = rem / 512; nt = (rem / 64) % 8; lane = rem % 64;
    const int W1 = 256 * 128;
    if (mat == 0) { src0 = Ws1; src1 = Ws1 + W1; src2 = Ws1 + 3 * W1; }
    else if (mat <= 4) src0 = Wn1 + (size_t)(mat - 1) * W1;
    else src0 = Ws1 + 2 * W1;
    dst = Bp1 + (size_t)mat * W1 + ((size_t)(kt * 8 + nt) * 64 + lane) * 8;
  } else {
    int t2 = tid - L1T;
    int mat = t2 / 2048, rem = t2 % 2048;
    kt = rem / 512; nt = (rem / 64) % 8; lane = rem % 64;
    const int W2 = 128 * 128;
    if (mat == 0) { src0 = Ws2; src1 = Ws2 + W2; src2 = Ws2 + 3 * W2; }
    else if (mat <= 4) src0 = Wn2 + (size_t)(mat - 1) * W2;
    else src0 = Ws2 + 2 * W2;
    dst = Bp2 + (size_t)mat * W2 + ((size_t)(kt * 8 + nt) * 64 + lane) * 8;
  }
  int n = nt * 16 + (lane & 15);
  int kb = kt * 32 + (lane >> 4) * 8;
  short8 v;
#pragma unroll
  for (int j = 0; j < 8; ++j) {
    float f = src0[(size_t)(kb + j) * 128 + n];
    if (src1) f += src1[(size_t)(kb + j) * 128 + n] + src2[(size_t)(kb + j) * 128 + n];
    v[j] = (short)f2bf(f);
  }
  *(short8*)dst = v;
}

// ---------------- CSR build: bin (fixed-cap staging) -> bscan -> place -------
__device__ inline void rel_map(int b, const int* wwd, const int* wwrd, const int* wdrd,
                               const int* wdd, const int*& dst, int& E, int& gbase, int& lb) {
  if (b < NBLK_WW) { dst = wwd; E = E_WW; gbase = 0; lb = b; }
  else if (b < 2 * NBLK_WW) { dst = wwrd; E = E_WW; gbase = NBK_W; lb = b - NBLK_WW; }
  else if (b < 2 * NBLK_WW + NBLK_WD) { dst = wdrd; E = E_WD; gbase = 2 * NBK_W; lb = b - 2 * NBLK_WW; }
  else { dst = wdd; E = E_WD; gbase = 3 * NBK_W; lb = b - 2 * NBLK_WW - NBLK_WD; }
}

// bin: LDS histogram -> reserve bucket run via global cursor -> staged write
// into per-bucket fixed-capacity window (coalesced runs, no scattered atomics)
__global__ __launch_bounds__(256) void bin_kernel(
    const int* wws, const int* wwd, const int* wwrs, const int* wwrd,
    const int* wdrs, const int* wdrd, const int* wds, const int* wdd,
    int* bcnt, unsigned* st_ww, unsigned* st_wwr, unsigned* st_wdr, unsigned* st_wd) {
  __shared__ int h[NBK_W], base[NBK_W], cur[NBK_W];
  int b = blockIdx.x;
  const int* dst; int E, gbase, lb;
  rel_map(b, wwd, wwrd, wdrd, wdd, dst, E, gbase, lb);
  const int* src; unsigned* st; int cap;
  if (b < NBLK_WW) { src = wws; st = st_ww; cap = CAP_WW; }
  else if (b < 2 * NBLK_WW) { src = wwrs; st = st_wwr; cap = CAP_WW; }
  else if (b < 2 * NBLK_WW + NBLK_WD) { src = wdrs; st = st_wdr; cap = CAP_WDR; }
  else { src = wds; st = st_wd; cap = CAP_WD; }
  for (int i = threadIdx.x; i < NBK_W; i += 256) h[i] = 0;
  __syncthreads();
  int e0 = lb * EPB;
#pragma unroll
  for (int k = 0; k < EPB / 256; ++k) {
    int i = e0 + k * 256 + threadIdx.x;
    if (i < E) atomicAdd(&h[dst[i] >> 10], 1);
  }
  __syncthreads();
  if (threadIdx.x < NBK_W) {
    base[threadIdx.x] = h[threadIdx.x] ? atomicAdd(&bcnt[gbase + threadIdx.x], h[threadIdx.x]) : 0;
    cur[threadIdx.x] = 0;
  }
  __syncthreads();
#pragma unroll
  for (int k = 0; k < EPB / 256; ++k) {
    int i = e0 + k * 256 + threadIdx.x;
    if (i < E) {
      int d = dst[i];
      int bk = d >> 10;
      int l = atomicAdd(&cur[bk], 1);
      st[(size_t)bk * cap + base[bk] + l] =
          (unsigned)(src[i] & 0xFFFF) | ((unsigned)(d & (NPB - 1)) << 16);
    }
  }
}

// segmented exclusive scan of final bucket counts -> dense CSR bases
__global__ __launch_bounds__(256) void bscan_kernel(const int* __restrict__ bcnt,
    int* bbase, int* rp_ww, int* rp_wwr, int* rp_wdr, int* rp_wd) {
  __shared__ int sm[256];
  int tid = threadIdx.x;
  int v = (tid < BKT) ? bcnt[tid] : 0;
  sm[tid] = v;
  __syncthreads();
  int segbase = tid < NBK_W ? 0 : tid < 2 * NBK_W ? NBK_W
              : tid < 3 * NBK_W ? 2 * NBK_W : tid < BKT ? 3 * NBK_W : BKT;
  for (int off = 1; off < 256; off <<= 1) {
    int add = (tid - off >= segbase) ? sm[tid - off] : 0;
    __syncthreads();
    sm[tid] += add;
    __syncthreads();
  }
  if (tid < BKT) bbase[tid] = sm[tid] - v;
  if (tid == 0) rp_ww[N_WORD] = E_WW;
  if (tid == 1) rp_wwr[N_WORD] = E_WW;
  if (tid == 2) rp_wdr[N_WORD] = E_WD;
  if (tid == 3) rp_wd[N_DOC] = E_WD;
}

// one block per bucket: per-node LDS count+scan -> rp, place into private
// contiguous csr window (single-XCD line completion)
__global__ __launch_bounds__(256) void place_kernel(
    const int* __restrict__ bcnt, const int* __restrict__ bbase,
    const unsigned* st_ww, const unsigned* st_wwr, const unsigned* st_wdr, const unsigned* st_wd,
    unsigned short* c_ww, unsigned short* c_wwr, unsigned short* c_wdr, unsigned short* c_wd,
    int* rp_ww, int* rp_wwr, int* rp_wdr, int* rp_wd) {
  __shared__ int cnt[NPB], off[NPB], sm[256];
  int g = blockIdx.x;
  const unsigned* st; unsigned short* csr; int* rp; int relFirst, n, cap;
  if (g < NBK_W)            { st = st_ww;  csr = c_ww;  rp = rp_ww;  relFirst = 0;         n = N_WORD; cap = CAP_WW; }
  else if (g < 2 * NBK_W)   { st = st_wwr; csr = c_wwr; rp = rp_wwr; relFirst = NBK_W;     n = N_WORD; cap = CAP_WW; }
  else if (g < 3 * NBK_W)   { st = st_wdr; csr = c_wdr; rp = rp_wdr; relFirst = 2 * NBK_W; n = N_WORD; cap = CAP_WDR; }
  else                      { st = st_wd;  csr = c_wd;  rp = rp_wd;  relFirst = 3 * NBK_W; n = N_DOC;  cap = CAP_WD; }
  int cb = g - relFirst;
  int node_base = cb << 10;
  int node_cnt = n - node_base; if (node_cnt > NPB) node_cnt = NPB;
  int ecnt = bcnt[g];
  int bstart = bbase[g];
  const unsigned* w = st + (size_t)cb * cap;
  int tid = threadIdx.x;
  for (int i = tid; i < NPB; i += 256) cnt[i] = 0;
  __syncthreads();
  for (int j = tid; j < ecnt; j += 256) atomicAdd(&cnt[w[j] >> 16], 1);
  __syncthreads();
  int c[4], s = 0;
#pragma unroll
  for (int jj = 0; jj < 4; ++jj) { c[jj] = cnt[tid * 4 + jj]; s += c[jj]; }
  sm[tid] = s;
  __syncthreads();
  for (int o = 1; o < 256; o <<= 1) {
    int add = (tid >= o) ? sm[tid - o] : 0;
    __syncthreads();
    sm[tid] += add;
    __syncthreads();
  }
  int ex = sm[tid] - s;
#pragma unroll
  for (int jj = 0; jj < 4; ++jj) { off[tid * 4 + jj] = ex; ex += c[jj]; }
  __syncthreads();
#pragma unroll
  for (int jj = 0; jj < 4; ++jj) {
    int i = tid * 4 + jj;
    if (i < node_cnt) rp[node_base + i] = bstart + off[i];
  }
  __syncthreads();
  for (int j = tid; j < ecnt; j += 256) {
    unsigned e = w[j];
    int p = atomicAdd(&off[e >> 16], 1);
    csr[bstart + p] = (unsigned short)(e & 0xFFFFu);
  }
}

// ---------------- merged gather: shfl-broadcast indices, 8-deep MLP ----------
__device__ inline void accum_rel(const unsigned* __restrict__ y,
                                 const unsigned short* __restrict__ csr,
                                 int beg, int end, int lane, float& f0, float& f1) {
  float a0 = 0.f, a1 = 0.f;
  for (int base = beg; base < end; base += 64) {
    int cnt = end - base; if (cnt > 64) cnt = 64;
    int ld = base + lane; if (ld >= end) ld = end - 1;
    int idx = csr[ld];                 // 64 indices per coalesced 128B load
    int j = 0;
    for (; j + 7 < cnt; j += 8) {      // 8 loads in flight
      unsigned u[8];
#pragma unroll
      for (int k = 0; k < 8; ++k) {
        int s = __shfl(idx, j + k);
        u[k] = y[((size_t)s << 6) + lane];
      }
#pragma unroll
      for (int k = 0; k < 8; ++k) {
        a0 += __uint_as_float(u[k] << 16);
        a1 += __uint_as_float(u[k] & 0xffff0000u);
      }
    }
    for (; j < cnt; ++j) {
      int s = __shfl(idx, j);
      unsigned uu = y[((size_t)s << 6) + lane];
      a0 += __uint_as_float(uu << 16);
      a1 += __uint_as_float(uu & 0xffff0000u);
    }
  }
  int deg = end - beg;
  float inv = 1.0f / (float)(deg > 1 ? deg : 1);
  f0 += a0 * inv;
  f1 += a1 * inv;
}

// mode 1: write bf16 activations; mode 2: fused linear+sigmoid readout.
__global__ __launch_bounds__(256) void gather_all(
    const unsigned* __restrict__ y_ww, const unsigned* __restrict__ y_wwr,
    const unsigned* __restrict__ y_wdr, const unsigned* __restrict__ y_wd,
    const unsigned short* __restrict__ c_ww, const unsigned short* __restrict__ c_wwr,
    const unsigned short* __restrict__ c_wdr, const unsigned short* __restrict__ c_wd,
    const int* __restrict__ r_ww, const int* __restrict__ r_wwr,
    const int* __restrict__ r_wdr, const int* __restrict__ r_wd,
    const unsigned* __restrict__ tW, const unsigned* __restrict__ tD,
    const float* __restrict__ bW, const float* __restrict__ bD,
    const float* __restrict__ lw, const float* __restrict__ lb,
    unsigned* __restrict__ oW16, unsigned* __restrict__ oD16,
    float* __restrict__ oF, int mode) {
  int gn = (blockIdx.x << 2) + (threadIdx.x >> 6);
  if (gn >= N_WORD + N_DOC) return;
  int lane = threadIdx.x & 63;
  float f0, f1;
  if (gn < N_WORD) {
    int node = gn;
    unsigned tu = tW[((size_t)node << 6) + lane];     // bf16 self term
    f0 = __uint_as_float(tu << 16);
    f1 = __uint_as_float(tu & 0xffff0000u);
    accum_rel(y_ww, c_ww, r_ww[node], r_ww[node + 1], lane, f0, f1);
    accum_rel(y_wwr, c_wwr, r_wwr[node], r_wwr[node + 1], lane, f0, f1);
    accum_rel(y_wdr, c_wdr, r_wdr[node], r_wdr[node + 1], lane, f0, f1);
    float2 bv = ((const float2*)bW)[lane];
    f0 = fmaxf(f0 + bv.x, 0.f);
    f1 = fmaxf(f1 + bv.y, 0.f);
    if (mode == 1) {
      oW16[((size_t)node << 6) + lane] = (unsigned)f2bf(f0) | ((unsigned)f2bf(f1) << 16);
    } else {
      float2 lv = ((const float2*)lw)[lane];
      float s = f0 * lv.x + f1 * lv.y;
#pragma unroll
      for (int off = 32; off > 0; off >>= 1) s += __shfl_xor(s, off);
      if (lane == 0) oF[node] = 1.0f / (1.0f + expf(-(s + lb[0])));
    }
  } else {
    int node = gn - N_WORD;
    unsigned tu = tD[((size_t)node << 6) + lane];
    f0 = __uint_as_float(tu << 16);
    f1 = __uint_as_float(tu & 0xffff0000u);
    accum_rel(y_wd, c_wd, r_wd[node], r_wd[node + 1], lane, f0, f1);
    float2 bv = ((const float2*)bD)[lane];
    f0 = fmaxf(f0 + bv.x, 0.f);
    f1 = fmaxf(f1 + bv.y, 0.f);
    if (mode == 1) {
      oD16[((size_t)node << 6) + lane] = (unsigned)f2bf(f0) | ((unsigned)f2bf(f1) << 16);
    } else {
      float2 lv = ((const float2*)lw)[lane];
      float s = f0 * lv.x + f1 * lv.y;
#pragma unroll
      for (int off = 32; off > 0; off >>= 1) s += __shfl_xor(s, off);
      if (lane == 0) oF[N_WORD + node] = 1.0f / (1.0f + expf(-(s + lb[0])));
    }
  }
}

// ---------------------------------------------------------------------------
extern "C" void kernel_launch(void* const* d_in, const int* in_sizes, int n_in,
                              void* d_out, int out_size, void* d_ws, size_t ws_size,
                              hipStream_t stream) {
  const float* xw      = (const float*)d_in[0];
  const float* xd      = (const float*)d_in[1];
  const int*   ww_src  = (const int*)d_in[2];
  const int*   ww_dst  = (const int*)d_in[3];
  const int*   wwr_src = (const int*)d_in[4];
  const int*   wwr_dst = (const int*)d_in[5];
  const int*   wd_src  = (const int*)d_in[6];
  const int*   wd_dst  = (const int*)d_in[7];
  const int*   wdr_src = (const int*)d_in[8];
  const int*   wdr_dst = (const int*)d_in[9];
  const float* Ws1     = (const float*)d_in[10];
  const float* Wn1     = (const float*)d_in[11];
  const float* b1      = (const float*)d_in[12];
  const float* Ws2     = (const float*)d_in[13];
  const float* Wn2     = (const float*)d_in[14];
  const float* b2      = (const float*)d_in[15];
  const float* lin_w   = (const float*)d_in[16];
  const float* lin_b   = (const float*)d_in[17];
  float* out = (float*)d_out;

  // ---- workspace carve (~70 MB; staging aliases yB0/yB1 pre-GEMM) ----
  char* p = (char*)d_ws;
  auto alloc = [&](size_t nbytes) {
    char* r = p;
    p += (nbytes + 255) & ~(size_t)255;
    return r;
  };
  unsigned* twA  = (unsigned*)alloc((size_t)N_WORD * D_H * 2);  // bf16 self acc
  unsigned* tdA  = (unsigned*)alloc((size_t)N_DOC * D_H * 2);
  unsigned* xw1B = (unsigned*)alloc((size_t)N_WORD * D_H * 2);
  unsigned* xd1B = (unsigned*)alloc((size_t)N_DOC * D_H * 2);
  unsigned* yB0 = (unsigned*)alloc((size_t)N_WORD * D_H * 2);
  unsigned* yB1 = (unsigned*)alloc((size_t)N_WORD * D_H * 2);
  unsigned* yB2 = (unsigned*)alloc((size_t)N_WORD * D_H * 2);
  unsigned* ydB = (unsigned*)alloc((size_t)N_DOC * D_H * 2);
  unsigned short* csr_ww  = (unsigned short*)alloc((size_t)E_WW * 2);
  unsigned short* csr_wwr = (unsigned short*)alloc((size_t)E_WW * 2);
  unsigned short* csr_wdr = (unsigned short*)alloc((size_t)E_WD * 2);
  unsigned short* csr_wd  = (unsigned short*)alloc((size_t)E_WD * 2);
  int* rp_ww  = (int*)alloc((size_t)(N_WORD + 1) * 4);
  int* rp_wwr = (int*)alloc((size_t)(N_WORD + 1) * 4);
  int* rp_wdr = (int*)alloc((size_t)(N_WORD + 1) * 4);
  int* rp_wd  = (int*)alloc((size_t)(N_DOC + 1) * 4);
  short* Bp1 = (short*)alloc((size_t)6 * 256 * 128 * 2);
  short* Bp2 = (short*)alloc((size_t)6 * 128 * 128 * 2);
  int* bcnt  = (int*)alloc((size_t)BKT * 4);
  int* bbase = (int*)alloc((size_t)BKT * 4);
  float* bs1 = (float*)alloc(D_H * 4);
  float* bs2 = (float*)alloc(D_H * 4);
  // staging aliases (dead before GEMM writes yB0/yB1):
  // yB0: ww 49*18432*4 = 3.61MB + wwr 3.61MB = 7.22MB (yB0 is 12.8MB)
  // yB1: wdr 49*8192*4 = 1.61MB + wd 10*34816*4 = 1.39MB = 3.0MB
  unsigned* st_ww  = yB0;
  unsigned* st_wwr = st_ww + (size_t)NBK_W * CAP_WW;
  unsigned* st_wdr = yB1;
  unsigned* st_wd  = st_wdr + (size_t)NBK_W * CAP_WDR;

  // ---- CSR build: bin -> bscan -> place ----
  hipMemsetAsync(bcnt, 0, BKT * 4, stream);
  bin_kernel<<<NBLK_TOT, 256, 0, stream>>>(
      ww_src, ww_dst, wwr_src, wwr_dst, wdr_src, wdr_dst, wd_src, wd_dst,
      bcnt, st_ww, st_wwr, st_wdr, st_wd);
  bscan_kernel<<<1, 256, 0, stream>>>(bcnt, bbase, rp_ww, rp_wwr, rp_wdr, rp_wd);
  place_kernel<<<BKT, 256, 0, stream>>>(
      bcnt, bbase, st_ww, st_wwr, st_wdr, st_wd,
      csr_ww, csr_wwr, csr_wdr, csr_wd, rp_ww, rp_wwr, rp_wdr, rp_wd);

  // ---- weight pack + fused bias combine ----
  pack_w_kernel<<<(6 * 4096 + 6 * 2048 + 256 + 255) / 256, 256, 0, stream>>>(
      Ws1, Wn1, Ws2, Wn2, Bp1, Bp2, b1, b2, bs1, bs2);

  const int W1 = 256 * 128;
  const int W2 = 128 * 128;
  const int NSTRIP = WSTRIP + DSTRIP;

  // ================= layer 1: strip GEMM + merged gather =================
  G6 g1;
  g1.B[0] = Bp1 + 0 * W1; g1.C[0] = (unsigned short*)twA;   // word self
  g1.B[1] = Bp1 + 1 * W1; g1.C[1] = (unsigned short*)yB0;   // ww neigh
  g1.B[2] = Bp1 + 2 * W1; g1.C[2] = (unsigned short*)yB1;   // wwr neigh
  g1.B[3] = Bp1 + 3 * W1; g1.C[3] = (unsigned short*)yB2;   // wd neigh
  g1.B[4] = Bp1 + 5 * W1; g1.C[4] = (unsigned short*)tdA;   // doc self
  g1.B[5] = Bp1 + 4 * W1; g1.C[5] = (unsigned short*)ydB;   // wdr neigh
  gemm_strip<0><<<NSTRIP, 256, 0, stream>>>(xw, xd, g1, 256, 5);
  gather_all<<<(N_WORD + N_DOC + 3) / 4, 256, 0, stream>>>(
      yB0, yB1, ydB, yB2, csr_ww, csr_wwr, csr_wdr, csr_wd,
      rp_ww, rp_wwr, rp_wdr, rp_wd, twA, tdA, bs1, b1 + 256,
      lin_w, lin_b, xw1B, xd1B, nullptr, 1);

  // ================= layer 2: strip GEMM + merged gather (readout) =========
  G6 g2;
  g2.B[0] = Bp2 + 0 * W2; g2.C[0] = (unsigned short*)twA;
  g2.B[1] = Bp2 + 1 * W2; g2.C[1] = (unsigned short*)yB0;
  g2.B[2] = Bp2 + 2 * W2; g2.C[2] = (unsigned short*)yB1;
  g2.B[3] = Bp2 + 3 * W2; g2.C[3] = (unsigned short*)yB2;
  g2.B[4] = Bp2 + 5 * W2; g2.C[4] = (unsigned short*)tdA;
  g2.B[5] = Bp2 + 4 * W2; g2.C[5] = (unsigned short*)ydB;
  gemm_strip<1><<<NSTRIP, 256, 0, stream>>>(xw1B, xd1B, g2, 128, 4);
  gather_all<<<(N_WORD + N_DOC + 3) / 4, 256, 0, stream>>>(
      yB0, yB1, ydB, yB2, csr_ww, csr_wwr, csr_wdr, csr_wd,
      rp_ww, rp_wwr, rp_wdr, rp_wd, twA, tdA, bs2, b2 + 256,
      lin_w, lin_b, nullptr, nullptr, out, 2);
}

// Round 10
// 464.591 us; speedup vs baseline: 1.7430x; 1.0319x over previous
//
#include <hip/hip_runtime.h>
#include <math.h>

#define N_WORD 50000
#define N_DOC  10000
#define E_WW   800000
#define E_WD   320000
#define D_IN   256
#define D_H    128

#define NPB    1024           // nodes per bucket
#define NBK_W  49             // ceil(50000/1024)
#define NBK_D  10             // ceil(10000/1024)
#define BKT    (3 * NBK_W + NBK_D)   // 157 buckets total
#define EPB    8192           // edges per block in bin
#define NBLK_WW 98
#define NBLK_WD 40
#define NBLK_TOT (2 * NBLK_WW + 2 * NBLK_WD)
#define PACK_BLKS ((6 * 4096 + 6 * 2048 + 256 + 255) / 256)   // 145

// fixed per-bucket staging capacity (mean + >10 sigma for binomial counts)
// ww/wwr: dst=word, 49 buckets, mean 16327; wdr: dst=word, mean 6531;
// wd: dst=doc, 10 buckets, mean 32000.
#define CAP_WW  18432
#define CAP_WDR 8192
#define CAP_WD  34816

#define WSTRIP ((N_WORD + 63) / 64)  // 782
#define DSTRIP ((N_DOC + 63) / 64)   // 157

typedef __attribute__((ext_vector_type(8))) short short8;
typedef __attribute__((ext_vector_type(4))) float f32x4;

__device__ inline unsigned short f2bf(float f) {  // fp32 -> bf16 bits, RNE
  unsigned u = __float_as_uint(f);
  u = (u + 0x7fffu + ((u >> 16) & 1u)) >> 16;
  return (unsigned short)u;
}

// ---------------- strip GEMM: stage A once in LDS, run all heads on it ------
struct G6 { const short* B[6]; unsigned short* C[6]; };

template <int ABF>
__global__ __launch_bounds__(256) void gemm_strip(
    const void* __restrict__ Aw, const void* __restrict__ Ad,
    G6 g, int K, int kd8s) {
  __shared__ short As[64 * 264];   // max K=256: 64*(256+8) shorts = 33.8 KB
  int blk = blockIdx.x;
  const void* A; int M, row0, h0, h1;
  if (blk < WSTRIP) { A = Aw; M = N_WORD; row0 = blk << 6; h0 = 0; h1 = 4; }
  else { A = Ad; M = N_DOC; row0 = (blk - WSTRIP) << 6; h0 = 4; h1 = 6; }
  int stride = K + 8;
  int kd8 = K >> 3;
  int total = kd8 << 6;            // 64 rows * K/8 chunks
  for (int c = threadIdx.x; c < total; c += 256) {
    int row = c >> kd8s;
    int col8 = c & (kd8 - 1);
    int grow = row0 + row; if (grow >= M) grow = M - 1;  // clamp, never stored
    short8 v;
    if (ABF) {
      v = *(const short8*)((const short*)A + (size_t)grow * K + col8 * 8);
    } else {
      const float* a = (const float*)A + (size_t)grow * K + col8 * 8;
      float4 a0 = *(const float4*)a, a1 = *(const float4*)(a + 4);
      v[0] = (short)f2bf(a0.x); v[1] = (short)f2bf(a0.y);
      v[2] = (short)f2bf(a0.z); v[3] = (short)f2bf(a0.w);
      v[4] = (short)f2bf(a1.x); v[5] = (short)f2bf(a1.y);
      v[6] = (short)f2bf(a1.z); v[7] = (short)f2bf(a1.w);
    }
    *(short8*)&As[row * stride + col8 * 8] = v;
  }
  __syncthreads();
  int wid = threadIdx.x >> 6, lane = threadIdx.x & 63;
  int r = lane & 15, quad = lane >> 4;
  int KT = K >> 5;
  int m0 = row0 + wid * 16;
  for (int h = h0; h < h1; ++h) {
    const short* Bp = g.B[h];
    f32x4 acc[8];
#pragma unroll
    for (int nt = 0; nt < 8; ++nt) acc[nt] = (f32x4){0.f, 0.f, 0.f, 0.f};
    for (int kt = 0; kt < KT; ++kt) {
      short8 af = *(const short8*)&As[(wid * 16 + r) * stride + kt * 32 + quad * 8];
      const short* bbase = Bp + ((size_t)kt * 4096) + lane * 8;
#pragma unroll
      for (int nt = 0; nt < 8; ++nt) {
        short8 bf = *(const short8*)(bbase + (size_t)nt * 512);
        acc[nt] = __builtin_amdgcn_mfma_f32_16x16x32_bf16(af, bf, acc[nt], 0, 0, 0);
      }
    }
    // C/D: col = lane&15, row = quad*4 + rr  [m89-verified]
    unsigned short* C = g.C[h];
#pragma unroll
    for (int nt = 0; nt < 8; ++nt)
#pragma unroll
      for (int rr = 0; rr < 4; ++rr) {
        int row = m0 + quad * 4 + rr;
        if (row < M) C[(size_t)row * 128 + nt * 16 + r] = f2bf(acc[nt][rr]);
      }
  }
}

// ---------------- fused CSR-bin + weight-pack dispatch -----------------------
// blocks [0, NBLK_TOT): bin edges into staging (per-wave hist/reserve/cursors)
// blocks [NBLK_TOT, NBLK_TOT+PACK_BLKS): pack weights + bias combine
__device__ inline void rel_map(int b, const int* wwd, const int* wwrd, const int* wdrd,
                               const int* wdd, const int*& dst, int& E, int& gbase, int& lb) {
  if (b < NBLK_WW) { dst = wwd; E = E_WW; gbase = 0; lb = b; }
  else if (b < 2 * NBLK_WW) { dst = wwrd; E = E_WW; gbase = NBK_W; lb = b - NBLK_WW; }
  else if (b < 2 * NBLK_WW + NBLK_WD) { dst = wdrd; E = E_WD; gbase = 2 * NBK_W; lb = b - 2 * NBLK_WW; }
  else { dst = wdd; E = E_WD; gbase = 3 * NBK_W; lb = b - 2 * NBLK_WW - NBLK_WD; }
}

__global__ __launch_bounds__(256) void binpack_kernel(
    const int* wws, const int* wwd, const int* wwrs, const int* wwrd,
    const int* wdrs, const int* wdrd, const int* wds, const int* wdd,
    int* bcnt, unsigned* st_ww, unsigned* st_wwr, unsigned* st_wdr, unsigned* st_wd,
    const float* __restrict__ Ws1, const float* __restrict__ Wn1,
    const float* __restrict__ Ws2, const float* __restrict__ Wn2,
    short* __restrict__ Bp1, short* __restrict__ Bp2,
    const float* __restrict__ b1, const float* __restrict__ b2,
    float* __restrict__ bs1, float* __restrict__ bs2) {
  int b = blockIdx.x;
  if (b >= NBLK_TOT) {
    // ---------- pack branch ----------
    int tid = (b - NBLK_TOT) * 256 + threadIdx.x;
    const int L1T = 6 * 4096;
    const int L2T = 6 * 2048;
    if (tid >= L1T + L2T) {          // bias combine tail
      int t = tid - (L1T + L2T);
      if (t < 128) bs1[t] = b1[t] + b1[128 + t] + b1[384 + t];
      else if (t < 256) { int u = t - 128; bs2[u] = b2[u] + b2[128 + u] + b2[384 + u]; }
      return;
    }
    const float *src0, *src1 = nullptr, *src2 = nullptr;
    short* dstp;
    int kt, nt, lane;
    if (tid < L1T) {
      int mat = tid / 4096, rem = tid % 4096;
      kt = rem / 512; nt = (rem / 64) % 8; lane = rem % 64;
      const int W1 = 256 * 128;
      if (mat == 0) { src0 = Ws1; src1 = Ws1 + W1; src2 = Ws1 + 3 * W1; }
      else if (mat <= 4) src0 = Wn1 + (size_t)(mat - 1) * W1;
      else src0 = Ws1 + 2 * W1;
      dstp = Bp1 + (size_t)mat * W1 + ((size_t)(kt * 8 + nt) * 64 + lane) * 8;
    } else {
      int t2 = tid - L1T;
      int mat = t2 / 2048, rem = t2 % 2048;
      kt = rem / 512; nt = (rem / 64) % 8; lane = rem % 64;
      const int W2 = 128 * 128;
      if (mat == 0) { src0 = Ws2; src1 = Ws2 + W2; src2 = Ws2 + 3 * W2; }
      else if (mat <= 4) src0 = Wn2 + (size_t)(mat - 1) * W2;
      else src0 = Ws2 + 2 * W2;
      dstp = Bp2 + (size_t)mat * W2 + ((size_t)(kt * 8 + nt) * 64 + lane) * 8;
    }
    int n = nt * 16 + (lane & 15);
    int kb = kt * 32 + (lane >> 4) * 8;
    short8 v;
#pragma unroll
    for (int j = 0; j < 8; ++j) {
      float f = src0[(size_t)(kb + j) * 128 + n];
      if (src1) f += src1[(size_t)(kb + j) * 128 + n] + src2[(size_t)(kb + j) * 128 + n];
      v[j] = (short)f2bf(f);
    }
    *(short8*)dstp = v;
    return;
  }
  // ---------- bin branch: per-wave hist -> per-wave reservation -> scatter ---
  __shared__ int h[4][64], wb[4][64], cur[4][64];
  const int* dst; int E, gbase, lb;
  rel_map(b, wwd, wwrd, wdrd, wdd, dst, E, gbase, lb);
  const int* src; unsigned* st; int cap;
  if (b < NBLK_WW) { src = wws; st = st_ww; cap = CAP_WW; }
  else if (b < 2 * NBLK_WW) { src = wwrs; st = st_wwr; cap = CAP_WW; }
  else if (b < 2 * NBLK_WW + NBLK_WD) { src = wdrs; st = st_wdr; cap = CAP_WDR; }
  else { src = wds; st = st_wd; cap = CAP_WD; }
  int tid = threadIdx.x;
  int wave = tid >> 6;
  ((int*)h)[tid] = 0;
  ((int*)cur)[tid] = 0;
  __syncthreads();
  int e0 = lb * EPB;
#pragma unroll
  for (int k = 0; k < EPB / 256; ++k) {
    int i = e0 + k * 256 + tid;
    if (i < E) atomicAdd(&h[wave][dst[i] >> 10], 1);
  }
  __syncthreads();
  if (tid < NBK_W) {
    int t0 = h[0][tid], t1 = h[1][tid], t2 = h[2][tid], t3 = h[3][tid];
    int tot = t0 + t1 + t2 + t3;
    int base = tot ? atomicAdd(&bcnt[gbase + tid], tot) : 0;
    wb[0][tid] = base;
    wb[1][tid] = base + t0;
    wb[2][tid] = base + t0 + t1;
    wb[3][tid] = base + t0 + t1 + t2;
  }
  __syncthreads();
#pragma unroll
  for (int k = 0; k < EPB / 256; ++k) {
    int i = e0 + k * 256 + tid;
    if (i < E) {
      int d = dst[i];
      int bk = d >> 10;
      int l = atomicAdd(&cur[wave][bk], 1);
      st[(size_t)bk * cap + wb[wave][bk] + l] =
          (unsigned)(src[i] & 0xFFFF) | ((unsigned)(d & (NPB - 1)) << 16);
    }
  }
}

// one block per bucket: computes its own segment prefix (no bscan kernel),
// per-node LDS count+scan -> rp, place into private contiguous csr window
__global__ __launch_bounds__(256) void place_kernel(
    const int* __restrict__ bcnt,
    const unsigned* st_ww, const unsigned* st_wwr, const unsigned* st_wdr, const unsigned* st_wd,
    unsigned short* c_ww, unsigned short* c_wwr, unsigned short* c_wdr, unsigned short* c_wd,
    int* rp_ww, int* rp_wwr, int* rp_wdr, int* rp_wd) {
  __shared__ int cnt[NPB], off[NPB], sm[256];
  __shared__ int s_bstart;
  int g = blockIdx.x;
  const unsigned* st; unsigned short* csr; int* rp; int relFirst, relLast, n, cap, Etot;
  if (g < NBK_W)            { st = st_ww;  csr = c_ww;  rp = rp_ww;  relFirst = 0;         relLast = NBK_W - 1;     n = N_WORD; cap = CAP_WW;  Etot = E_WW; }
  else if (g < 2 * NBK_W)   { st = st_wwr; csr = c_wwr; rp = rp_wwr; relFirst = NBK_W;     relLast = 2 * NBK_W - 1; n = N_WORD; cap = CAP_WW;  Etot = E_WW; }
  else if (g < 3 * NBK_W)   { st = st_wdr; csr = c_wdr; rp = rp_wdr; relFirst = 2 * NBK_W; relLast = 3 * NBK_W - 1; n = N_WORD; cap = CAP_WDR; Etot = E_WD; }
  else                      { st = st_wd;  csr = c_wd;  rp = rp_wd;  relFirst = 3 * NBK_W; relLast = BKT - 1;       n = N_DOC;  cap = CAP_WD;  Etot = E_WD; }
  int cb = g - relFirst;
  int tid = threadIdx.x;
  // segment-exclusive prefix of bcnt over [relFirst, g) — one wave, <=48 terms
  if (tid < 64) {
    int v = (tid < cb) ? bcnt[relFirst + tid] : 0;
#pragma unroll
    for (int o = 32; o > 0; o >>= 1) v += __shfl_xor(v, o);
    if (tid == 0) s_bstart = v;
  }
  if (g == relLast && tid == 65) rp[n] = Etot;   // tail sentinel (word/doc count)
  int node_base = cb << 10;
  int node_cnt = n - node_base; if (node_cnt > NPB) node_cnt = NPB;
  int ecnt = bcnt[g];
  const unsigned* w = st + (size_t)cb * cap;
  for (int i = tid; i < NPB; i += 256) cnt[i] = 0;
  __syncthreads();
  int bstart = s_bstart;
  for (int j = tid; j < ecnt; j += 256) atomicAdd(&cnt[w[j] >> 16], 1);
  __syncthreads();
  int c[4], s = 0;
#pragma unroll
  for (int jj = 0; jj < 4; ++jj) { c[jj] = cnt[tid * 4 + jj]; s += c[jj]; }
  sm[tid] = s;
  __syncthreads();
  for (int o = 1; o < 256; o <<= 1) {
    int add = (tid >= o) ? sm[tid - o] : 0;
    __syncthreads();
    sm[tid] += add;
    __syncthreads();
  }
  int ex = sm[tid] - s;
#pragma unroll
  for (int jj = 0; jj < 4; ++jj) { off[tid * 4 + jj] = ex; ex += c[jj]; }
  __syncthreads();
#pragma unroll
  for (int jj = 0; jj < 4; ++jj) {
    int i = tid * 4 + jj;
    if (i < node_cnt) rp[node_base + i] = bstart + off[i];
  }
  __syncthreads();
  for (int j = tid; j < ecnt; j += 256) {
    unsigned e = w[j];
    int p = atomicAdd(&off[e >> 16], 1);
    csr[bstart + p] = (unsigned short)(e & 0xFFFFu);
  }
}

// ---------------- merged gather: shfl-broadcast indices, 8-deep MLP ----------
__device__ inline void accum_rel(const unsigned* __restrict__ y,
                                 const unsigned short* __restrict__ csr,
                                 int beg, int end, int lane, float& f0, float& f1) {
  float a0 = 0.f, a1 = 0.f;
  for (int base = beg; base < end; base += 64) {
    int cnt = end - base; if (cnt > 64) cnt = 64;
    int ld = base + lane; if (ld >= end) ld = end - 1;
    int idx = csr[ld];                 // 64 indices per coalesced 128B load
    int j = 0;
    for (; j + 7 < cnt; j += 8) {      // 8 loads in flight
      unsigned u[8];
#pragma unroll
      for (int k = 0; k < 8; ++k) {
        int s = __shfl(idx, j + k);
        u[k] = y[((size_t)s << 6) + lane];
      }
#pragma unroll
      for (int k = 0; k < 8; ++k) {
        a0 += __uint_as_float(u[k] << 16);
        a1 += __uint_as_float(u[k] & 0xffff0000u);
      }
    }
    for (; j < cnt; ++j) {
      int s = __shfl(idx, j);
      unsigned uu = y[((size_t)s << 6) + lane];
      a0 += __uint_as_float(uu << 16);
      a1 += __uint_as_float(uu & 0xffff0000u);
    }
  }
  int deg = end - beg;
  float inv = 1.0f / (float)(deg > 1 ? deg : 1);
  f0 += a0 * inv;
  f1 += a1 * inv;
}

// mode 1: write bf16 activations; mode 2: fused linear+sigmoid readout.
__global__ __launch_bounds__(256) void gather_all(
    const unsigned* __restrict__ y_ww, const unsigned* __restrict__ y_wwr,
    const unsigned* __restrict__ y_wdr, const unsigned* __restrict__ y_wd,
    const unsigned short* __restrict__ c_ww, const unsigned short* __restrict__ c_wwr,
    const unsigned short* __restrict__ c_wdr, const unsigned short* __restrict__ c_wd,
    const int* __restrict__ r_ww, const int* __restrict__ r_wwr,
    const int* __restrict__ r_wdr, const int* __restrict__ r_wd,
    const unsigned* __restrict__ tW, const unsigned* __restrict__ tD,
    const float* __restrict__ bW, const float* __restrict__ bD,
    const float* __restrict__ lw, const float* __restrict__ lb,
    unsigned* __restrict__ oW16, unsigned* __restrict__ oD16,
    float* __restrict__ oF, int mode) {
  int gn = (blockIdx.x << 2) + (threadIdx.x >> 6);
  if (gn >= N_WORD + N_DOC) return;
  int lane = threadIdx.x & 63;
  float f0, f1;
  if (gn < N_WORD) {
    int node = gn;
    unsigned tu = tW[((size_t)node << 6) + lane];     // bf16 self term
    f0 = __uint_as_float(tu << 16);
    f1 = __uint_as_float(tu & 0xffff0000u);
    accum_rel(y_ww, c_ww, r_ww[node], r_ww[node + 1], lane, f0, f1);
    accum_rel(y_wwr, c_wwr, r_wwr[node], r_wwr[node + 1], lane, f0, f1);
    accum_rel(y_wdr, c_wdr, r_wdr[node], r_wdr[node + 1], lane, f0, f1);
    float2 bv = ((const float2*)bW)[lane];
    f0 = fmaxf(f0 + bv.x, 0.f);
    f1 = fmaxf(f1 + bv.y, 0.f);
    if (mode == 1) {
      oW16[((size_t)node << 6) + lane] = (unsigned)f2bf(f0) | ((unsigned)f2bf(f1) << 16);
    } else {
      float2 lv = ((const float2*)lw)[lane];
      float s = f0 * lv.x + f1 * lv.y;
#pragma unroll
      for (int off = 32; off > 0; off >>= 1) s += __shfl_xor(s, off);
      if (lane == 0) oF[node] = 1.0f / (1.0f + expf(-(s + lb[0])));
    }
  } else {
    int node = gn - N_WORD;
    unsigned tu = tD[((size_t)node << 6) + lane];
    f0 = __uint_as_float(tu << 16);
    f1 = __uint_as_float(tu & 0xffff0000u);
    accum_rel(y_wd, c_wd, r_wd[node], r_wd[node + 1], lane, f0, f1);
    float2 bv = ((const float2*)bD)[lane];
    f0 = fmaxf(f0 + bv.x, 0.f);
    f1 = fmaxf(f1 + bv.y, 0.f);
    if (mode == 1) {
      oD16[((size_t)node << 6) + lane] = (unsigned)f2bf(f0) | ((unsigned)f2bf(f1) << 16);
    } else {
      float2 lv = ((const float2*)lw)[lane];
      float s = f0 * lv.x + f1 * lv.y;
#pragma unroll
      for (int off = 32; off > 0; off >>= 1) s += __shfl_xor(s, off);
      if (lane == 0) oF[N_WORD + node] = 1.0f / (1.0f + expf(-(s + lb[0])));
    }
  }
}

// ---------------------------------------------------------------------------
extern "C" void kernel_launch(void* const* d_in, const int* in_sizes, int n_in,
                              void* d_out, int out_size, void* d_ws, size_t ws_size,
                              hipStream_t stream) {
  const float* xw      = (const float*)d_in[0];
  const float* xd      = (const float*)d_in[1];
  const int*   ww_src  = (const int*)d_in[2];
  const int*   ww_dst  = (const int*)d_in[3];
  const int*   wwr_src = (const int*)d_in[4];
  const int*   wwr_dst = (const int*)d_in[5];
  const int*   wd_src  = (const int*)d_in[6];
  const int*   wd_dst  = (const int*)d_in[7];
  const int*   wdr_src = (const int*)d_in[8];
  const int*   wdr_dst = (const int*)d_in[9];
  const float* Ws1     = (const float*)d_in[10];
  const float* Wn1     = (const float*)d_in[11];
  const float* b1      = (const float*)d_in[12];
  const float* Ws2     = (const float*)d_in[13];
  const float* Wn2     = (const float*)d_in[14];
  const float* b2      = (const float*)d_in[15];
  const float* lin_w   = (const float*)d_in[16];
  const float* lin_b   = (const float*)d_in[17];
  float* out = (float*)d_out;

  // ---- workspace carve (~70 MB; staging aliases yB0/yB1 pre-GEMM) ----
  char* p = (char*)d_ws;
  auto alloc = [&](size_t nbytes) {
    char* r = p;
    p += (nbytes + 255) & ~(size_t)255;
    return r;
  };
  unsigned* twA  = (unsigned*)alloc((size_t)N_WORD * D_H * 2);  // bf16 self acc
  unsigned* tdA  = (unsigned*)alloc((size_t)N_DOC * D_H * 2);
  unsigned* xw1B = (unsigned*)alloc((size_t)N_WORD * D_H * 2);
  unsigned* xd1B = (unsigned*)alloc((size_t)N_DOC * D_H * 2);
  unsigned* yB0 = (unsigned*)alloc((size_t)N_WORD * D_H * 2);
  unsigned* yB1 = (unsigned*)alloc((size_t)N_WORD * D_H * 2);
  unsigned* yB2 = (unsigned*)alloc((size_t)N_WORD * D_H * 2);
  unsigned* ydB = (unsigned*)alloc((size_t)N_DOC * D_H * 2);
  unsigned short* csr_ww  = (unsigned short*)alloc((size_t)E_WW * 2);
  unsigned short* csr_wwr = (unsigned short*)alloc((size_t)E_WW * 2);
  unsigned short* csr_wdr = (unsigned short*)alloc((size_t)E_WD * 2);
  unsigned short* csr_wd  = (unsigned short*)alloc((size_t)E_WD * 2);
  int* rp_ww  = (int*)alloc((size_t)(N_WORD + 1) * 4);
  int* rp_wwr = (int*)alloc((size_t)(N_WORD + 1) * 4);
  int* rp_wdr = (int*)alloc((size_t)(N_WORD + 1) * 4);
  int* rp_wd  = (int*)alloc((size_t)(N_DOC + 1) * 4);
  short* Bp1 = (short*)alloc((size_t)6 * 256 * 128 * 2);
  short* Bp2 = (short*)alloc((size_t)6 * 128 * 128 * 2);
  int* bcnt  = (int*)alloc((size_t)BKT * 4);
  float* bs1 = (float*)alloc(D_H * 4);
  float* bs2 = (float*)alloc(D_H * 4);
  // staging aliases (dead before GEMM writes yB0/yB1):
  // yB0: ww 49*18432*4 = 3.61MB + wwr 3.61MB = 7.22MB (yB0 is 12.8MB)
  // yB1: wdr 49*8192*4 = 1.61MB + wd 10*34816*4 = 1.39MB = 3.0MB
  unsigned* st_ww  = yB0;
  unsigned* st_wwr = st_ww + (size_t)NBK_W * CAP_WW;
  unsigned* st_wdr = yB1;
  unsigned* st_wd  = st_wdr + (size_t)NBK_W * CAP_WDR;

  // ---- CSR build + weight pack: memset -> [bin|pack] -> place ----
  hipMemsetAsync(bcnt, 0, BKT * 4, stream);
  binpack_kernel<<<NBLK_TOT + PACK_BLKS, 256, 0, stream>>>(
      ww_src, ww_dst, wwr_src, wwr_dst, wdr_src, wdr_dst, wd_src, wd_dst,
      bcnt, st_ww, st_wwr, st_wdr, st_wd,
      Ws1, Wn1, Ws2, Wn2, Bp1, Bp2, b1, b2, bs1, bs2);
  place_kernel<<<BKT, 256, 0, stream>>>(
      bcnt, st_ww, st_wwr, st_wdr, st_wd,
      csr_ww, csr_wwr, csr_wdr, csr_wd, rp_ww, rp_wwr, rp_wdr, rp_wd);

  const int W1 = 256 * 128;
  const int W2 = 128 * 128;
  const int NSTRIP = WSTRIP + DSTRIP;

  // ================= layer 1: strip GEMM + merged gather =================
  G6 g1;
  g1.B[0] = Bp1 + 0 * W1; g1.C[0] = (unsigned short*)twA;   // word self
  g1.B[1] = Bp1 + 1 * W1; g1.C[1] = (unsigned short*)yB0;   // ww neigh
  g1.B[2] = Bp1 + 2 * W1; g1.C[2] = (unsigned short*)yB1;   // wwr neigh
  g1.B[3] = Bp1 + 3 * W1; g1.C[3] = (unsigned short*)yB2;   // wd neigh
  g1.B[4] = Bp1 + 5 * W1; g1.C[4] = (unsigned short*)tdA;   // doc self
  g1.B[5] = Bp1 + 4 * W1; g1.C[5] = (unsigned short*)ydB;   // wdr neigh
  gemm_strip<0><<<NSTRIP, 256, 0, stream>>>(xw, xd, g1, 256, 5);
  gather_all<<<(N_WORD + N_DOC + 3) / 4, 256, 0, stream>>>(
      yB0, yB1, ydB, yB2, csr_ww, csr_wwr, csr_wdr, csr_wd,
      rp_ww, rp_wwr, rp_wdr, rp_wd, twA, tdA, bs1, b1 + 256,
      lin_w, lin_b, xw1B, xd1B, nullptr, 1);

  // ================= layer 2: strip GEMM + merged gather (readout) =========
  G6 g2;
  g2.B[0] = Bp2 + 0 * W2; g2.C[0] = (unsigned short*)twA;
  g2.B[1] = Bp2 + 1 * W2; g2.C[1] = (unsigned short*)yB0;
  g2.B[2] = Bp2 + 2 * W2; g2.C[2] = (unsigned short*)yB1;
  g2.B[3] = Bp2 + 3 * W2; g2.C[3] = (unsigned short*)yB2;
  g2.B[4] = Bp2 + 5 * W2; g2.C[4] = (unsigned short*)tdA;
  g2.B[5] = Bp2 + 4 * W2; g2.C[5] = (unsigned short*)ydB;
  gemm_strip<1><<<NSTRIP, 256, 0, stream>>>(xw1B, xd1B, g2, 128, 4);
  gather_all<<<(N_WORD + N_DOC + 3) / 4, 256, 0, stream>>>(
      yB0, yB1, ydB, yB2, csr_ww, csr_wwr, csr_wdr, csr_wd,
      rp_ww, rp_wwr, rp_wdr, rp_wd, twA, tdA, bs2, b2 + 256,
      lin_w, lin_b, nullptr, nullptr, out, 2);
}

// Round 11
// 443.167 us; speedup vs baseline: 1.8272x; 1.0483x over previous
//
#include <hip/hip_runtime.h>
#include <math.h>

#define N_WORD 50000
#define N_DOC  10000
#define E_WW   800000
#define E_WD   320000
#define D_IN   256
#define D_H    128

#define NPB    1024           // nodes per bucket
#define NBK_W  49             // ceil(50000/1024)
#define NBK_D  10             // ceil(10000/1024)
#define BKT    (3 * NBK_W + NBK_D)   // 157 buckets total
#define EPB    4096           // edges per block in bin (r11: 8192->4096, 2x blocks)
#define NBLK_WW 196           // ceil(800000/4096)
#define NBLK_WD 79            // ceil(320000/4096)
#define NBLK_TOT (2 * NBLK_WW + 2 * NBLK_WD)   // 550
#define PACK_BLKS 145         // 6*4096 + 6*2048 + 256 threads, /256

// fixed per-bucket staging capacity (mean + >10 sigma)
#define CAP_WW  18432
#define CAP_WDR 8192
#define CAP_WD  34816

#define WSTRIP ((N_WORD + 63) / 64)  // 782
#define DSTRIP ((N_DOC + 63) / 64)   // 157
#define NSTRIP (WSTRIP + DSTRIP)     // 939

typedef __attribute__((ext_vector_type(8))) short short8;
typedef __attribute__((ext_vector_type(4))) float f32x4;

__device__ inline unsigned short f2bf(float f) {  // fp32 -> bf16 bits, RNE
  unsigned u = __float_as_uint(f);
  u = (u + 0x7fffu + ((u >> 16) & 1u)) >> 16;
  return (unsigned short)u;
}

// ---------------- GEMM body: stage A strip in LDS, run all heads on it ------
struct G6 { const short* B[6]; unsigned short* C[6]; };

template <int ABF, int K>
__device__ void gemm_body(const void* __restrict__ Aw, const void* __restrict__ Ad,
                          const G6& g, int blk, short* As) {
  constexpr int kd8s = (K == 256) ? 5 : 4;
  constexpr int stride = K + 8;
  constexpr int kd8 = K >> 3;
  const void* A; int M, row0, h0, h1;
  if (blk < WSTRIP) { A = Aw; M = N_WORD; row0 = blk << 6; h0 = 0; h1 = 4; }
  else { A = Ad; M = N_DOC; row0 = (blk - WSTRIP) << 6; h0 = 4; h1 = 6; }
  constexpr int total = kd8 << 6;
  for (int c = threadIdx.x; c < total; c += 256) {
    int row = c >> kd8s;
    int col8 = c & (kd8 - 1);
    int grow = row0 + row; if (grow >= M) grow = M - 1;  // clamp, never stored
    short8 v;
    if (ABF) {
      v = *(const short8*)((const short*)A + (size_t)grow * K + col8 * 8);
    } else {
      const float* a = (const float*)A + (size_t)grow * K + col8 * 8;
      float4 a0 = *(const float4*)a, a1 = *(const float4*)(a + 4);
      v[0] = (short)f2bf(a0.x); v[1] = (short)f2bf(a0.y);
      v[2] = (short)f2bf(a0.z); v[3] = (short)f2bf(a0.w);
      v[4] = (short)f2bf(a1.x); v[5] = (short)f2bf(a1.y);
      v[6] = (short)f2bf(a1.z); v[7] = (short)f2bf(a1.w);
    }
    *(short8*)&As[row * stride + col8 * 8] = v;
  }
  __syncthreads();
  int wid = threadIdx.x >> 6, lane = threadIdx.x & 63;
  int r = lane & 15, quad = lane >> 4;
  constexpr int KT = K >> 5;
  int m0 = row0 + wid * 16;
  for (int h = h0; h < h1; ++h) {
    const short* Bp = g.B[h];
    f32x4 acc[8];
#pragma unroll
    for (int nt = 0; nt < 8; ++nt) acc[nt] = (f32x4){0.f, 0.f, 0.f, 0.f};
    for (int kt = 0; kt < KT; ++kt) {
      short8 af = *(const short8*)&As[(wid * 16 + r) * stride + kt * 32 + quad * 8];
      const short* bbase = Bp + ((size_t)kt * 4096) + lane * 8;
#pragma unroll
      for (int nt = 0; nt < 8; ++nt) {
        short8 bf = *(const short8*)(bbase + (size_t)nt * 512);
        acc[nt] = __builtin_amdgcn_mfma_f32_16x16x32_bf16(af, bf, acc[nt], 0, 0, 0);
      }
    }
    // C/D: col = lane&15, row = quad*4 + rr  [m89-verified]
    unsigned short* C = g.C[h];
#pragma unroll
    for (int nt = 0; nt < 8; ++nt)
#pragma unroll
      for (int rr = 0; rr < 4; ++rr) {
        int row = m0 + quad * 4 + rr;
        if (row < M) C[(size_t)row * 128 + nt * 16 + r] = f2bf(acc[nt][rr]);
      }
  }
}

// ---------------- place body (shared-memory passed in) -----------------------
struct CSRB {
  const unsigned *st_ww, *st_wwr, *st_wdr, *st_wd;
  unsigned short *c_ww, *c_wwr, *c_wdr, *c_wd;
  int *rp_ww, *rp_wwr, *rp_wdr, *rp_wd;
  const int* bcnt;
};

__device__ void place_body(int g, const CSRB& q, char* smem) {
  int* cnt = (int*)smem;            // NPB
  int* off = cnt + NPB;             // NPB
  int* sm  = off + NPB;             // 256
  int* s_b = sm + 256;              // 1
  const unsigned* st; unsigned short* csr; int* rp; int relFirst, relLast, n, cap, Etot;
  if (g < NBK_W)            { st = q.st_ww;  csr = q.c_ww;  rp = q.rp_ww;  relFirst = 0;         relLast = NBK_W - 1;     n = N_WORD; cap = CAP_WW;  Etot = E_WW; }
  else if (g < 2 * NBK_W)   { st = q.st_wwr; csr = q.c_wwr; rp = q.rp_wwr; relFirst = NBK_W;     relLast = 2 * NBK_W - 1; n = N_WORD; cap = CAP_WW;  Etot = E_WW; }
  else if (g < 3 * NBK_W)   { st = q.st_wdr; csr = q.c_wdr; rp = q.rp_wdr; relFirst = 2 * NBK_W; relLast = 3 * NBK_W - 1; n = N_WORD; cap = CAP_WDR; Etot = E_WD; }
  else                      { st = q.st_wd;  csr = q.c_wd;  rp = q.rp_wd;  relFirst = 3 * NBK_W; relLast = BKT - 1;       n = N_DOC;  cap = CAP_WD;  Etot = E_WD; }
  int cb = g - relFirst;
  int tid = threadIdx.x;
  // segment-exclusive prefix of bcnt over [relFirst, g) — one wave, <=48 terms
  if (tid < 64) {
    int v = (tid < cb) ? q.bcnt[relFirst + tid] : 0;
#pragma unroll
    for (int o = 32; o > 0; o >>= 1) v += __shfl_xor(v, o);
    if (tid == 0) s_b[0] = v;
  }
  if (g == relLast && tid == 65) rp[n] = Etot;   // tail sentinel
  int node_base = cb << 10;
  int node_cnt = n - node_base; if (node_cnt > NPB) node_cnt = NPB;
  int ecnt = q.bcnt[g];
  const unsigned* w = st + (size_t)cb * cap;
  for (int i = tid; i < NPB; i += 256) cnt[i] = 0;
  __syncthreads();
  int bstart = s_b[0];
  for (int j = tid; j < ecnt; j += 256) atomicAdd(&cnt[w[j] >> 16], 1);
  __syncthreads();
  int c[4], s = 0;
#pragma unroll
  for (int jj = 0; jj < 4; ++jj) { c[jj] = cnt[tid * 4 + jj]; s += c[jj]; }
  sm[tid] = s;
  __syncthreads();
  for (int o = 1; o < 256; o <<= 1) {
    int add = (tid >= o) ? sm[tid - o] : 0;
    __syncthreads();
    sm[tid] += add;
    __syncthreads();
  }
  int ex = sm[tid] - s;
#pragma unroll
  for (int jj = 0; jj < 4; ++jj) { off[tid * 4 + jj] = ex; ex += c[jj]; }
  __syncthreads();
#pragma unroll
  for (int jj = 0; jj < 4; ++jj) {
    int i = tid * 4 + jj;
    if (i < node_cnt) rp[node_base + i] = bstart + off[i];
  }
  __syncthreads();
  for (int j = tid; j < ecnt; j += 256) {
    unsigned e = w[j];
    int p = atomicAdd(&off[e >> 16], 1);
    csr[bstart + p] = (unsigned short)(e & 0xFFFFu);
  }
}

// ---------------- fused dispatches -------------------------------------------
// layer-1 GEMM (939 blocks) || place (157 blocks): independent, both pre-gather1
__global__ __launch_bounds__(256) void gemm1_place(
    const float* __restrict__ Aw, const float* __restrict__ Ad, G6 g, CSRB q) {
  __shared__ char smem[64 * 264 * 2];   // gemm K=256 strip; place uses 9.2KB of it
  if (blockIdx.x < NSTRIP) gemm_body<0, 256>(Aw, Ad, g, blockIdx.x, (short*)smem);
  else place_body(blockIdx.x - NSTRIP, q, smem);
}

__global__ __launch_bounds__(256) void gemm2_kernel(
    const void* __restrict__ Aw, const void* __restrict__ Ad, G6 g) {
  __shared__ short As[64 * 136];        // K=128: 17.4 KB -> better occupancy
  gemm_body<1, 128>(Aw, Ad, g, blockIdx.x, As);
}

// ---------------- fused CSR-bin + weight-pack dispatch -----------------------
__device__ inline void rel_map(int b, const int* wwd, const int* wwrd, const int* wdrd,
                               const int* wdd, const int*& dst, int& E, int& gbase, int& lb) {
  if (b < NBLK_WW) { dst = wwd; E = E_WW; gbase = 0; lb = b; }
  else if (b < 2 * NBLK_WW) { dst = wwrd; E = E_WW; gbase = NBK_W; lb = b - NBLK_WW; }
  else if (b < 2 * NBLK_WW + NBLK_WD) { dst = wdrd; E = E_WD; gbase = 2 * NBK_W; lb = b - 2 * NBLK_WW; }
  else { dst = wdd; E = E_WD; gbase = 3 * NBK_W; lb = b - 2 * NBLK_WW - NBLK_WD; }
}

__global__ __launch_bounds__(256) void binpack_kernel(
    const int* wws, const int* wwd, const int* wwrs, const int* wwrd,
    const int* wdrs, const int* wdrd, const int* wds, const int* wdd,
    int* bcnt, unsigned* st_ww, unsigned* st_wwr, unsigned* st_wdr, unsigned* st_wd,
    const float* __restrict__ Ws1, const float* __restrict__ Wn1,
    const float* __restrict__ Ws2, const float* __restrict__ Wn2,
    short* __restrict__ Bp1, short* __restrict__ Bp2,
    const float* __restrict__ b1, const float* __restrict__ b2,
    float* __restrict__ bs1, float* __restrict__ bs2) {
  int b = blockIdx.x;
  if (b >= NBLK_TOT) {
    // ---------- pack branch ----------
    int tid = (b - NBLK_TOT) * 256 + threadIdx.x;
    const int L1T = 6 * 4096;
    const int L2T = 6 * 2048;
    if (tid >= L1T + L2T) {          // bias combine tail
      int t = tid - (L1T + L2T);
      if (t < 128) bs1[t] = b1[t] + b1[128 + t] + b1[384 + t];
      else if (t < 256) { int u = t - 128; bs2[u] = b2[u] + b2[128 + u] + b2[384 + u]; }
      return;
    }
    const float *src0, *src1 = nullptr, *src2 = nullptr;
    short* dstp;
    int kt, nt, lane;
    if (tid < L1T) {
      int mat = tid / 4096, rem = tid % 4096;
      kt = rem / 512; nt = (rem / 64) % 8; lane = rem % 64;
      const int W1 = 256 * 128;
      if (mat == 0) { src0 = Ws1; src1 = Ws1 + W1; src2 = Ws1 + 3 * W1; }
      else if (mat <= 4) src0 = Wn1 + (size_t)(mat - 1) * W1;
      else src0 = Ws1 + 2 * W1;
      dstp = Bp1 + (size_t)mat * W1 + ((size_t)(kt * 8 + nt) * 64 + lane) * 8;
    } else {
      int t2 = tid - L1T;
      int mat = t2 / 2048, rem = t2 % 2048;
      kt = rem / 512; nt = (rem / 64) % 8; lane = rem % 64;
      const int W2 = 128 * 128;
      if (mat == 0) { src0 = Ws2; src1 = Ws2 + W2; src2 = Ws2 + 3 * W2; }
      else if (mat <= 4) src0 = Wn2 + (size_t)(mat - 1) * W2;
      else src0 = Ws2 + 2 * W2;
      dstp = Bp2 + (size_t)mat * W2 + ((size_t)(kt * 8 + nt) * 64 + lane) * 8;
    }
    int n = nt * 16 + (lane & 15);
    int kb = kt * 32 + (lane >> 4) * 8;
    short8 v;
#pragma unroll
    for (int j = 0; j < 8; ++j) {
      float f = src0[(size_t)(kb + j) * 128 + n];
      if (src1) f += src1[(size_t)(kb + j) * 128 + n] + src2[(size_t)(kb + j) * 128 + n];
      v[j] = (short)f2bf(f);
    }
    *(short8*)dstp = v;
    return;
  }
  // ---------- bin branch: per-wave hist -> per-wave reservation -> scatter ---
  __shared__ int h[4][64], wb[4][64], cur[4][64];
  const int* dst; int E, gbase, lb;
  rel_map(b, wwd, wwrd, wdrd, wdd, dst, E, gbase, lb);
  const int* src; unsigned* st; int cap;
  if (b < NBLK_WW) { src = wws; st = st_ww; cap = CAP_WW; }
  else if (b < 2 * NBLK_WW) { src = wwrs; st = st_wwr; cap = CAP_WW; }
  else if (b < 2 * NBLK_WW + NBLK_WD) { src = wdrs; st = st_wdr; cap = CAP_WDR; }
  else { src = wds; st = st_wd; cap = CAP_WD; }
  int tid = threadIdx.x;
  int wave = tid >> 6;
  ((int*)h)[tid] = 0;
  ((int*)cur)[tid] = 0;
  __syncthreads();
  int e0 = lb * EPB;
#pragma unroll
  for (int k = 0; k < EPB / 256; ++k) {
    int i = e0 + k * 256 + tid;
    if (i < E) atomicAdd(&h[wave][dst[i] >> 10], 1);
  }
  __syncthreads();
  if (tid < NBK_W) {
    int t0 = h[0][tid], t1 = h[1][tid], t2 = h[2][tid], t3 = h[3][tid];
    int tot = t0 + t1 + t2 + t3;
    int base = tot ? atomicAdd(&bcnt[gbase + tid], tot) : 0;
    wb[0][tid] = base;
    wb[1][tid] = base + t0;
    wb[2][tid] = base + t0 + t1;
    wb[3][tid] = base + t0 + t1 + t2;
  }
  __syncthreads();
#pragma unroll
  for (int k = 0; k < EPB / 256; ++k) {
    int i = e0 + k * 256 + tid;
    if (i < E) {
      int d = dst[i];
      int bk = d >> 10;
      int l = atomicAdd(&cur[wave][bk], 1);
      st[(size_t)bk * cap + wb[wave][bk] + l] =
          (unsigned)(src[i] & 0xFFFF) | ((unsigned)(d & (NPB - 1)) << 16);
    }
  }
}

// ---------------- merged gather: readlane scalar-base loads, 8-deep MLP ------
__device__ inline void accum_rel(const unsigned* __restrict__ y,
                                 const unsigned short* __restrict__ csr,
                                 int beg, int end, int lane, float& f0, float& f1) {
  float a0 = 0.f, a1 = 0.f;
  for (int base = beg; base < end; base += 64) {
    int cnt = end - base; if (cnt > 64) cnt = 64;
    int ld = base + lane; if (ld >= end) ld = end - 1;
    int idx = csr[ld];                 // 64 indices per coalesced 128B load
    int j = 0;
    for (; j + 7 < cnt; j += 8) {      // 8 loads in flight
      unsigned u[8];
#pragma unroll
      for (int k = 0; k < 8; ++k) {
        int s = __builtin_amdgcn_readlane(idx, j + k);   // SGPR row -> scalar base
        u[k] = y[((size_t)s << 6) + lane];
      }
#pragma unroll
      for (int k = 0; k < 8; ++k) {
        a0 += __uint_as_float(u[k] << 16);
        a1 += __uint_as_float(u[k] & 0xffff0000u);
      }
    }
    for (; j < cnt; ++j) {
      int s = __builtin_amdgcn_readlane(idx, j);
      unsigned uu = y[((size_t)s << 6) + lane];
      a0 += __uint_as_float(uu << 16);
      a1 += __uint_as_float(uu & 0xffff0000u);
    }
  }
  int deg = end - beg;
  float inv = 1.0f / (float)(deg > 1 ? deg : 1);
  f0 += a0 * inv;
  f1 += a1 * inv;
}

// mode 1: write bf16 activations; mode 2: fused linear+sigmoid readout.
__global__ __launch_bounds__(256) void gather_all(
    const unsigned* __restrict__ y_ww, const unsigned* __restrict__ y_wwr,
    const unsigned* __restrict__ y_wdr, const unsigned* __restrict__ y_wd,
    const unsigned short* __restrict__ c_ww, const unsigned short* __restrict__ c_wwr,
    const unsigned short* __restrict__ c_wdr, const unsigned short* __restrict__ c_wd,
    const int* __restrict__ r_ww, const int* __restrict__ r_wwr,
    const int* __restrict__ r_wdr, const int* __restrict__ r_wd,
    const unsigned* __restrict__ tW, const unsigned* __restrict__ tD,
    const float* __restrict__ bW, const float* __restrict__ bD,
    const float* __restrict__ lw, const float* __restrict__ lb,
    unsigned* __restrict__ oW16, unsigned* __restrict__ oD16,
    float* __restrict__ oF, int mode) {
  int gn = (blockIdx.x << 2) + (threadIdx.x >> 6);
  if (gn >= N_WORD + N_DOC) return;
  int lane = threadIdx.x & 63;
  float f0, f1;
  if (gn < N_WORD) {
    int node = gn;
    unsigned tu = tW[((size_t)node << 6) + lane];     // bf16 self term
    f0 = __uint_as_float(tu << 16);
    f1 = __uint_as_float(tu & 0xffff0000u);
    accum_rel(y_ww, c_ww, r_ww[node], r_ww[node + 1], lane, f0, f1);
    accum_rel(y_wwr, c_wwr, r_wwr[node], r_wwr[node + 1], lane, f0, f1);
    accum_rel(y_wdr, c_wdr, r_wdr[node], r_wdr[node + 1], lane, f0, f1);
    float2 bv = ((const float2*)bW)[lane];
    f0 = fmaxf(f0 + bv.x, 0.f);
    f1 = fmaxf(f1 + bv.y, 0.f);
    if (mode == 1) {
      oW16[((size_t)node << 6) + lane] = (unsigned)f2bf(f0) | ((unsigned)f2bf(f1) << 16);
    } else {
      float2 lv = ((const float2*)lw)[lane];
      float s = f0 * lv.x + f1 * lv.y;
#pragma unroll
      for (int off = 32; off > 0; off >>= 1) s += __shfl_xor(s, off);
      if (lane == 0) oF[node] = 1.0f / (1.0f + expf(-(s + lb[0])));
    }
  } else {
    int node = gn - N_WORD;
    unsigned tu = tD[((size_t)node << 6) + lane];
    f0 = __uint_as_float(tu << 16);
    f1 = __uint_as_float(tu & 0xffff0000u);
    accum_rel(y_wd, c_wd, r_wd[node], r_wd[node + 1], lane, f0, f1);
    float2 bv = ((const float2*)bD)[lane];
    f0 = fmaxf(f0 + bv.x, 0.f);
    f1 = fmaxf(f1 + bv.y, 0.f);
    if (mode == 1) {
      oD16[((size_t)node << 6) + lane] = (unsigned)f2bf(f0) | ((unsigned)f2bf(f1) << 16);
    } else {
      float2 lv = ((const float2*)lw)[lane];
      float s = f0 * lv.x + f1 * lv.y;
#pragma unroll
      for (int off = 32; off > 0; off >>= 1) s += __shfl_xor(s, off);
      if (lane == 0) oF[N_WORD + node] = 1.0f / (1.0f + expf(-(s + lb[0])));
    }
  }
}

// ---------------------------------------------------------------------------
extern "C" void kernel_launch(void* const* d_in, const int* in_sizes, int n_in,
                              void* d_out, int out_size, void* d_ws, size_t ws_size,
                              hipStream_t stream) {
  const float* xw      = (const float*)d_in[0];
  const float* xd      = (const float*)d_in[1];
  const int*   ww_src  = (const int*)d_in[2];
  const int*   ww_dst  = (const int*)d_in[3];
  const int*   wwr_src = (const int*)d_in[4];
  const int*   wwr_dst = (const int*)d_in[5];
  const int*   wd_src  = (const int*)d_in[6];
  const int*   wd_dst  = (const int*)d_in[7];
  const int*   wdr_src = (const int*)d_in[8];
  const int*   wdr_dst = (const int*)d_in[9];
  const float* Ws1     = (const float*)d_in[10];
  const float* Wn1     = (const float*)d_in[11];
  const float* b1      = (const float*)d_in[12];
  const float* Ws2     = (const float*)d_in[13];
  const float* Wn2     = (const float*)d_in[14];
  const float* b2      = (const float*)d_in[15];
  const float* lin_w   = (const float*)d_in[16];
  const float* lin_b   = (const float*)d_in[17];
  float* out = (float*)d_out;

  // ---- workspace carve (~70 MB; staging aliases yB0/yB1 pre-GEMM) ----
  char* p = (char*)d_ws;
  auto alloc = [&](size_t nbytes) {
    char* r = p;
    p += (nbytes + 255) & ~(size_t)255;
    return r;
  };
  unsigned* twA  = (unsigned*)alloc((size_t)N_WORD * D_H * 2);  // bf16 self acc
  unsigned* tdA  = (unsigned*)alloc((size_t)N_DOC * D_H * 2);
  unsigned* xw1B = (unsigned*)alloc((size_t)N_WORD * D_H * 2);
  unsigned* xd1B = (unsigned*)alloc((size_t)N_DOC * D_H * 2);
  unsigned* yB0 = (unsigned*)alloc((size_t)N_WORD * D_H * 2);
  unsigned* yB1 = (unsigned*)alloc((size_t)N_WORD * D_H * 2);
  unsigned* yB2 = (unsigned*)alloc((size_t)N_WORD * D_H * 2);
  unsigned* ydB = (unsigned*)alloc((size_t)N_DOC * D_H * 2);
  unsigned short* csr_ww  = (unsigned short*)alloc((size_t)E_WW * 2);
  unsigned short* csr_wwr = (unsigned short*)alloc((size_t)E_WW * 2);
  unsigned short* csr_wdr = (unsigned short*)alloc((size_t)E_WD * 2);
  unsigned short* csr_wd  = (unsigned short*)alloc((size_t)E_WD * 2);
  int* rp_ww  = (int*)alloc((size_t)(N_WORD + 1) * 4);
  int* rp_wwr = (int*)alloc((size_t)(N_WORD + 1) * 4);
  int* rp_wdr = (int*)alloc((size_t)(N_WORD + 1) * 4);
  int* rp_wd  = (int*)alloc((size_t)(N_DOC + 1) * 4);
  short* Bp1 = (short*)alloc((size_t)6 * 256 * 128 * 2);
  short* Bp2 = (short*)alloc((size_t)6 * 128 * 128 * 2);
  int* bcnt  = (int*)alloc((size_t)BKT * 4);
  float* bs1 = (float*)alloc(D_H * 4);
  float* bs2 = (float*)alloc(D_H * 4);
  // staging aliases (dead before GEMM writes yB0/yB1)
  unsigned* st_ww  = yB0;
  unsigned* st_wwr = st_ww + (size_t)NBK_W * CAP_WW;
  unsigned* st_wdr = yB1;
  unsigned* st_wd  = st_wdr + (size_t)NBK_W * CAP_WDR;

  // ---- CSR bin + weight pack (fused dispatch) ----
  hipMemsetAsync(bcnt, 0, BKT * 4, stream);
  binpack_kernel<<<NBLK_TOT + PACK_BLKS, 256, 0, stream>>>(
      ww_src, ww_dst, wwr_src, wwr_dst, wdr_src, wdr_dst, wd_src, wd_dst,
      bcnt, st_ww, st_wwr, st_wdr, st_wd,
      Ws1, Wn1, Ws2, Wn2, Bp1, Bp2, b1, b2, bs1, bs2);

  const int W1 = 256 * 128;
  const int W2 = 128 * 128;

  // ================= layer 1: [GEMM || place] + merged gather ==============
  G6 g1;
  g1.B[0] = Bp1 + 0 * W1; g1.C[0] = (unsigned short*)twA;   // word self
  g1.B[1] = Bp1 + 1 * W1; g1.C[1] = (unsigned short*)yB0;   // ww neigh
  g1.B[2] = Bp1 + 2 * W1; g1.C[2] = (unsigned short*)yB1;   // wwr neigh
  g1.B[3] = Bp1 + 3 * W1; g1.C[3] = (unsigned short*)yB2;   // wd neigh
  g1.B[4] = Bp1 + 5 * W1; g1.C[4] = (unsigned short*)tdA;   // doc self
  g1.B[5] = Bp1 + 4 * W1; g1.C[5] = (unsigned short*)ydB;   // wdr neigh
  CSRB q;
  q.st_ww = st_ww; q.st_wwr = st_wwr; q.st_wdr = st_wdr; q.st_wd = st_wd;
  q.c_ww = csr_ww; q.c_wwr = csr_wwr; q.c_wdr = csr_wdr; q.c_wd = csr_wd;
  q.rp_ww = rp_ww; q.rp_wwr = rp_wwr; q.rp_wdr = rp_wdr; q.rp_wd = rp_wd;
  q.bcnt = bcnt;
  // NOTE: gemm reads yB0/yB1 aliases? No — gemm WRITES yB0/yB1 (heads 1,2) while
  // place READS staging in yB0/yB1!  -> collision?  Heads 1,2 write yB0/yB1 and
  // place reads st_* which alias yB0/yB1.  This is a true RAW/WAR hazard.
  // Resolution: layer-1 gemm word-head outputs write to xw1B/xd1B-adjacent
  // scratch instead: reuse csr-independent buffers — heads 1,2 -> xw1B区? xw1B
  // is needed only after gather1 writes it.  So: head1 -> xw1B, head2 -> xd1B?
  // xd1B is only 10000*128 — too small.  Instead keep yB2 (no staging alias)
  // for head1, xw1B for head2, and gather1 writes its word output to yB0
  // (staging dead by then).  Mappings below reflect this.
  g1.C[1] = (unsigned short*)yB2;    // ww neigh  (yB2 never aliased staging)
  g1.C[2] = (unsigned short*)xw1B;   // wwr neigh (xw1B free until gather1)
  g1.C[3] = (unsigned short*)twA;    // conflict! twA used by head0...
  // -- final safe mapping: head0(self word)->tdA? also wrong.  Use explicit
  //    scratch: allocate one extra word-sized buffer instead of aliasing golf.
  (void)0;
  // (see yBX alloc below — appended to carve, ws has headroom)
  static_assert(true, "");
  unsigned* yBX = (unsigned*)alloc((size_t)N_WORD * D_H * 2);  // 12.8 MB extra
  g1.C[0] = (unsigned short*)twA;
  g1.C[1] = (unsigned short*)yB2;    // ww
  g1.C[2] = (unsigned short*)xw1B;   // wwr (free until gather1 output)
  g1.C[3] = (unsigned short*)yBX;    // wd
  g1.C[4] = (unsigned short*)tdA;
  g1.C[5] = (unsigned short*)ydB;
  gemm1_place<<<NSTRIP + BKT, 256, 0, stream>>>(xw, xd, g1, q);
  // gather1: word act -> yB0 (staging dead now), doc act -> xd1B
  gather_all<<<(N_WORD + N_DOC + 3) / 4, 256, 0, stream>>>(
      yB2, xw1B, ydB, yBX, csr_ww, csr_wwr, csr_wdr, csr_wd,
      rp_ww, rp_wwr, rp_wdr, rp_wd, twA, tdA, bs1, b1 + 256,
      lin_w, lin_b, yB0, xd1B, nullptr, 1);

  // ================= layer 2: GEMM + merged gather (readout) ===============
  G6 g2;
  g2.B[0] = Bp2 + 0 * W2; g2.C[0] = (unsigned short*)twA;
  g2.B[1] = Bp2 + 1 * W2; g2.C[1] = (unsigned short*)yB2;
  g2.B[2] = Bp2 + 2 * W2; g2.C[2] = (unsigned short*)xw1B;
  g2.B[3] = Bp2 + 3 * W2; g2.C[3] = (unsigned short*)yBX;
  g2.B[4] = Bp2 + 5 * W2; g2.C[4] = (unsigned short*)tdA;
  g2.B[5] = Bp2 + 4 * W2; g2.C[5] = (unsigned short*)ydB;
  gemm2_kernel<<<NSTRIP, 256, 0, stream>>>(yB0, xd1B, g2);
  gather_all<<<(N_WORD + N_DOC + 3) / 4, 256, 0, stream>>>(
      yB2, xw1B, ydB, yBX, csr_ww, csr_wwr, csr_wdr, csr_wd,
      rp_ww, rp_wwr, rp_wdr, rp_wd, twA, tdA, bs2, b2 + 256,
      lin_w, lin_b, nullptr, nullptr, out, 2);
}

// Round 12
// 428.692 us; speedup vs baseline: 1.8889x; 1.0338x over previous
//
#include <hip/hip_runtime.h>
#include <math.h>

#define N_WORD 50000
#define N_DOC  10000
#define E_WW   800000
#define E_WD   320000
#define D_IN   256
#define D_H    128

#define NPB    1024           // nodes per bucket
#define NBK_W  49             // ceil(50000/1024)
#define NBK_D  10             // ceil(10000/1024)
#define BKT    (3 * NBK_W + NBK_D)   // 157 buckets total
#define EPB    4096           // edges per block in bin
#define NBLK_WW 196           // ceil(800000/4096)
#define NBLK_WD 79            // ceil(320000/4096)
#define NBLK_TOT (2 * NBLK_WW + 2 * NBLK_WD)   // 550
#define PACK_BLKS 145

// fixed per-bucket staging capacity (mean + >10 sigma)
#define CAP_WW  18432
#define CAP_WDR 8192
#define CAP_WD  34816

#define WSTRIP ((N_WORD + 63) / 64)  // 782
#define DSTRIP ((N_DOC + 63) / 64)   // 157
#define NSTRIP (WSTRIP + DSTRIP)     // 939

typedef __attribute__((ext_vector_type(8))) short short8;
typedef __attribute__((ext_vector_type(4))) float f32x4;

__device__ inline unsigned short f2bf(float f) {  // fp32 -> bf16 bits, RNE
  unsigned u = __float_as_uint(f);
  u = (u + 0x7fffu + ((u >> 16) & 1u)) >> 16;
  return (unsigned short)u;
}

// ---------------- GEMM body: register-resident A fragments, no LDS ----------
// Wave owns 16 rows; A fragments for the whole K preloaded into afr[] once
// (shared across all heads). B streams from L2. No barriers, waves independent.
struct G6 { const short* B[6]; unsigned short* C[6]; };

template <int ABF, int K>
__device__ void gemm_body(const void* __restrict__ Aw, const void* __restrict__ Ad,
                          const G6& g, int blk) {
  constexpr int KT = K >> 5;
  int wid = threadIdx.x >> 6, lane = threadIdx.x & 63;
  const void* A; int M, row0, h0, h1;
  if (blk < WSTRIP) { A = Aw; M = N_WORD; row0 = blk << 6; h0 = 0; h1 = 4; }
  else { A = Ad; M = N_DOC; row0 = (blk - WSTRIP) << 6; h0 = 4; h1 = 6; }
  int r = lane & 15, quad = lane >> 4;
  int m0 = row0 + wid * 16;
  int mA = m0 + r; if (mA >= M) mA = M - 1;   // clamp: garbage rows never stored
  short8 afr[KT];
  if (ABF) {
    const short* ap = (const short*)A + (size_t)mA * K + quad * 8;
#pragma unroll
    for (int kt = 0; kt < KT; ++kt) afr[kt] = *(const short8*)(ap + kt * 32);
  } else {
    const float* ap = (const float*)A + (size_t)mA * K + quad * 8;
#pragma unroll
    for (int kt = 0; kt < KT; ++kt) {
      float4 a0 = *(const float4*)(ap + kt * 32);
      float4 a1 = *(const float4*)(ap + kt * 32 + 4);
      short8 v;
      v[0] = (short)f2bf(a0.x); v[1] = (short)f2bf(a0.y);
      v[2] = (short)f2bf(a0.z); v[3] = (short)f2bf(a0.w);
      v[4] = (short)f2bf(a1.x); v[5] = (short)f2bf(a1.y);
      v[6] = (short)f2bf(a1.z); v[7] = (short)f2bf(a1.w);
      afr[kt] = v;
    }
  }
  for (int h = h0; h < h1; ++h) {
    const short* Bp = g.B[h];
    f32x4 acc[8];
#pragma unroll
    for (int nt = 0; nt < 8; ++nt) acc[nt] = (f32x4){0.f, 0.f, 0.f, 0.f};
#pragma unroll
    for (int kt = 0; kt < KT; ++kt) {
      const short* bbase = Bp + ((size_t)kt * 4096) + lane * 8;
#pragma unroll
      for (int nt = 0; nt < 8; ++nt) {
        short8 bf = *(const short8*)(bbase + (size_t)nt * 512);
        acc[nt] = __builtin_amdgcn_mfma_f32_16x16x32_bf16(afr[kt], bf, acc[nt], 0, 0, 0);
      }
    }
    // C/D: col = lane&15, row = quad*4 + rr  [m89-verified]
    unsigned short* C = g.C[h];
#pragma unroll
    for (int nt = 0; nt < 8; ++nt)
#pragma unroll
      for (int rr = 0; rr < 4; ++rr) {
        int row = m0 + quad * 4 + rr;
        if (row < M) C[(size_t)row * 128 + nt * 16 + r] = f2bf(acc[nt][rr]);
      }
  }
}

// ---------------- place body (shared-memory passed in) -----------------------
struct CSRB {
  const unsigned *st_ww, *st_wwr, *st_wdr, *st_wd;
  unsigned short *c_ww, *c_wwr, *c_wdr, *c_wd;
  int *rp_ww, *rp_wwr, *rp_wdr, *rp_wd;
  const int* bcnt;
};

__device__ void place_body(int g, const CSRB& q, int* smem) {
  int* cnt = smem;                  // NPB
  int* off = cnt + NPB;             // NPB
  int* sm  = off + NPB;             // 256
  int* s_b = sm + 256;              // 1
  const unsigned* st; unsigned short* csr; int* rp; int relFirst, relLast, n, cap, Etot;
  if (g < NBK_W)            { st = q.st_ww;  csr = q.c_ww;  rp = q.rp_ww;  relFirst = 0;         relLast = NBK_W - 1;     n = N_WORD; cap = CAP_WW;  Etot = E_WW; }
  else if (g < 2 * NBK_W)   { st = q.st_wwr; csr = q.c_wwr; rp = q.rp_wwr; relFirst = NBK_W;     relLast = 2 * NBK_W - 1; n = N_WORD; cap = CAP_WW;  Etot = E_WW; }
  else if (g < 3 * NBK_W)   { st = q.st_wdr; csr = q.c_wdr; rp = q.rp_wdr; relFirst = 2 * NBK_W; relLast = 3 * NBK_W - 1; n = N_WORD; cap = CAP_WDR; Etot = E_WD; }
  else                      { st = q.st_wd;  csr = q.c_wd;  rp = q.rp_wd;  relFirst = 3 * NBK_W; relLast = BKT - 1;       n = N_DOC;  cap = CAP_WD;  Etot = E_WD; }
  int cb = g - relFirst;
  int tid = threadIdx.x;
  // segment-exclusive prefix of bcnt over [relFirst, g) — one wave, <=48 terms
  if (tid < 64) {
    int v = (tid < cb) ? q.bcnt[relFirst + tid] : 0;
#pragma unroll
    for (int o = 32; o > 0; o >>= 1) v += __shfl_xor(v, o);
    if (tid == 0) s_b[0] = v;
  }
  if (g == relLast && tid == 65) rp[n] = Etot;   // tail sentinel
  int node_base = cb << 10;
  int node_cnt = n - node_base; if (node_cnt > NPB) node_cnt = NPB;
  int ecnt = q.bcnt[g];
  const unsigned* w = st + (size_t)cb * cap;
  for (int i = tid; i < NPB; i += 256) cnt[i] = 0;
  __syncthreads();
  int bstart = s_b[0];
  for (int j = tid; j < ecnt; j += 256) atomicAdd(&cnt[w[j] >> 16], 1);
  __syncthreads();
  int c[4], s = 0;
#pragma unroll
  for (int jj = 0; jj < 4; ++jj) { c[jj] = cnt[tid * 4 + jj]; s += c[jj]; }
  sm[tid] = s;
  __syncthreads();
  for (int o = 1; o < 256; o <<= 1) {
    int add = (tid >= o) ? sm[tid - o] : 0;
    __syncthreads();
    sm[tid] += add;
    __syncthreads();
  }
  int ex = sm[tid] - s;
#pragma unroll
  for (int jj = 0; jj < 4; ++jj) { off[tid * 4 + jj] = ex; ex += c[jj]; }
  __syncthreads();
#pragma unroll
  for (int jj = 0; jj < 4; ++jj) {
    int i = tid * 4 + jj;
    if (i < node_cnt) rp[node_base + i] = bstart + off[i];
  }
  __syncthreads();
  for (int j = tid; j < ecnt; j += 256) {
    unsigned e = w[j];
    int p = atomicAdd(&off[e >> 16], 1);
    csr[bstart + p] = (unsigned short)(e & 0xFFFFu);
  }
}

// ---------------- fused dispatches -------------------------------------------
// place blocks FIRST (start immediately, overlap gemm), then layer-1 gemm.
__global__ __launch_bounds__(256, 4) void gemm1_place(
    const float* __restrict__ Aw, const float* __restrict__ Ad, G6 g, CSRB q) {
  __shared__ int smem[NPB * 2 + 256 + 1];   // 9.2 KB (place only; gemm LDS-free)
  if (blockIdx.x < BKT) place_body(blockIdx.x, q, smem);
  else gemm_body<0, 256>(Aw, Ad, g, blockIdx.x - BKT);
}

__global__ __launch_bounds__(256, 4) void gemm2_kernel(
    const void* __restrict__ Aw, const void* __restrict__ Ad, G6 g) {
  gemm_body<1, 128>(Aw, Ad, g, blockIdx.x);
}

// ---------------- fused CSR-bin + weight-pack dispatch -----------------------
__device__ inline void rel_map(int b, const int* wwd, const int* wwrd, const int* wdrd,
                               const int* wdd, const int*& dst, int& E, int& gbase, int& lb) {
  if (b < NBLK_WW) { dst = wwd; E = E_WW; gbase = 0; lb = b; }
  else if (b < 2 * NBLK_WW) { dst = wwrd; E = E_WW; gbase = NBK_W; lb = b - NBLK_WW; }
  else if (b < 2 * NBLK_WW + NBLK_WD) { dst = wdrd; E = E_WD; gbase = 2 * NBK_W; lb = b - 2 * NBLK_WW; }
  else { dst = wdd; E = E_WD; gbase = 3 * NBK_W; lb = b - 2 * NBLK_WW - NBLK_WD; }
}

__global__ __launch_bounds__(256) void binpack_kernel(
    const int* wws, const int* wwd, const int* wwrs, const int* wwrd,
    const int* wdrs, const int* wdrd, const int* wds, const int* wdd,
    int* bcnt, unsigned* st_ww, unsigned* st_wwr, unsigned* st_wdr, unsigned* st_wd,
    const float* __restrict__ Ws1, const float* __restrict__ Wn1,
    const float* __restrict__ Ws2, const float* __restrict__ Wn2,
    short* __restrict__ Bp1, short* __restrict__ Bp2,
    const float* __restrict__ b1, const float* __restrict__ b2,
    float* __restrict__ bs1, float* __restrict__ bs2) {
  int b = blockIdx.x;
  if (b >= NBLK_TOT) {
    // ---------- pack branch ----------
    int tid = (b - NBLK_TOT) * 256 + threadIdx.x;
    const int L1T = 6 * 4096;
    const int L2T = 6 * 2048;
    if (tid >= L1T + L2T) {          // bias combine tail
      int t = tid - (L1T + L2T);
      if (t < 128) bs1[t] = b1[t] + b1[128 + t] + b1[384 + t];
      else if (t < 256) { int u = t - 128; bs2[u] = b2[u] + b2[128 + u] + b2[384 + u]; }
      return;
    }
    const float *src0, *src1 = nullptr, *src2 = nullptr;
    short* dstp;
    int kt, nt, lane;
    if (tid < L1T) {
      int mat = tid / 4096, rem = tid % 4096;
      kt = rem / 512; nt = (rem / 64) % 8; lane = rem % 64;
      const int W1 = 256 * 128;
      if (mat == 0) { src0 = Ws1; src1 = Ws1 + W1; src2 = Ws1 + 3 * W1; }
      else if (mat <= 4) src0 = Wn1 + (size_t)(mat - 1) * W1;
      else src0 = Ws1 + 2 * W1;
      dstp = Bp1 + (size_t)mat * W1 + ((size_t)(kt * 8 + nt) * 64 + lane) * 8;
    } else {
      int t2 = tid - L1T;
      int mat = t2 / 2048, rem = t2 % 2048;
      kt = rem / 512; nt = (rem / 64) % 8; lane = rem % 64;
      const int W2 = 128 * 128;
      if (mat == 0) { src0 = Ws2; src1 = Ws2 + W2; src2 = Ws2 + 3 * W2; }
      else if (mat <= 4) src0 = Wn2 + (size_t)(mat - 1) * W2;
      else src0 = Ws2 + 2 * W2;
      dstp = Bp2 + (size_t)mat * W2 + ((size_t)(kt * 8 + nt) * 64 + lane) * 8;
    }
    int n = nt * 16 + (lane & 15);
    int kb = kt * 32 + (lane >> 4) * 8;
    short8 v;
#pragma unroll
    for (int j = 0; j < 8; ++j) {
      float f = src0[(size_t)(kb + j) * 128 + n];
      if (src1) f += src1[(size_t)(kb + j) * 128 + n] + src2[(size_t)(kb + j) * 128 + n];
      v[j] = (short)f2bf(f);
    }
    *(short8*)dstp = v;
    return;
  }
  // ---------- bin branch: per-wave hist -> per-wave reservation -> scatter ---
  __shared__ int h[4][64], wb[4][64], cur[4][64];
  const int* dst; int E, gbase, lb;
  rel_map(b, wwd, wwrd, wdrd, wdd, dst, E, gbase, lb);
  const int* src; unsigned* st; int cap;
  if (b < NBLK_WW) { src = wws; st = st_ww; cap = CAP_WW; }
  else if (b < 2 * NBLK_WW) { src = wwrs; st = st_wwr; cap = CAP_WW; }
  else if (b < 2 * NBLK_WW + NBLK_WD) { src = wdrs; st = st_wdr; cap = CAP_WDR; }
  else { src = wds; st = st_wd; cap = CAP_WD; }
  int tid = threadIdx.x;
  int wave = tid >> 6;
  ((int*)h)[tid] = 0;
  ((int*)cur)[tid] = 0;
  __syncthreads();
  int e0 = lb * EPB;
#pragma unroll
  for (int k = 0; k < EPB / 256; ++k) {
    int i = e0 + k * 256 + tid;
    if (i < E) atomicAdd(&h[wave][dst[i] >> 10], 1);
  }
  __syncthreads();
  if (tid < NBK_W) {
    int t0 = h[0][tid], t1 = h[1][tid], t2 = h[2][tid], t3 = h[3][tid];
    int tot = t0 + t1 + t2 + t3;
    int base = tot ? atomicAdd(&bcnt[gbase + tid], tot) : 0;
    wb[0][tid] = base;
    wb[1][tid] = base + t0;
    wb[2][tid] = base + t0 + t1;
    wb[3][tid] = base + t0 + t1 + t2;
  }
  __syncthreads();
#pragma unroll
  for (int k = 0; k < EPB / 256; ++k) {
    int i = e0 + k * 256 + tid;
    if (i < E) {
      int d = dst[i];
      int bk = d >> 10;
      int l = atomicAdd(&cur[wave][bk], 1);
      st[(size_t)bk * cap + wb[wave][bk] + l] =
          (unsigned)(src[i] & 0xFFFF) | ((unsigned)(d & (NPB - 1)) << 16);
    }
  }
}

// ---------------- merged gather: readlane scalar-base loads, 8-deep MLP ------
__device__ inline void accum_rel(const unsigned* __restrict__ y,
                                 const unsigned short* __restrict__ csr,
                                 int beg, int end, int lane, float& f0, float& f1) {
  float a0 = 0.f, a1 = 0.f;
  for (int base = beg; base < end; base += 64) {
    int cnt = end - base; if (cnt > 64) cnt = 64;
    int ld = base + lane; if (ld >= end) ld = end - 1;
    int idx = csr[ld];                 // 64 indices per coalesced 128B load
    int j = 0;
    for (; j + 7 < cnt; j += 8) {      // 8 loads in flight
      unsigned u[8];
#pragma unroll
      for (int k = 0; k < 8; ++k) {
        int s = __builtin_amdgcn_readlane(idx, j + k);   // SGPR row -> scalar base
        u[k] = y[((size_t)s << 6) + lane];
      }
#pragma unroll
      for (int k = 0; k < 8; ++k) {
        a0 += __uint_as_float(u[k] << 16);
        a1 += __uint_as_float(u[k] & 0xffff0000u);
      }
    }
    for (; j < cnt; ++j) {
      int s = __builtin_amdgcn_readlane(idx, j);
      unsigned uu = y[((size_t)s << 6) + lane];
      a0 += __uint_as_float(uu << 16);
      a1 += __uint_as_float(uu & 0xffff0000u);
    }
  }
  int deg = end - beg;
  float inv = 1.0f / (float)(deg > 1 ? deg : 1);
  f0 += a0 * inv;
  f1 += a1 * inv;
}

// mode 1: write bf16 activations; mode 2: fused linear+sigmoid readout.
__global__ __launch_bounds__(256) void gather_all(
    const unsigned* __restrict__ y_ww, const unsigned* __restrict__ y_wwr,
    const unsigned* __restrict__ y_wdr, const unsigned* __restrict__ y_wd,
    const unsigned short* __restrict__ c_ww, const unsigned short* __restrict__ c_wwr,
    const unsigned short* __restrict__ c_wdr, const unsigned short* __restrict__ c_wd,
    const int* __restrict__ r_ww, const int* __restrict__ r_wwr,
    const int* __restrict__ r_wdr, const int* __restrict__ r_wd,
    const unsigned* __restrict__ tW, const unsigned* __restrict__ tD,
    const float* __restrict__ bW, const float* __restrict__ bD,
    const float* __restrict__ lw, const float* __restrict__ lb,
    unsigned* __restrict__ oW16, unsigned* __restrict__ oD16,
    float* __restrict__ oF, int mode) {
  int gn = (blockIdx.x << 2) + (threadIdx.x >> 6);
  if (gn >= N_WORD + N_DOC) return;
  int lane = threadIdx.x & 63;
  float f0, f1;
  if (gn < N_WORD) {
    int node = gn;
    unsigned tu = tW[((size_t)node << 6) + lane];     // bf16 self term
    f0 = __uint_as_float(tu << 16);
    f1 = __uint_as_float(tu & 0xffff0000u);
    accum_rel(y_ww, c_ww, r_ww[node], r_ww[node + 1], lane, f0, f1);
    accum_rel(y_wwr, c_wwr, r_wwr[node], r_wwr[node + 1], lane, f0, f1);
    accum_rel(y_wdr, c_wdr, r_wdr[node], r_wdr[node + 1], lane, f0, f1);
    float2 bv = ((const float2*)bW)[lane];
    f0 = fmaxf(f0 + bv.x, 0.f);
    f1 = fmaxf(f1 + bv.y, 0.f);
    if (mode == 1) {
      oW16[((size_t)node << 6) + lane] = (unsigned)f2bf(f0) | ((unsigned)f2bf(f1) << 16);
    } else {
      float2 lv = ((const float2*)lw)[lane];
      float s = f0 * lv.x + f1 * lv.y;
#pragma unroll
      for (int off = 32; off > 0; off >>= 1) s += __shfl_xor(s, off);
      if (lane == 0) oF[node] = 1.0f / (1.0f + expf(-(s + lb[0])));
    }
  } else {
    int node = gn - N_WORD;
    unsigned tu = tD[((size_t)node << 6) + lane];
    f0 = __uint_as_float(tu << 16);
    f1 = __uint_as_float(tu & 0xffff0000u);
    accum_rel(y_wd, c_wd, r_wd[node], r_wd[node + 1], lane, f0, f1);
    float2 bv = ((const float2*)bD)[lane];
    f0 = fmaxf(f0 + bv.x, 0.f);
    f1 = fmaxf(f1 + bv.y, 0.f);
    if (mode == 1) {
      oD16[((size_t)node << 6) + lane] = (unsigned)f2bf(f0) | ((unsigned)f2bf(f1) << 16);
    } else {
      float2 lv = ((const float2*)lw)[lane];
      float s = f0 * lv.x + f1 * lv.y;
#pragma unroll
      for (int off = 32; off > 0; off >>= 1) s += __shfl_xor(s, off);
      if (lane == 0) oF[N_WORD + node] = 1.0f / (1.0f + expf(-(s + lb[0])));
    }
  }
}

// ---------------------------------------------------------------------------
extern "C" void kernel_launch(void* const* d_in, const int* in_sizes, int n_in,
                              void* d_out, int out_size, void* d_ws, size_t ws_size,
                              hipStream_t stream) {
  const float* xw      = (const float*)d_in[0];
  const float* xd      = (const float*)d_in[1];
  const int*   ww_src  = (const int*)d_in[2];
  const int*   ww_dst  = (const int*)d_in[3];
  const int*   wwr_src = (const int*)d_in[4];
  const int*   wwr_dst = (const int*)d_in[5];
  const int*   wd_src  = (const int*)d_in[6];
  const int*   wd_dst  = (const int*)d_in[7];
  const int*   wdr_src = (const int*)d_in[8];
  const int*   wdr_dst = (const int*)d_in[9];
  const float* Ws1     = (const float*)d_in[10];
  const float* Wn1     = (const float*)d_in[11];
  const float* b1      = (const float*)d_in[12];
  const float* Ws2     = (const float*)d_in[13];
  const float* Wn2     = (const float*)d_in[14];
  const float* b2      = (const float*)d_in[15];
  const float* lin_w   = (const float*)d_in[16];
  const float* lin_b   = (const float*)d_in[17];
  float* out = (float*)d_out;

  // ---- workspace carve (~91 MB; staging aliases yB0/yB1 pre-GEMM) ----
  char* p = (char*)d_ws;
  auto alloc = [&](size_t nbytes) {
    char* r = p;
    p += (nbytes + 255) & ~(size_t)255;
    return r;
  };
  unsigned* twA  = (unsigned*)alloc((size_t)N_WORD * D_H * 2);  // bf16 self acc
  unsigned* tdA  = (unsigned*)alloc((size_t)N_DOC * D_H * 2);
  unsigned* xw1B = (unsigned*)alloc((size_t)N_WORD * D_H * 2);
  unsigned* xd1B = (unsigned*)alloc((size_t)N_DOC * D_H * 2);
  unsigned* yB0 = (unsigned*)alloc((size_t)N_WORD * D_H * 2);
  unsigned* yB1 = (unsigned*)alloc((size_t)N_WORD * D_H * 2);
  unsigned* yB2 = (unsigned*)alloc((size_t)N_WORD * D_H * 2);
  unsigned* ydB = (unsigned*)alloc((size_t)N_DOC * D_H * 2);
  unsigned short* csr_ww  = (unsigned short*)alloc((size_t)E_WW * 2);
  unsigned short* csr_wwr = (unsigned short*)alloc((size_t)E_WW * 2);
  unsigned short* csr_wdr = (unsigned short*)alloc((size_t)E_WD * 2);
  unsigned short* csr_wd  = (unsigned short*)alloc((size_t)E_WD * 2);
  int* rp_ww  = (int*)alloc((size_t)(N_WORD + 1) * 4);
  int* rp_wwr = (int*)alloc((size_t)(N_WORD + 1) * 4);
  int* rp_wdr = (int*)alloc((size_t)(N_WORD + 1) * 4);
  int* rp_wd  = (int*)alloc((size_t)(N_DOC + 1) * 4);
  short* Bp1 = (short*)alloc((size_t)6 * 256 * 128 * 2);
  short* Bp2 = (short*)alloc((size_t)6 * 128 * 128 * 2);
  int* bcnt  = (int*)alloc((size_t)BKT * 4);
  float* bs1 = (float*)alloc(D_H * 4);
  float* bs2 = (float*)alloc(D_H * 4);
  unsigned* yBX = (unsigned*)alloc((size_t)N_WORD * D_H * 2);   // wd-neigh out
  // staging aliases (dead before gather1 writes yB0; yB1 staging-only now)
  unsigned* st_ww  = yB0;
  unsigned* st_wwr = st_ww + (size_t)NBK_W * CAP_WW;
  unsigned* st_wdr = yB1;
  unsigned* st_wd  = st_wdr + (size_t)NBK_W * CAP_WDR;

  // ---- CSR bin + weight pack (fused dispatch) ----
  hipMemsetAsync(bcnt, 0, BKT * 4, stream);
  binpack_kernel<<<NBLK_TOT + PACK_BLKS, 256, 0, stream>>>(
      ww_src, ww_dst, wwr_src, wwr_dst, wdr_src, wdr_dst, wd_src, wd_dst,
      bcnt, st_ww, st_wwr, st_wdr, st_wd,
      Ws1, Wn1, Ws2, Wn2, Bp1, Bp2, b1, b2, bs1, bs2);

  const int W1 = 256 * 128;
  const int W2 = 128 * 128;

  // ================= layer 1: [place || GEMM] + merged gather ==============
  // gemm1 outputs avoid all staging aliases (yB0/yB1); gather1 writes word act
  // into yB0 (staging dead by then) and doc act into xd1B.
  G6 g1;
  g1.B[0] = Bp1 + 0 * W1; g1.C[0] = (unsigned short*)twA;   // word self
  g1.B[1] = Bp1 + 1 * W1; g1.C[1] = (unsigned short*)yB2;   // ww neigh
  g1.B[2] = Bp1 + 2 * W1; g1.C[2] = (unsigned short*)xw1B;  // wwr neigh
  g1.B[3] = Bp1 + 3 * W1; g1.C[3] = (unsigned short*)yBX;   // wd neigh
  g1.B[4] = Bp1 + 5 * W1; g1.C[4] = (unsigned short*)tdA;   // doc self
  g1.B[5] = Bp1 + 4 * W1; g1.C[5] = (unsigned short*)ydB;   // wdr neigh
  CSRB q;
  q.st_ww = st_ww; q.st_wwr = st_wwr; q.st_wdr = st_wdr; q.st_wd = st_wd;
  q.c_ww = csr_ww; q.c_wwr = csr_wwr; q.c_wdr = csr_wdr; q.c_wd = csr_wd;
  q.rp_ww = rp_ww; q.rp_wwr = rp_wwr; q.rp_wdr = rp_wdr; q.rp_wd = rp_wd;
  q.bcnt = bcnt;
  gemm1_place<<<BKT + NSTRIP, 256, 0, stream>>>(xw, xd, g1, q);
  gather_all<<<(N_WORD + N_DOC + 3) / 4, 256, 0, stream>>>(
      yB2, xw1B, ydB, yBX, csr_ww, csr_wwr, csr_wdr, csr_wd,
      rp_ww, rp_wwr, rp_wdr, rp_wd, twA, tdA, bs1, b1 + 256,
      lin_w, lin_b, yB0, xd1B, nullptr, 1);

  // ================= layer 2: GEMM + merged gather (readout) ===============
  G6 g2;
  g2.B[0] = Bp2 + 0 * W2; g2.C[0] = (unsigned short*)twA;
  g2.B[1] = Bp2 + 1 * W2; g2.C[1] = (unsigned short*)yB2;
  g2.B[2] = Bp2 + 2 * W2; g2.C[2] = (unsigned short*)xw1B;
  g2.B[3] = Bp2 + 3 * W2; g2.C[3] = (unsigned short*)yBX;
  g2.B[4] = Bp2 + 5 * W2; g2.C[4] = (unsigned short*)tdA;
  g2.B[5] = Bp2 + 4 * W2; g2.C[5] = (unsigned short*)ydB;
  gemm2_kernel<<<NSTRIP, 256, 0, stream>>>(yB0, xd1B, g2);
  gather_all<<<(N_WORD + N_DOC + 3) / 4, 256, 0, stream>>>(
      yB2, xw1B, ydB, yBX, csr_ww, csr_wwr, csr_wdr, csr_wd,
      rp_ww, rp_wwr, rp_wdr, rp_wd, twA, tdA, bs2, b2 + 256,
      lin_w, lin_b, nullptr, nullptr, out, 2);
}

// Round 13
// 402.875 us; speedup vs baseline: 2.0100x; 1.0641x over previous
//
#include <hip/hip_runtime.h>
#include <math.h>

#define N_WORD 50000
#define N_DOC  10000
#define E_WW   800000
#define E_WD   320000
#define D_IN   256
#define D_H    128

#define NPB    256            // nodes per bucket (r13: 1024->256, 4x place blocks)
#define NBK_W  196            // ceil(50000/256)
#define NBK_D  40             // ceil(10000/256)
#define BKT    (3 * NBK_W + NBK_D)   // 628 buckets total
#define EPB    4096           // edges per block in bin
#define NBLK_WW 196           // ceil(800000/4096)
#define NBLK_WD 79            // ceil(320000/4096)
#define NBLK_TOT (2 * NBLK_WW + 2 * NBLK_WD)   // 550
#define PACK_BLKS 145

// per-bucket staging caps (binomial mean + >10 sigma; graph fixed by seed)
#define CAP_WW  4736          // mean 4082, sigma ~64
#define CAP_WDR 2176          // mean 1633, sigma ~40
#define CAP_WD  8960          // mean 8000, sigma ~89

#define WSTRIP ((N_WORD + 63) / 64)  // 782
#define DSTRIP ((N_DOC + 63) / 64)   // 157
#define NSTRIP (WSTRIP + DSTRIP)     // 939

typedef __attribute__((ext_vector_type(8))) short short8;
typedef __attribute__((ext_vector_type(4))) float f32x4;

__device__ inline unsigned short f2bf(float f) {  // fp32 -> bf16 bits, RNE
  unsigned u = __float_as_uint(f);
  u = (u + 0x7fffu + ((u >> 16) & 1u)) >> 16;
  return (unsigned short)u;
}

// ---------------- GEMM body: register-resident A fragments, no LDS ----------
struct G6 { const short* B[6]; unsigned short* C[6]; };

template <int ABF, int K>
__device__ void gemm_body(const void* __restrict__ Aw, const void* __restrict__ Ad,
                          const G6& g, int blk) {
  constexpr int KT = K >> 5;
  int wid = threadIdx.x >> 6, lane = threadIdx.x & 63;
  const void* A; int M, row0, h0, h1;
  if (blk < WSTRIP) { A = Aw; M = N_WORD; row0 = blk << 6; h0 = 0; h1 = 4; }
  else { A = Ad; M = N_DOC; row0 = (blk - WSTRIP) << 6; h0 = 4; h1 = 6; }
  int r = lane & 15, quad = lane >> 4;
  int m0 = row0 + wid * 16;
  int mA = m0 + r; if (mA >= M) mA = M - 1;   // clamp: garbage rows never stored
  short8 afr[KT];
  if (ABF) {
    const short* ap = (const short*)A + (size_t)mA * K + quad * 8;
#pragma unroll
    for (int kt = 0; kt < KT; ++kt) afr[kt] = *(const short8*)(ap + kt * 32);
  } else {
    const float* ap = (const float*)A + (size_t)mA * K + quad * 8;
#pragma unroll
    for (int kt = 0; kt < KT; ++kt) {
      float4 a0 = *(const float4*)(ap + kt * 32);
      float4 a1 = *(const float4*)(ap + kt * 32 + 4);
      short8 v;
      v[0] = (short)f2bf(a0.x); v[1] = (short)f2bf(a0.y);
      v[2] = (short)f2bf(a0.z); v[3] = (short)f2bf(a0.w);
      v[4] = (short)f2bf(a1.x); v[5] = (short)f2bf(a1.y);
      v[6] = (short)f2bf(a1.z); v[7] = (short)f2bf(a1.w);
      afr[kt] = v;
    }
  }
  for (int h = h0; h < h1; ++h) {
    const short* Bp = g.B[h];
    f32x4 acc[8];
#pragma unroll
    for (int nt = 0; nt < 8; ++nt) acc[nt] = (f32x4){0.f, 0.f, 0.f, 0.f};
#pragma unroll
    for (int kt = 0; kt < KT; ++kt) {
      const short* bbase = Bp + ((size_t)kt * 4096) + lane * 8;
#pragma unroll
      for (int nt = 0; nt < 8; ++nt) {
        short8 bf = *(const short8*)(bbase + (size_t)nt * 512);
        acc[nt] = __builtin_amdgcn_mfma_f32_16x16x32_bf16(afr[kt], bf, acc[nt], 0, 0, 0);
      }
    }
    // C/D: col = lane&15, row = quad*4 + rr  [m89-verified]
    unsigned short* C = g.C[h];
#pragma unroll
    for (int nt = 0; nt < 8; ++nt)
#pragma unroll
      for (int rr = 0; rr < 4; ++rr) {
        int row = m0 + quad * 4 + rr;
        if (row < M) C[(size_t)row * 128 + nt * 16 + r] = f2bf(acc[nt][rr]);
      }
  }
}

// ---------------- place body: one block per 256-node bucket ------------------
struct CSRB {
  const unsigned *st_ww, *st_wwr, *st_wdr, *st_wd;
  unsigned short *c_ww, *c_wwr, *c_wdr, *c_wd;
  int *rp_ww, *rp_wwr, *rp_wdr, *rp_wd;
  const int* bcnt;
};

__device__ void place_body(int g, const CSRB& q, int* smem) {
  int* cnt = smem;                  // 256
  int* off = cnt + 256;             // 256
  int* sm  = off + 256;             // 256
  const unsigned* st; unsigned short* csr; int* rp; int relFirst, relLast, n, cap, Etot;
  if (g < NBK_W)            { st = q.st_ww;  csr = q.c_ww;  rp = q.rp_ww;  relFirst = 0;         relLast = NBK_W - 1;     n = N_WORD; cap = CAP_WW;  Etot = E_WW; }
  else if (g < 2 * NBK_W)   { st = q.st_wwr; csr = q.c_wwr; rp = q.rp_wwr; relFirst = NBK_W;     relLast = 2 * NBK_W - 1; n = N_WORD; cap = CAP_WW;  Etot = E_WW; }
  else if (g < 3 * NBK_W)   { st = q.st_wdr; csr = q.c_wdr; rp = q.rp_wdr; relFirst = 2 * NBK_W; relLast = 3 * NBK_W - 1; n = N_WORD; cap = CAP_WDR; Etot = E_WD; }
  else                      { st = q.st_wd;  csr = q.c_wd;  rp = q.rp_wd;  relFirst = 3 * NBK_W; relLast = BKT - 1;       n = N_DOC;  cap = CAP_WD;  Etot = E_WD; }
  int cb = g - relFirst;
  int tid = threadIdx.x;
  // segment-exclusive prefix of bcnt over [relFirst, g): block tree-reduce
  int v = (tid < cb) ? q.bcnt[relFirst + tid] : 0;
  sm[tid] = v;
  __syncthreads();
  for (int o = 128; o > 0; o >>= 1) {
    if (tid < o) sm[tid] += sm[tid + o];
    __syncthreads();
  }
  int bstart = sm[0];
  if (g == relLast && tid == 0) rp[n] = Etot;   // tail sentinel
  __syncthreads();                               // sm reuse below
  int node_base = cb << 8;
  int node_cnt = n - node_base; if (node_cnt > NPB) node_cnt = NPB;
  int ecnt = q.bcnt[g];
  const unsigned* w = st + (size_t)cb * cap;
  cnt[tid] = 0;
  __syncthreads();
  for (int j = tid; j < ecnt; j += 256) atomicAdd(&cnt[w[j] >> 16], 1);
  __syncthreads();
  int c = cnt[tid];
  sm[tid] = c;
  __syncthreads();
  for (int o = 1; o < 256; o <<= 1) {
    int add = (tid >= o) ? sm[tid - o] : 0;
    __syncthreads();
    sm[tid] += add;
    __syncthreads();
  }
  int ex = sm[tid] - c;
  off[tid] = ex;
  if (tid < node_cnt) rp[node_base + tid] = bstart + ex;
  __syncthreads();
  for (int j = tid; j < ecnt; j += 256) {
    unsigned e = w[j];
    int p = atomicAdd(&off[e >> 16], 1);
    csr[bstart + p] = (unsigned short)(e & 0xFFFFu);
  }
}

// ---------------- fused dispatches -------------------------------------------
// place blocks FIRST (628, start immediately), then layer-1 gemm (939).
__global__ __launch_bounds__(256, 4) void gemm1_place(
    const float* __restrict__ Aw, const float* __restrict__ Ad, G6 g, CSRB q) {
  __shared__ int smem[768];          // 3 KB (place only; gemm is LDS-free)
  if (blockIdx.x < BKT) place_body(blockIdx.x, q, smem);
  else gemm_body<0, 256>(Aw, Ad, g, blockIdx.x - BKT);
}

__global__ __launch_bounds__(256, 4) void gemm2_kernel(
    const void* __restrict__ Aw, const void* __restrict__ Ad, G6 g) {
  gemm_body<1, 128>(Aw, Ad, g, blockIdx.x);
}

// ---------------- fused CSR-bin + weight-pack dispatch -----------------------
__device__ inline void rel_map(int b, const int* wwd, const int* wwrd, const int* wdrd,
                               const int* wdd, const int*& dst, int& E, int& gbase, int& lb) {
  if (b < NBLK_WW) { dst = wwd; E = E_WW; gbase = 0; lb = b; }
  else if (b < 2 * NBLK_WW) { dst = wwrd; E = E_WW; gbase = NBK_W; lb = b - NBLK_WW; }
  else if (b < 2 * NBLK_WW + NBLK_WD) { dst = wdrd; E = E_WD; gbase = 2 * NBK_W; lb = b - 2 * NBLK_WW; }
  else { dst = wdd; E = E_WD; gbase = 3 * NBK_W; lb = b - 2 * NBLK_WW - NBLK_WD; }
}

__global__ __launch_bounds__(256) void binpack_kernel(
    const int* wws, const int* wwd, const int* wwrs, const int* wwrd,
    const int* wdrs, const int* wdrd, const int* wds, const int* wdd,
    int* bcnt, unsigned* st_ww, unsigned* st_wwr, unsigned* st_wdr, unsigned* st_wd,
    const float* __restrict__ Ws1, const float* __restrict__ Wn1,
    const float* __restrict__ Ws2, const float* __restrict__ Wn2,
    short* __restrict__ Bp1, short* __restrict__ Bp2,
    const float* __restrict__ b1, const float* __restrict__ b2,
    float* __restrict__ bs1, float* __restrict__ bs2) {
  __shared__ int h[4][NBK_W], wb[4][NBK_W], cur[4][NBK_W];   // 9.4 KB
  int b = blockIdx.x;
  if (b >= NBLK_TOT) {
    // ---------- pack branch ----------
    int tid = (b - NBLK_TOT) * 256 + threadIdx.x;
    const int L1T = 6 * 4096;
    const int L2T = 6 * 2048;
    if (tid >= L1T + L2T) {          // bias combine tail
      int t = tid - (L1T + L2T);
      if (t < 128) bs1[t] = b1[t] + b1[128 + t] + b1[384 + t];
      else if (t < 256) { int u = t - 128; bs2[u] = b2[u] + b2[128 + u] + b2[384 + u]; }
      return;
    }
    const float *src0, *src1 = nullptr, *src2 = nullptr;
    short* dstp;
    int kt, nt, lane;
    if (tid < L1T) {
      int mat = tid / 4096, rem = tid % 4096;
      kt = rem / 512; nt = (rem / 64) % 8; lane = rem % 64;
      const int W1 = 256 * 128;
      if (mat == 0) { src0 = Ws1; src1 = Ws1 + W1; src2 = Ws1 + 3 * W1; }
      else if (mat <= 4) src0 = Wn1 + (size_t)(mat - 1) * W1;
      else src0 = Ws1 + 2 * W1;
      dstp = Bp1 + (size_t)mat * W1 + ((size_t)(kt * 8 + nt) * 64 + lane) * 8;
    } else {
      int t2 = tid - L1T;
      int mat = t2 / 2048, rem = t2 % 2048;
      kt = rem / 512; nt = (rem / 64) % 8; lane = rem % 64;
      const int W2 = 128 * 128;
      if (mat == 0) { src0 = Ws2; src1 = Ws2 + W2; src2 = Ws2 + 3 * W2; }
      else if (mat <= 4) src0 = Wn2 + (size_t)(mat - 1) * W2;
      else src0 = Ws2 + 2 * W2;
      dstp = Bp2 + (size_t)mat * W2 + ((size_t)(kt * 8 + nt) * 64 + lane) * 8;
    }
    int n = nt * 16 + (lane & 15);
    int kb = kt * 32 + (lane >> 4) * 8;
    short8 v;
#pragma unroll
    for (int j = 0; j < 8; ++j) {
      float f = src0[(size_t)(kb + j) * 128 + n];
      if (src1) f += src1[(size_t)(kb + j) * 128 + n] + src2[(size_t)(kb + j) * 128 + n];
      v[j] = (short)f2bf(f);
    }
    *(short8*)dstp = v;
    return;
  }
  // ---------- bin branch: per-wave hist -> per-wave reservation -> scatter ---
  const int* dst; int E, gbase, lb;
  rel_map(b, wwd, wwrd, wdrd, wdd, dst, E, gbase, lb);
  const int* src; unsigned* st; int cap;
  if (b < NBLK_WW) { src = wws; st = st_ww; cap = CAP_WW; }
  else if (b < 2 * NBLK_WW) { src = wwrs; st = st_wwr; cap = CAP_WW; }
  else if (b < 2 * NBLK_WW + NBLK_WD) { src = wdrs; st = st_wdr; cap = CAP_WDR; }
  else { src = wds; st = st_wd; cap = CAP_WD; }
  int tid = threadIdx.x;
  int wave = tid >> 6;
  for (int i = tid; i < 4 * NBK_W; i += 256) { ((int*)h)[i] = 0; ((int*)cur)[i] = 0; }
  __syncthreads();
  int e0 = lb * EPB;
#pragma unroll
  for (int k = 0; k < EPB / 256; ++k) {
    int i = e0 + k * 256 + tid;
    if (i < E) atomicAdd(&h[wave][dst[i] >> 8], 1);
  }
  __syncthreads();
  if (tid < NBK_W) {
    int t0 = h[0][tid], t1 = h[1][tid], t2 = h[2][tid], t3 = h[3][tid];
    int tot = t0 + t1 + t2 + t3;
    int base = tot ? atomicAdd(&bcnt[gbase + tid], tot) : 0;
    wb[0][tid] = base;
    wb[1][tid] = base + t0;
    wb[2][tid] = base + t0 + t1;
    wb[3][tid] = base + t0 + t1 + t2;
  }
  __syncthreads();
#pragma unroll
  for (int k = 0; k < EPB / 256; ++k) {
    int i = e0 + k * 256 + tid;
    if (i < E) {
      int d = dst[i];
      int bk = d >> 8;
      int l = atomicAdd(&cur[wave][bk], 1);
      st[(size_t)bk * cap + wb[wave][bk] + l] =
          (unsigned)(src[i] & 0xFFFF) | ((unsigned)(d & (NPB - 1)) << 16);
    }
  }
}

// ---------------- merged gather: readlane scalar-base loads, 8-deep MLP ------
__device__ inline void accum_rel(const unsigned* __restrict__ y,
                                 const unsigned short* __restrict__ csr,
                                 int beg, int end, int lane, float& f0, float& f1) {
  float a0 = 0.f, a1 = 0.f;
  for (int base = beg; base < end; base += 64) {
    int cnt = end - base; if (cnt > 64) cnt = 64;
    int ld = base + lane; if (ld >= end) ld = end - 1;
    int idx = csr[ld];                 // 64 indices per coalesced 128B load
    int j = 0;
    for (; j + 7 < cnt; j += 8) {      // 8 loads in flight
      unsigned u[8];
#pragma unroll
      for (int k = 0; k < 8; ++k) {
        int s = __builtin_amdgcn_readlane(idx, j + k);   // SGPR row -> scalar base
        u[k] = y[((size_t)s << 6) + lane];
      }
#pragma unroll
      for (int k = 0; k < 8; ++k) {
        a0 += __uint_as_float(u[k] << 16);
        a1 += __uint_as_float(u[k] & 0xffff0000u);
      }
    }
    for (; j < cnt; ++j) {
      int s = __builtin_amdgcn_readlane(idx, j);
      unsigned uu = y[((size_t)s << 6) + lane];
      a0 += __uint_as_float(uu << 16);
      a1 += __uint_as_float(uu & 0xffff0000u);
    }
  }
  int deg = end - beg;
  float inv = 1.0f / (float)(deg > 1 ? deg : 1);
  f0 += a0 * inv;
  f1 += a1 * inv;
}

// mode 1: write bf16 activations; mode 2: fused linear+sigmoid readout.
__global__ __launch_bounds__(256) void gather_all(
    const unsigned* __restrict__ y_ww, const unsigned* __restrict__ y_wwr,
    const unsigned* __restrict__ y_wdr, const unsigned* __restrict__ y_wd,
    const unsigned short* __restrict__ c_ww, const unsigned short* __restrict__ c_wwr,
    const unsigned short* __restrict__ c_wdr, const unsigned short* __restrict__ c_wd,
    const int* __restrict__ r_ww, const int* __restrict__ r_wwr,
    const int* __restrict__ r_wdr, const int* __restrict__ r_wd,
    const unsigned* __restrict__ tW, const unsigned* __restrict__ tD,
    const float* __restrict__ bW, const float* __restrict__ bD,
    const float* __restrict__ lw, const float* __restrict__ lb,
    unsigned* __restrict__ oW16, unsigned* __restrict__ oD16,
    float* __restrict__ oF, int mode) {
  int gn = (blockIdx.x << 2) + (threadIdx.x >> 6);
  if (gn >= N_WORD + N_DOC) return;
  int lane = threadIdx.x & 63;
  float f0, f1;
  if (gn < N_WORD) {
    int node = gn;
    unsigned tu = tW[((size_t)node << 6) + lane];     // bf16 self term
    f0 = __uint_as_float(tu << 16);
    f1 = __uint_as_float(tu & 0xffff0000u);
    accum_rel(y_ww, c_ww, r_ww[node], r_ww[node + 1], lane, f0, f1);
    accum_rel(y_wwr, c_wwr, r_wwr[node], r_wwr[node + 1], lane, f0, f1);
    accum_rel(y_wdr, c_wdr, r_wdr[node], r_wdr[node + 1], lane, f0, f1);
    float2 bv = ((const float2*)bW)[lane];
    f0 = fmaxf(f0 + bv.x, 0.f);
    f1 = fmaxf(f1 + bv.y, 0.f);
    if (mode == 1) {
      oW16[((size_t)node << 6) + lane] = (unsigned)f2bf(f0) | ((unsigned)f2bf(f1) << 16);
    } else {
      float2 lv = ((const float2*)lw)[lane];
      float s = f0 * lv.x + f1 * lv.y;
#pragma unroll
      for (int off = 32; off > 0; off >>= 1) s += __shfl_xor(s, off);
      if (lane == 0) oF[node] = 1.0f / (1.0f + expf(-(s + lb[0])));
    }
  } else {
    int node = gn - N_WORD;
    unsigned tu = tD[((size_t)node << 6) + lane];
    f0 = __uint_as_float(tu << 16);
    f1 = __uint_as_float(tu & 0xffff0000u);
    accum_rel(y_wd, c_wd, r_wd[node], r_wd[node + 1], lane, f0, f1);
    float2 bv = ((const float2*)bD)[lane];
    f0 = fmaxf(f0 + bv.x, 0.f);
    f1 = fmaxf(f1 + bv.y, 0.f);
    if (mode == 1) {
      oD16[((size_t)node << 6) + lane] = (unsigned)f2bf(f0) | ((unsigned)f2bf(f1) << 16);
    } else {
      float2 lv = ((const float2*)lw)[lane];
      float s = f0 * lv.x + f1 * lv.y;
#pragma unroll
      for (int off = 32; off > 0; off >>= 1) s += __shfl_xor(s, off);
      if (lane == 0) oF[N_WORD + node] = 1.0f / (1.0f + expf(-(s + lb[0])));
    }
  }
}

// ---------------------------------------------------------------------------
extern "C" void kernel_launch(void* const* d_in, const int* in_sizes, int n_in,
                              void* d_out, int out_size, void* d_ws, size_t ws_size,
                              hipStream_t stream) {
  const float* xw      = (const float*)d_in[0];
  const float* xd      = (const float*)d_in[1];
  const int*   ww_src  = (const int*)d_in[2];
  const int*   ww_dst  = (const int*)d_in[3];
  const int*   wwr_src = (const int*)d_in[4];
  const int*   wwr_dst = (const int*)d_in[5];
  const int*   wd_src  = (const int*)d_in[6];
  const int*   wd_dst  = (const int*)d_in[7];
  const int*   wdr_src = (const int*)d_in[8];
  const int*   wdr_dst = (const int*)d_in[9];
  const float* Ws1     = (const float*)d_in[10];
  const float* Wn1     = (const float*)d_in[11];
  const float* b1      = (const float*)d_in[12];
  const float* Ws2     = (const float*)d_in[13];
  const float* Wn2     = (const float*)d_in[14];
  const float* b2      = (const float*)d_in[15];
  const float* lin_w   = (const float*)d_in[16];
  const float* lin_b   = (const float*)d_in[17];
  float* out = (float*)d_out;

  // ---- workspace carve (~91 MB; staging aliases yB0/yB1 pre-place) ----
  char* p = (char*)d_ws;
  auto alloc = [&](size_t nbytes) {
    char* r = p;
    p += (nbytes + 255) & ~(size_t)255;
    return r;
  };
  unsigned* twA  = (unsigned*)alloc((size_t)N_WORD * D_H * 2);  // bf16 self acc
  unsigned* tdA  = (unsigned*)alloc((size_t)N_DOC * D_H * 2);
  unsigned* xw1B = (unsigned*)alloc((size_t)N_WORD * D_H * 2);
  unsigned* xd1B = (unsigned*)alloc((size_t)N_DOC * D_H * 2);
  unsigned* yB0 = (unsigned*)alloc((size_t)N_WORD * D_H * 2);
  unsigned* yB1 = (unsigned*)alloc((size_t)N_WORD * D_H * 2);
  unsigned* yB2 = (unsigned*)alloc((size_t)N_WORD * D_H * 2);
  unsigned* ydB = (unsigned*)alloc((size_t)N_DOC * D_H * 2);
  unsigned short* csr_ww  = (unsigned short*)alloc((size_t)E_WW * 2);
  unsigned short* csr_wwr = (unsigned short*)alloc((size_t)E_WW * 2);
  unsigned short* csr_wdr = (unsigned short*)alloc((size_t)E_WD * 2);
  unsigned short* csr_wd  = (unsigned short*)alloc((size_t)E_WD * 2);
  int* rp_ww  = (int*)alloc((size_t)(N_WORD + 1) * 4);
  int* rp_wwr = (int*)alloc((size_t)(N_WORD + 1) * 4);
  int* rp_wdr = (int*)alloc((size_t)(N_WORD + 1) * 4);
  int* rp_wd  = (int*)alloc((size_t)(N_DOC + 1) * 4);
  short* Bp1 = (short*)alloc((size_t)6 * 256 * 128 * 2);
  short* Bp2 = (short*)alloc((size_t)6 * 128 * 128 * 2);
  int* bcnt  = (int*)alloc((size_t)BKT * 4);
  float* bs1 = (float*)alloc(D_H * 4);
  float* bs2 = (float*)alloc(D_H * 4);
  unsigned* yBX = (unsigned*)alloc((size_t)N_WORD * D_H * 2);   // wd-neigh out
  // staging aliases (dead before gather1 writes yB0; yB1 staging-only)
  // yB0: ww 196*4736*4 = 3.54MB + wwr 3.54MB = 7.1MB (yB0 is 12.8MB)
  // yB1: wdr 196*2176*4 = 1.63MB + wd 40*8960*4 = 1.37MB = 3.0MB
  unsigned* st_ww  = yB0;
  unsigned* st_wwr = st_ww + (size_t)NBK_W * CAP_WW;
  unsigned* st_wdr = yB1;
  unsigned* st_wd  = st_wdr + (size_t)NBK_W * CAP_WDR;

  // ---- CSR bin + weight pack (fused dispatch) ----
  hipMemsetAsync(bcnt, 0, BKT * 4, stream);
  binpack_kernel<<<NBLK_TOT + PACK_BLKS, 256, 0, stream>>>(
      ww_src, ww_dst, wwr_src, wwr_dst, wdr_src, wdr_dst, wd_src, wd_dst,
      bcnt, st_ww, st_wwr, st_wdr, st_wd,
      Ws1, Wn1, Ws2, Wn2, Bp1, Bp2, b1, b2, bs1, bs2);

  const int W1 = 256 * 128;
  const int W2 = 128 * 128;

  // ================= layer 1: [place || GEMM] + merged gather ==============
  G6 g1;
  g1.B[0] = Bp1 + 0 * W1; g1.C[0] = (unsigned short*)twA;   // word self
  g1.B[1] = Bp1 + 1 * W1; g1.C[1] = (unsigned short*)yB2;   // ww neigh
  g1.B[2] = Bp1 + 2 * W1; g1.C[2] = (unsigned short*)xw1B;  // wwr neigh
  g1.B[3] = Bp1 + 3 * W1; g1.C[3] = (unsigned short*)yBX;   // wd neigh
  g1.B[4] = Bp1 + 5 * W1; g1.C[4] = (unsigned short*)tdA;   // doc self
  g1.B[5] = Bp1 + 4 * W1; g1.C[5] = (unsigned short*)ydB;   // wdr neigh
  CSRB q;
  q.st_ww = st_ww; q.st_wwr = st_wwr; q.st_wdr = st_wdr; q.st_wd = st_wd;
  q.c_ww = csr_ww; q.c_wwr = csr_wwr; q.c_wdr = csr_wdr; q.c_wd = csr_wd;
  q.rp_ww = rp_ww; q.rp_wwr = rp_wwr; q.rp_wdr = rp_wdr; q.rp_wd = rp_wd;
  q.bcnt = bcnt;
  gemm1_place<<<BKT + NSTRIP, 256, 0, stream>>>(xw, xd, g1, q);
  // gather1: word act -> yB0 (staging dead now), doc act -> xd1B
  gather_all<<<(N_WORD + N_DOC + 3) / 4, 256, 0, stream>>>(
      yB2, xw1B, ydB, yBX, csr_ww, csr_wwr, csr_wdr, csr_wd,
      rp_ww, rp_wwr, rp_wdr, rp_wd, twA, tdA, bs1, b1 + 256,
      lin_w, lin_b, yB0, xd1B, nullptr, 1);

  // ================= layer 2: GEMM + merged gather (readout) ===============
  G6 g2;
  g2.B[0] = Bp2 + 0 * W2; g2.C[0] = (unsigned short*)twA;
  g2.B[1] = Bp2 + 1 * W2; g2.C[1] = (unsigned short*)yB2;
  g2.B[2] = Bp2 + 2 * W2; g2.C[2] = (unsigned short*)xw1B;
  g2.B[3] = Bp2 + 3 * W2; g2.C[3] = (unsigned short*)yBX;
  g2.B[4] = Bp2 + 5 * W2; g2.C[4] = (unsigned short*)tdA;
  g2.B[5] = Bp2 + 4 * W2; g2.C[5] = (unsigned short*)ydB;
  gemm2_kernel<<<NSTRIP, 256, 0, stream>>>(yB0, xd1B, g2);
  gather_all<<<(N_WORD + N_DOC + 3) / 4, 256, 0, stream>>>(
      yB2, xw1B, ydB, yBX, csr_ww, csr_wwr, csr_wdr, csr_wd,
      rp_ww, rp_wwr, rp_wdr, rp_wd, twA, tdA, bs2, b2 + 256,
      lin_w, lin_b, nullptr, nullptr, out, 2);
}